// Round 1
// 780.304 us; speedup vs baseline: 1.1373x; 1.1373x over previous
//
#include <hip/hip_runtime.h>
#include <cmath>

typedef unsigned short u16;
typedef __attribute__((ext_vector_type(8))) short short8;
typedef __attribute__((ext_vector_type(4))) float float4v;
typedef unsigned short ushort2v __attribute__((ext_vector_type(2)));

#define S_LEN 2048
#define NTOK  8192   // B*S
#define TOPK  35
#define NT512 ((size_t)NTOK*512)

__device__ __forceinline__ u16 f2b(float f){
  unsigned int x = __float_as_uint(f);
  unsigned int r = (x + 0x7fffu + ((x >> 16) & 1u)) >> 16;
  return (u16)r;
}
__device__ __forceinline__ float b2f(u16 u){
  return __uint_as_float(((unsigned int)u) << 16);
}

// bf16(f) -> monotone-increasing u16 sort key (no NaNs assumed)
__device__ __forceinline__ unsigned key_of(float f){
  unsigned u = (unsigned)f2b(f);
  unsigned m = (u & 0x8000u) ? 0xFFFFu : 0x8000u;
  return (u ^ m) & 0xFFFFu;
}
__device__ __forceinline__ float key_to_f(unsigned key){
  unsigned m = (key & 0x8000u) ? 0x8000u : 0xFFFFu;
  return __uint_as_float(((key ^ m) & 0xFFFFu) << 16);
}
__device__ __forceinline__ unsigned pkmax(unsigned a, unsigned b){
  union { unsigned u; ushort2v v; } x, y, r;
  x.u = a; y.u = b;
  r.v = __builtin_elementwise_max(x.v, y.v);
  return r.u;
}
__device__ __forceinline__ unsigned pkmin(unsigned a, unsigned b){
  union { unsigned u; ushort2v v; } x, y, r;
  x.u = a; y.u = b;
  r.v = __builtin_elementwise_min(x.v, y.v);
  return r.u;
}

// full bitonic sort, DESCENDING, of 128 packed-u16x2 values distributed
// 2 per lane: element e = l (v0) and e = 64+l (v1). Sorts both u16 halves
// independently (pk ops are per-half).
__device__ __forceinline__ void bsort128(unsigned &v0, unsigned &v1, int l){
  #pragma unroll
  for (int k = 2; k <= 128; k <<= 1){
    #pragma unroll
    for (int j = k >> 1; j > 0; j >>= 1){
      if (j == 64){
        // local CE between e=l and e=64+l (k==128 only): lower keeps max
        unsigned hi = pkmax(v0, v1), lo = pkmin(v0, v1);
        v0 = hi; v1 = lo;
      } else {
        unsigned o0 = (unsigned)__shfl_xor((int)v0, j, 64);
        unsigned o1 = (unsigned)__shfl_xor((int)v1, j, 64);
        // keep_max(e) = ((e&k)==0) XOR ((e&j)!=0)
        bool up0 = (((l & k) == 0) != ((l & j) != 0));
        bool up1 = ((((64 + l) & k) == 0) != ((l & j) != 0));
        unsigned hi0 = pkmax(v0, o0), lo0 = pkmin(v0, o0);
        unsigned hi1 = pkmax(v1, o1), lo1 = pkmin(v1, o1);
        v0 = up0 ? hi0 : lo0;
        v1 = up1 ? hi1 : lo1;
      }
    }
  }
}

// async global->LDS 16B direct copy; LDS dest pattern = wave-uniform base + lane*16
__device__ __forceinline__ void gload16(const void* g, void* l){
  __builtin_amdgcn_global_load_lds(
      (const __attribute__((address_space(1))) unsigned int*)g,
      (__attribute__((address_space(3))) unsigned int*)l, 16, 0, 0);
}

// ---------------- fused weight transpose + bf16 convert (all 12 weights) ----------------
// 32x32 tiles; blockIdx.y = layer, blockIdx.x = flat tile id across 6 segments.
struct WtArgs {
  const float* wq; const float* wk; const float* wv; const float* wo;
  const float* ff1w; const float* ff2w;
  u16* wt_qkv; u16* wt_wo; u16* wt_ff1; u16* wt_ff2;
};
__global__ void convert_all(WtArgs a){
  __shared__ u16 t[32][33];
  int l = blockIdx.y;
  int tt = blockIdx.x;
  const float* W; u16* Wt; int K, N, tx_, ty_;
  if (tt < 1024){                 // qkv (3 segs) + wo, all 512x512, 16x16 tiles
    int seg = tt >> 8, r = tt & 255;
    tx_ = r & 15; ty_ = r >> 4; K = 512; N = 512;
    if (seg == 0){ W = a.wq + (size_t)l*262144; Wt = a.wt_qkv + (size_t)l*786432; }
    else if (seg == 1){ W = a.wk + (size_t)l*262144; Wt = a.wt_qkv + (size_t)l*786432 + 262144; }
    else if (seg == 2){ W = a.wv + (size_t)l*262144; Wt = a.wt_qkv + (size_t)l*786432 + 524288; }
    else { W = a.wo + (size_t)l*262144; Wt = a.wt_wo + (size_t)l*262144; }
  } else if (tt < 2048){          // ff1: K=512, N=2048 -> tiles 64 x 16
    int r = tt - 1024;
    tx_ = r & 63; ty_ = r >> 6; K = 512; N = 2048;
    W = a.ff1w + (size_t)l*1048576; Wt = a.wt_ff1 + (size_t)l*1048576;
  } else {                        // ff2: K=2048, N=512 -> tiles 16 x 64
    int r = tt - 2048;
    tx_ = r & 15; ty_ = r >> 4; K = 2048; N = 512;
    W = a.ff2w + (size_t)l*1048576; Wt = a.wt_ff2 + (size_t)l*1048576;
  }
  int k0 = ty_*32, n0 = tx_*32;
  int tx = threadIdx.x, ty = threadIdx.y;   // 32x8
  #pragma unroll
  for (int i = ty; i < 32; i += 8)
    t[i][tx] = f2b(W[(size_t)(k0+i)*N + n0+tx]);
  __syncthreads();
  #pragma unroll
  for (int i = ty; i < 32; i += 8)
    Wt[(size_t)(n0+i)*K + k0+tx] = t[tx][i];
}

// ---------------- embedding + sinusoidal PE (writes fp32 h + bf16 h16) ----------------
__global__ void embed_kernel(const float* __restrict__ x, const float* __restrict__ w,
                             const float* __restrict__ bias, float* __restrict__ h,
                             u16* __restrict__ h16){
  int t = blockIdx.x;          // token 0..8191
  int tid = threadIdx.x;       // 0..255
  __shared__ float xs[64];
  if (tid < 64) xs[tid] = x[(size_t)t*64 + tid];
  __syncthreads();
  float acc0 = bias[tid];
  float acc1 = bias[tid + 256];
  #pragma unroll 8
  for (int k = 0; k < 64; ++k){
    float xv = xs[k];
    acc0 += xv * w[k*512 + tid];
    acc1 += xv * w[k*512 + tid + 256];
  }
  int s = t & (S_LEN - 1);
  const float neg_ln1e4_over_D = -9.210340371976184f / 512.f;
  int c0 = tid, c1 = tid + 256;
  float a0 = (float)s * expf((float)(c0 & ~1) * neg_ln1e4_over_D);
  float p0 = (c0 & 1) ? cosf(a0) : sinf(a0);
  float a1 = (float)s * expf((float)(c1 & ~1) * neg_ln1e4_over_D);
  float p1 = (c1 & 1) ? cosf(a1) : sinf(a1);
  float v0 = acc0 + p0, v1 = acc1 + p1;
  h[(size_t)t*512 + c0] = v0;  h16[(size_t)t*512 + c0] = f2b(v0);
  h[(size_t)t*512 + c1] = v1;  h16[(size_t)t*512 + c1] = f2b(v1);
}

// ---------------- bf16 MFMA GEMM: C = A[M,lda] @ Bt[N,ldb]^T + bias ----------------
// 128x128 tile, BK=64, 4 waves, 4x4 16x16x32 MFMA per wave. global_load_lds
// staging; XOR chunk swizzle on the GLOBAL side (LDS dst lane-contiguous).
// EPI 0: fp32 Cf[M,N]; EPI 1: relu -> bf16 C16a; EPI 2: fused QKV scatter.
template<int EPI>
__global__ __launch_bounds__(256) void gemm_mfma(
    const u16* __restrict__ A, int lda, const u16* __restrict__ Bt, int ldb,
    const float* __restrict__ bias0, const float* __restrict__ bias1,
    const float* __restrict__ bias2,
    float* __restrict__ Cf, u16* __restrict__ C16a, u16* __restrict__ C16b,
    float* __restrict__ Cv, int M, int N, int Klen){
  __shared__ __align__(16) u16 As[128*64];
  __shared__ __align__(16) u16 Bs[128*64];
  int tid = threadIdx.x;
  int w = tid >> 6, l = tid & 63, quad = l >> 4, m = l & 15;
  int m0 = blockIdx.y*128, n0 = blockIdx.x*128;
  int mh = (w >> 1)*64, nh = (w & 1)*64;
  float4v acc[4][4];
  #pragma unroll
  for (int i = 0; i < 4; ++i)
    #pragma unroll
    for (int j = 0; j < 4; ++j) acc[i][j] = (float4v){0.f,0.f,0.f,0.f};

  for (int kt = 0; kt < Klen; kt += 64){
    #pragma unroll
    for (int c = 0; c < 4; ++c){
      int g = c*256 + tid;
      int row = g >> 3, sc = g & 7, dc = sc ^ (row & 7);
      gload16(A  + (size_t)(m0+row)*lda + kt + dc*8, As + (size_t)g*8);
      gload16(Bt + (size_t)(n0+row)*ldb + kt + dc*8, Bs + (size_t)g*8);
    }
    __syncthreads();
    #pragma unroll
    for (int kk = 0; kk < 2; ++kk){
      short8 af[4], bf[4];
      #pragma unroll
      for (int i = 0; i < 4; ++i){
        int dcx = kk*4 + quad;
        int ra = mh + i*16 + m;
        af[i] = *(const short8*)(As + (size_t)(ra*8 + (dcx ^ (ra & 7)))*8);
        int rb = nh + i*16 + m;
        bf[i] = *(const short8*)(Bs + (size_t)(rb*8 + (dcx ^ (rb & 7)))*8);
      }
      #pragma unroll
      for (int i = 0; i < 4; ++i)
        #pragma unroll
        for (int j = 0; j < 4; ++j)
          acc[i][j] = __builtin_amdgcn_mfma_f32_16x16x32_bf16(af[i], bf[j], acc[i][j], 0, 0, 0);
    }
    __syncthreads();
  }

  // C/D layout: row_local = quad*4+r, col_local = m
  #pragma unroll
  for (int i = 0; i < 4; ++i){
    #pragma unroll
    for (int j = 0; j < 4; ++j){
      int col = n0 + nh + j*16 + m;
      #pragma unroll
      for (int r = 0; r < 4; ++r){
        int row = m0 + mh + i*16 + quad*4 + r;
        float v = acc[i][j][r];
        if (EPI == 0){
          Cf[(size_t)row*N + col] = v + bias0[col];
        } else if (EPI == 1){
          C16a[(size_t)row*N + col] = f2b(fmaxf(v + bias0[col], 0.f));
        } else {
          int sel = col >> 9, n5 = col & 511;
          const float* bp = (sel == 0) ? bias0 : (sel == 1) ? bias1 : bias2;
          float vv = v + bp[n5];
          int d = n5 & 63, hh = n5 >> 6;
          int b = row >> 11, s = row & 2047;
          size_t idx = (((size_t)(b*8 + hh))*2048 + s)*64 + d;
          if (sel == 0)      C16a[idx] = f2b(vv);
          else if (sel == 1) C16b[idx] = f2b(vv);
          else               Cv[idx]  = vv;
        }
      }
    }
  }
}

// ---------------- fused MFMA scores + top-35 + softmax + P@V[:35] ----------------
// Selection strategy (replaces per-lane bitonic-32 + 35-round extract merge):
//   1. per-lane packed top-2 of its 32 keys
//   2. bitonic sort-128 of top-2s -> T' = 35th largest (valid prune bound:
//      any x < T' has >=35 distinct elements above it)
//   3. compact candidates (>= T', either query half) to LDS, capacity 128
//   4. bitonic sort-128 of candidates -> ranks 0..34 live in lanes 0..34
//   5. softmax computed once per rank (35 lanes), weights broadcast via LDS
__global__ __launch_bounds__(512) void attn_mfma_topk(
    const u16* __restrict__ qb16, const u16* __restrict__ kb16,
    const float* __restrict__ vb, u16* __restrict__ aob16){
  __shared__ unsigned pr[8*2048];   // 64 KB
  int tid  = threadIdx.x;
  int w    = tid >> 6, l = tid & 63;
  int quad = l >> 4,  m = l & 15;
  int bh = blockIdx.y;
  int q0 = blockIdx.x * 16;

  const u16* Qp = qb16 + ((size_t)bh*2048 + q0 + m)*64 + quad*8;
  short8 a0 = *(const short8*)Qp;
  short8 a1 = *(const short8*)(Qp + 32);

  const u16* Kbase = kb16 + (size_t)bh*2048*64;
  for (int kt = 0; kt < 16; ++kt){
    int k0 = w*256 + kt*16;
    const u16* Kp = Kbase + (size_t)(k0 + m)*64 + quad*8;
    short8 b0 = *(const short8*)Kp;
    short8 b1 = *(const short8*)(Kp + 32);
    float4v acc = {0.f, 0.f, 0.f, 0.f};
    acc = __builtin_amdgcn_mfma_f32_16x16x32_bf16(a0, b0, acc, 0, 0, 0);
    acc = __builtin_amdgcn_mfma_f32_16x16x32_bf16(a1, b1, acc, 0, 0, 0);
    #pragma unroll
    for (int c = 0; c < 2; ++c){
      unsigned lo = key_of(acc[2*c]);
      unsigned hi = key_of(acc[2*c+1]);
      pr[(quad*2 + c)*2048 + k0 + m] = lo | (hi << 16);
    }
  }
  __syncthreads();

  unsigned* row = &pr[w*2048];   // pair row w: queries 2w, 2w+1 (wave-private now)

  unsigned sc[32];
  const uint4* p4 = (const uint4*)row;
  #pragma unroll
  for (int j = 0; j < 8; ++j){
    uint4 v4 = p4[j*64 + l];
    sc[j*4+0] = v4.x; sc[j*4+1] = v4.y; sc[j*4+2] = v4.z; sc[j*4+3] = v4.w;
  }

  // ---- per-lane packed top-2 ----
  unsigned m1 = pkmax(sc[0], sc[1]);
  unsigned m2 = pkmin(sc[0], sc[1]);
  #pragma unroll
  for (int i = 2; i < 32; ++i){
    unsigned v = sc[i];
    unsigned nm1 = pkmax(m1, v);
    m2 = pkmax(m2, pkmin(m1, v));
    m1 = nm1;
  }

  // ---- T' = 35th largest of the 128 top-2 values (per query half) ----
  unsigned s0 = m1, s1 = m2;
  bsort128(s0, s1, l);
  unsigned Tp  = (unsigned)__shfl((int)s0, 34, 64);   // packed thresholds
  unsigned Tm1 = Tp - 0x00010001u;                    // per-half minus 1 (keys >= 0x0080)

  // ---- survivor mask: slot survives iff (A >= T'A) || (B >= T'B) ----
  unsigned mask = 0;
  #pragma unroll
  for (int i = 0; i < 32; ++i){
    mask |= (pkmax(sc[i], Tm1) != Tm1) ? (1u << i) : 0u;
  }
  int cnt = __popc(mask);

  // exclusive prefix over lanes
  int pre = cnt;
  #pragma unroll
  for (int off = 1; off < 64; off <<= 1){
    int n = __shfl_up(pre, off, 64);
    if (l >= off) pre += n;
  }
  pre -= cnt;

  // compact survivors into LDS (wave-private row; capacity 128)
  #pragma unroll
  for (int i = 0; i < 32; ++i){
    if (mask & (1u << i)){
      int p = pre++;
      if (p < 128) row[p] = sc[i];
    }
  }
  int tot = __shfl(pre, 63, 64);   // total candidate count

  // read back, pad with 0 (key 0 < any real key)
  unsigned c0 = (l < tot)      ? row[l]      : 0u;
  unsigned c1 = (64 + l < tot) ? row[64 + l] : 0u;

  // V rows 0..34 (loads overlap with the sort below)
  const float* Vb = vb + (size_t)bh*2048*64 + l;   // lane = d
  float vreg[TOPK];
  #pragma unroll
  for (int r = 0; r < TOPK; ++r) vreg[r] = Vb[(size_t)r*64];

  // ---- final sort: ranks 0..34 end up in c0, lanes 0..34 ----
  bsort128(c0, c1, l);

  // ---- softmax weights, computed once per rank ----
  unsigned top0 = (unsigned)__shfl((int)c0, 0, 64);
  float mAf = key_to_f(top0 & 0xFFFFu) * 0.125f;
  float mBf = key_to_f(top0 >> 16)     * 0.125f;
  float tvA = key_to_f(c0 & 0xFFFFu)   * 0.125f;
  float tvB = key_to_f(c0 >> 16)       * 0.125f;
  float wAv = (l < TOPK) ? __expf(tvA - mAf) : 0.f;
  float wBv = (l < TOPK) ? __expf(tvB - mBf) : 0.f;

  float dA = wAv, dB = wBv;
  #pragma unroll
  for (int off = 32; off > 0; off >>= 1){
    dA += __shfl_xor(dA, off, 64);
    dB += __shfl_xor(dB, off, 64);
  }

  float2* wls = (float2*)(row + 128);   // 280 B scratch within wave's row
  if (l < TOPK) wls[l] = make_float2(wAv, wBv);

  float accA = 0.f, accB = 0.f;
  #pragma unroll
  for (int r = 0; r < TOPK; ++r){
    float2 wv = wls[r];
    float vv = vreg[r];
    accA += wv.x * vv;
    accB += wv.y * vv;
  }
  accA *= __builtin_amdgcn_rcpf(dA);
  accB *= __builtin_amdgcn_rcpf(dB);

  int b = bh >> 3, hh = bh & 7;
  int sA = q0 + w*2;
  aob16[(((size_t)(b*2048 + sA))*8 + hh)*64 + l]     = f2b(accA);
  aob16[(((size_t)(b*2048 + sA + 1))*8 + hh)*64 + l] = f2b(accB);
}

// ---------------- h = LayerNorm(h + t) * g + b, in place; also bf16 copy ----------------
__global__ void resid_ln_kernel(float* __restrict__ h, const float* __restrict__ t,
                                const float* __restrict__ g, const float* __restrict__ b,
                                u16* __restrict__ h16){
  int tok = blockIdx.x;
  int tid = threadIdx.x;        // 256 threads, 2 elems each
  size_t base = (size_t)tok * 512;
  float x0 = h[base + tid]       + t[base + tid];
  float x1 = h[base + tid + 256] + t[base + tid + 256];
  __shared__ float red[8];
  int wid = tid >> 6, lane = tid & 63;

  float s = x0 + x1;
  #pragma unroll
  for (int off = 32; off > 0; off >>= 1) s += __shfl_xor(s, off, 64);
  if (lane == 0) red[wid] = s;
  __syncthreads();
  float mean = (red[0] + red[1] + red[2] + red[3]) * (1.f/512.f);

  float d0 = x0 - mean, d1 = x1 - mean;
  float sq = d0*d0 + d1*d1;
  #pragma unroll
  for (int off = 32; off > 0; off >>= 1) sq += __shfl_xor(sq, off, 64);
  if (lane == 0) red[4 + wid] = sq;
  __syncthreads();
  float var = (red[4] + red[5] + red[6] + red[7]) * (1.f/512.f);
  float inv = rsqrtf(var + 1e-5f);
  float o0 = d0 * inv * g[tid]       + b[tid];
  float o1 = d1 * inv * g[tid + 256] + b[tid + 256];
  h[base + tid]         = o0;  h16[base + tid]       = f2b(o0);
  h[base + tid + 256]   = o1;  h16[base + tid + 256] = f2b(o1);
}

// ---------------- mean over sequence: parallel partial sums + atomicAdd ----------------
__global__ void pool_zero(float* __restrict__ pooled){
  pooled[blockIdx.x*512 + threadIdx.x] = 0.f;   // grid 4, block 512
}
__global__ void pool_kernel(const float* __restrict__ h, float* __restrict__ pooled){
  int c = blockIdx.x * 256 + threadIdx.x;   // 0..511
  int b = blockIdx.y;
  int s0 = blockIdx.z * 64;
  const float* p = h + ((size_t)b * 2048 + s0) * 512 + c;
  float acc = 0.f;
  #pragma unroll 8
  for (int s = 0; s < 64; ++s) acc += p[(size_t)s * 512];
  atomicAdd(&pooled[b*512 + c], acc * (1.f/2048.f));
}

// ---------------- tiny decoder ----------------
__global__ void decoder_kernel(const float* __restrict__ pooled,
                               const float* __restrict__ w1, const float* __restrict__ b1,
                               const float* __restrict__ w2, const float* __restrict__ b2,
                               float* __restrict__ out){
  __shared__ float ps[4][512];
  __shared__ float hid[4][256];
  int tid = threadIdx.x;
  for (int i = tid; i < 2048; i += 256) ps[i >> 9][i & 511] = pooled[i];
  __syncthreads();
  float bb = b1[tid];
  for (int b = 0; b < 4; ++b){
    float acc = bb;
    for (int k = 0; k < 512; ++k) acc += ps[b][k] * w1[k*256 + tid];
    hid[b][tid] = fmaxf(acc, 0.f);
  }
  __syncthreads();
  if (tid < 8){
    int b = tid >> 1, c = tid & 1;
    float acc = b2[c];
    for (int j = 0; j < 256; ++j) acc += hid[b][j] * w2[j*2 + c];
    out[b*2 + c] = acc;
  }
}

extern "C" void kernel_launch(void* const* d_in, const int* in_sizes, int n_in,
                              void* d_out, int out_size, void* d_ws, size_t ws_size,
                              hipStream_t stream){
  const float* x     = (const float*)d_in[0];
  const float* emb_w = (const float*)d_in[1];
  const float* emb_b = (const float*)d_in[2];
  const float* wq    = (const float*)d_in[3];
  const float* bq    = (const float*)d_in[4];
  const float* wk    = (const float*)d_in[5];
  const float* bk    = (const float*)d_in[6];
  const float* wv    = (const float*)d_in[7];
  const float* bv    = (const float*)d_in[8];
  const float* wo    = (const float*)d_in[9];
  const float* bo    = (const float*)d_in[10];
  const float* ff1w  = (const float*)d_in[11];
  const float* ff1b  = (const float*)d_in[12];
  const float* ff2w  = (const float*)d_in[13];
  const float* ff2b  = (const float*)d_in[14];
  const float* ln1g  = (const float*)d_in[15];
  const float* ln1b  = (const float*)d_in[16];
  const float* ln2g  = (const float*)d_in[17];
  const float* ln2b  = (const float*)d_in[18];
  const float* d1w   = (const float*)d_in[19];
  const float* d1b   = (const float*)d_in[20];
  const float* d2w   = (const float*)d_in[21];
  const float* d2b   = (const float*)d_in[22];

  // ---- workspace layout (~92 MB) ----
  float* h      = (float*)d_ws;
  float* tmp    = h + NT512;
  u16*   u      = (u16*)(tmp + NT512);
  u16*   h16    = u;
  u16*   q16    = u + NT512;
  u16*   k16    = u + 2*NT512;
  float* vb     = (float*)(u + 3*NT512);
  u16*   ff16   = q16;                 // 32 MB overlay of q16+k16+vb
  u16*   aob16  = (u16*)(vb + NT512);
  u16*   wt     = aob16 + NT512;
  u16*   wt_qkv = wt;                          // 2 x 1536*512
  u16*   wt_wo  = wt_qkv + (size_t)2*1536*512; // 2 x 512*512
  u16*   wt_ff1 = wt_wo  + (size_t)2*512*512;  // 2 x 2048*512
  u16*   wt_ff2 = wt_ff1 + (size_t)2*2048*512; // 2 x 512*2048
  float* pooled = (float*)(wt_ff2 + (size_t)2*512*2048);

  WtArgs wa{wq, wk, wv, wo, ff1w, ff2w, wt_qkv, wt_wo, wt_ff1, wt_ff2};
  convert_all<<<dim3(3072, 2), dim3(32, 8), 0, stream>>>(wa);

  embed_kernel<<<NTOK, 256, 0, stream>>>(x, emb_w, emb_b, h, h16);

  for (int l = 0; l < 2; ++l){
    // fused QKV: N=1536, scatter epilogue
    gemm_mfma<2><<<dim3(12, 64), 256, 0, stream>>>(
        h16, 512, wt_qkv + (size_t)l*1536*512, 512,
        bq + l*512, bk + l*512, bv + l*512,
        nullptr, q16, k16, vb, NTOK, 1536, 512);

    attn_mfma_topk<<<dim3(128, 32), 512, 0, stream>>>(q16, k16, vb, aob16);

    gemm_mfma<0><<<dim3(4, 64), 256, 0, stream>>>(
        aob16, 512, wt_wo + (size_t)l*512*512, 512,
        bo + l*512, nullptr, nullptr,
        tmp, nullptr, nullptr, nullptr, NTOK, 512, 512);
    resid_ln_kernel<<<NTOK, 256, 0, stream>>>(h, tmp, ln1g + l*512, ln1b + l*512, h16);

    gemm_mfma<1><<<dim3(16, 64), 256, 0, stream>>>(
        h16, 512, wt_ff1 + (size_t)l*2048*512, 512,
        ff1b + l*2048, nullptr, nullptr,
        nullptr, ff16, nullptr, nullptr, NTOK, 2048, 512);

    gemm_mfma<0><<<dim3(4, 64), 256, 0, stream>>>(
        ff16, 2048, wt_ff2 + (size_t)l*512*2048, 2048,
        ff2b + l*512, nullptr, nullptr,
        tmp, nullptr, nullptr, nullptr, NTOK, 512, 2048);
    resid_ln_kernel<<<NTOK, 256, 0, stream>>>(h, tmp, ln2g + l*512, ln2b + l*512, h16);
  }

  pool_zero<<<4, 512, 0, stream>>>(pooled);
  pool_kernel<<<dim3(2, 4, 32), 256, 0, stream>>>(h, pooled);
  decoder_kernel<<<1, 256, 0, stream>>>(pooled, d1w, d1b, d2w, d2b, (float*)d_out);
}

// Round 2
// 750.015 us; speedup vs baseline: 1.1833x; 1.0404x over previous
//
#include <hip/hip_runtime.h>
#include <cmath>

typedef unsigned short u16;
typedef __attribute__((ext_vector_type(8))) short short8;
typedef __attribute__((ext_vector_type(4))) float float4v;
typedef unsigned short ushort2v __attribute__((ext_vector_type(2)));

#define S_LEN 2048
#define NTOK  8192   // B*S
#define TOPK  35
#define NT512 ((size_t)NTOK*512)

__device__ __forceinline__ u16 f2b(float f){
  unsigned int x = __float_as_uint(f);
  unsigned int r = (x + 0x7fffu + ((x >> 16) & 1u)) >> 16;
  return (u16)r;
}
__device__ __forceinline__ float b2f(u16 u){
  return __uint_as_float(((unsigned int)u) << 16);
}

// bf16(f) -> monotone-increasing u16 sort key (no NaNs assumed)
__device__ __forceinline__ unsigned key_of(float f){
  unsigned u = (unsigned)f2b(f);
  unsigned m = (u & 0x8000u) ? 0xFFFFu : 0x8000u;
  return (u ^ m) & 0xFFFFu;
}
__device__ __forceinline__ float key_to_f(unsigned key){
  unsigned m = (key & 0x8000u) ? 0x8000u : 0xFFFFu;
  return __uint_as_float(((key ^ m) & 0xFFFFu) << 16);
}
__device__ __forceinline__ unsigned pkmax(unsigned a, unsigned b){
  union { unsigned u; ushort2v v; } x, y, r;
  x.u = a; y.u = b;
  r.v = __builtin_elementwise_max(x.v, y.v);
  return r.u;
}
__device__ __forceinline__ unsigned pkmin(unsigned a, unsigned b){
  union { unsigned u; ushort2v v; } x, y, r;
  x.u = a; y.u = b;
  r.v = __builtin_elementwise_min(x.v, y.v);
  return r.u;
}

// full bitonic sort, DESCENDING, of 128 packed-u16x2 values distributed
// 2 per lane: element e = l (v0) and e = 64+l (v1). Sorts both u16 halves
// independently (pk ops are per-half).
__device__ __forceinline__ void bsort128(unsigned &v0, unsigned &v1, int l){
  #pragma unroll
  for (int k = 2; k <= 128; k <<= 1){
    #pragma unroll
    for (int j = k >> 1; j > 0; j >>= 1){
      if (j == 64){
        // local CE between e=l and e=64+l (k==128 only): lower keeps max
        unsigned hi = pkmax(v0, v1), lo = pkmin(v0, v1);
        v0 = hi; v1 = lo;
      } else {
        unsigned o0 = (unsigned)__shfl_xor((int)v0, j, 64);
        unsigned o1 = (unsigned)__shfl_xor((int)v1, j, 64);
        // keep_max(e) = ((e&k)==0) XOR ((e&j)!=0)
        bool up0 = (((l & k) == 0) != ((l & j) != 0));
        bool up1 = ((((64 + l) & k) == 0) != ((l & j) != 0));
        unsigned hi0 = pkmax(v0, o0), lo0 = pkmin(v0, o0);
        unsigned hi1 = pkmax(v1, o1), lo1 = pkmin(v1, o1);
        v0 = up0 ? hi0 : lo0;
        v1 = up1 ? hi1 : lo1;
      }
    }
  }
}

// async global->LDS 16B direct copy; LDS dest pattern = wave-uniform base + lane*16
__device__ __forceinline__ void gload16(const void* g, void* l){
  __builtin_amdgcn_global_load_lds(
      (const __attribute__((address_space(1))) unsigned int*)g,
      (__attribute__((address_space(3))) unsigned int*)l, 16, 0, 0);
}

// ---------------- fused weight transpose + bf16 convert (all 12 weights) ----------------
// 32x32 tiles; blockIdx.y = layer, blockIdx.x = flat tile id across 6 segments.
struct WtArgs {
  const float* wq; const float* wk; const float* wv; const float* wo;
  const float* ff1w; const float* ff2w;
  u16* wt_qkv; u16* wt_wo; u16* wt_ff1; u16* wt_ff2;
};
__global__ void convert_all(WtArgs a){
  __shared__ u16 t[32][33];
  int l = blockIdx.y;
  int tt = blockIdx.x;
  const float* W; u16* Wt; int K, N, tx_, ty_;
  if (tt < 1024){                 // qkv (3 segs) + wo, all 512x512, 16x16 tiles
    int seg = tt >> 8, r = tt & 255;
    tx_ = r & 15; ty_ = r >> 4; K = 512; N = 512;
    if (seg == 0){ W = a.wq + (size_t)l*262144; Wt = a.wt_qkv + (size_t)l*786432; }
    else if (seg == 1){ W = a.wk + (size_t)l*262144; Wt = a.wt_qkv + (size_t)l*786432 + 262144; }
    else if (seg == 2){ W = a.wv + (size_t)l*262144; Wt = a.wt_qkv + (size_t)l*786432 + 524288; }
    else { W = a.wo + (size_t)l*262144; Wt = a.wt_wo + (size_t)l*262144; }
  } else if (tt < 2048){          // ff1: K=512, N=2048 -> tiles 64 x 16
    int r = tt - 1024;
    tx_ = r & 63; ty_ = r >> 6; K = 512; N = 2048;
    W = a.ff1w + (size_t)l*1048576; Wt = a.wt_ff1 + (size_t)l*1048576;
  } else {                        // ff2: K=2048, N=512 -> tiles 16 x 64
    int r = tt - 2048;
    tx_ = r & 15; ty_ = r >> 4; K = 2048; N = 512;
    W = a.ff2w + (size_t)l*1048576; Wt = a.wt_ff2 + (size_t)l*1048576;
  }
  int k0 = ty_*32, n0 = tx_*32;
  int tx = threadIdx.x, ty = threadIdx.y;   // 32x8
  #pragma unroll
  for (int i = ty; i < 32; i += 8)
    t[i][tx] = f2b(W[(size_t)(k0+i)*N + n0+tx]);
  __syncthreads();
  #pragma unroll
  for (int i = ty; i < 32; i += 8)
    Wt[(size_t)(n0+i)*K + k0+tx] = t[tx][i];
}

// ---------------- embedding + sinusoidal PE (writes fp32 h + bf16 h16) ----------------
__global__ void embed_kernel(const float* __restrict__ x, const float* __restrict__ w,
                             const float* __restrict__ bias, float* __restrict__ h,
                             u16* __restrict__ h16){
  int t = blockIdx.x;          // token 0..8191
  int tid = threadIdx.x;       // 0..255
  __shared__ float xs[64];
  if (tid < 64) xs[tid] = x[(size_t)t*64 + tid];
  __syncthreads();
  float acc0 = bias[tid];
  float acc1 = bias[tid + 256];
  #pragma unroll 8
  for (int k = 0; k < 64; ++k){
    float xv = xs[k];
    acc0 += xv * w[k*512 + tid];
    acc1 += xv * w[k*512 + tid + 256];
  }
  int s = t & (S_LEN - 1);
  const float neg_ln1e4_over_D = -9.210340371976184f / 512.f;
  int c0 = tid, c1 = tid + 256;
  float a0 = (float)s * expf((float)(c0 & ~1) * neg_ln1e4_over_D);
  float p0 = (c0 & 1) ? cosf(a0) : sinf(a0);
  float a1 = (float)s * expf((float)(c1 & ~1) * neg_ln1e4_over_D);
  float p1 = (c1 & 1) ? cosf(a1) : sinf(a1);
  float v0 = acc0 + p0, v1 = acc1 + p1;
  h[(size_t)t*512 + c0] = v0;  h16[(size_t)t*512 + c0] = f2b(v0);
  h[(size_t)t*512 + c1] = v1;  h16[(size_t)t*512 + c1] = f2b(v1);
}

// ---------------- bf16 MFMA GEMM: C = A[M,lda] @ Bt[N,ldb]^T + bias ----------------
// 128x128 tile, BK=64, 4 waves, 4x4 16x16x32 MFMA per wave. global_load_lds
// staging; XOR chunk swizzle on the GLOBAL side (LDS dst lane-contiguous).
// EPI 0: fp32 Cf[M,N]; EPI 1: relu -> bf16 C16a; EPI 2: fused QKV scatter.
template<int EPI>
__global__ __launch_bounds__(256) void gemm_mfma(
    const u16* __restrict__ A, int lda, const u16* __restrict__ Bt, int ldb,
    const float* __restrict__ bias0, const float* __restrict__ bias1,
    const float* __restrict__ bias2,
    float* __restrict__ Cf, u16* __restrict__ C16a, u16* __restrict__ C16b,
    float* __restrict__ Cv, int M, int N, int Klen){
  __shared__ __align__(16) u16 As[128*64];
  __shared__ __align__(16) u16 Bs[128*64];
  int tid = threadIdx.x;
  int w = tid >> 6, l = tid & 63, quad = l >> 4, m = l & 15;
  int m0 = blockIdx.y*128, n0 = blockIdx.x*128;
  int mh = (w >> 1)*64, nh = (w & 1)*64;
  float4v acc[4][4];
  #pragma unroll
  for (int i = 0; i < 4; ++i)
    #pragma unroll
    for (int j = 0; j < 4; ++j) acc[i][j] = (float4v){0.f,0.f,0.f,0.f};

  for (int kt = 0; kt < Klen; kt += 64){
    #pragma unroll
    for (int c = 0; c < 4; ++c){
      int g = c*256 + tid;
      int row = g >> 3, sc = g & 7, dc = sc ^ (row & 7);
      gload16(A  + (size_t)(m0+row)*lda + kt + dc*8, As + (size_t)g*8);
      gload16(Bt + (size_t)(n0+row)*ldb + kt + dc*8, Bs + (size_t)g*8);
    }
    __syncthreads();
    #pragma unroll
    for (int kk = 0; kk < 2; ++kk){
      short8 af[4], bf[4];
      #pragma unroll
      for (int i = 0; i < 4; ++i){
        int dcx = kk*4 + quad;
        int ra = mh + i*16 + m;
        af[i] = *(const short8*)(As + (size_t)(ra*8 + (dcx ^ (ra & 7)))*8);
        int rb = nh + i*16 + m;
        bf[i] = *(const short8*)(Bs + (size_t)(rb*8 + (dcx ^ (rb & 7)))*8);
      }
      #pragma unroll
      for (int i = 0; i < 4; ++i)
        #pragma unroll
        for (int j = 0; j < 4; ++j)
          acc[i][j] = __builtin_amdgcn_mfma_f32_16x16x32_bf16(af[i], bf[j], acc[i][j], 0, 0, 0);
    }
    __syncthreads();
  }

  // C/D layout: row_local = quad*4+r, col_local = m
  #pragma unroll
  for (int i = 0; i < 4; ++i){
    #pragma unroll
    for (int j = 0; j < 4; ++j){
      int col = n0 + nh + j*16 + m;
      #pragma unroll
      for (int r = 0; r < 4; ++r){
        int row = m0 + mh + i*16 + quad*4 + r;
        float v = acc[i][j][r];
        if (EPI == 0){
          Cf[(size_t)row*N + col] = v + bias0[col];
        } else if (EPI == 1){
          C16a[(size_t)row*N + col] = f2b(fmaxf(v + bias0[col], 0.f));
        } else {
          int sel = col >> 9, n5 = col & 511;
          const float* bp = (sel == 0) ? bias0 : (sel == 1) ? bias1 : bias2;
          float vv = v + bp[n5];
          int d = n5 & 63, hh = n5 >> 6;
          int b = row >> 11, s = row & 2047;
          size_t idx = (((size_t)(b*8 + hh))*2048 + s)*64 + d;
          if (sel == 0)      C16a[idx] = f2b(vv);
          else if (sel == 1) C16b[idx] = f2b(vv);
          else               Cv[idx]  = vv;
        }
      }
    }
  }
}

// ---------------- fused MFMA scores + top-35 + softmax + P@V[:35] ----------------
// Selection strategy:
//   1. per-lane packed top-2 of its 32 keys
//   2. bitonic sort-128 of top-2s -> T' = 35th largest (valid prune bound)
//   3. compact candidates (>= T') to LDS, capacity 128
//   4. bitonic sort-128 of candidates -> ranks 0..34 live in lanes 0..34
//   5. softmax once per rank, weights broadcast via LDS
// LDS: score buffer split into TWO 1024-key half-passes reusing 32 KiB
// (8 rows x 1024 packed pairs) -> 4 blocks/CU instead of 2.
// Score writes XOR-swizzled by (quad&1)<<4: per-row bijection (top-k is
// permutation-invariant; indices discarded), turns 4-way bank conflict
// into free 2-way.
__global__ __launch_bounds__(512, 8) void attn_mfma_topk(
    const u16* __restrict__ qb16, const u16* __restrict__ kb16,
    const float* __restrict__ vb, u16* __restrict__ aob16){
  __shared__ unsigned pr[8*1024];   // 32 KB
  int tid  = threadIdx.x;
  int w    = tid >> 6, l = tid & 63;
  int quad = l >> 4,  m = l & 15;
  int bh = blockIdx.y;
  int q0 = blockIdx.x * 16;

  const u16* Qp = qb16 + ((size_t)bh*2048 + q0 + m)*64 + quad*8;
  short8 a0 = *(const short8*)Qp;
  short8 a1 = *(const short8*)(Qp + 32);

  const u16* Kbase = kb16 + (size_t)bh*2048*64;
  unsigned sc[32];
  int swz = (quad & 1) << 4;
  #pragma unroll
  for (int hlf = 0; hlf < 2; ++hlf){
    #pragma unroll
    for (int kt = 0; kt < 8; ++kt){
      int lk = w*128 + kt*16;                       // local key idx in half
      const u16* Kp = Kbase + (size_t)(hlf*1024 + lk + m)*64 + quad*8;
      short8 b0 = *(const short8*)Kp;
      short8 b1 = *(const short8*)(Kp + 32);
      float4v acc = {0.f, 0.f, 0.f, 0.f};
      acc = __builtin_amdgcn_mfma_f32_16x16x32_bf16(a0, b0, acc, 0, 0, 0);
      acc = __builtin_amdgcn_mfma_f32_16x16x32_bf16(a1, b1, acc, 0, 0, 0);
      #pragma unroll
      for (int c = 0; c < 2; ++c){
        unsigned lo = key_of(acc[2*c]);
        unsigned hi = key_of(acc[2*c+1]);
        pr[(quad*2 + c)*1024 + ((lk + m) ^ swz)] = lo | (hi << 16);
      }
    }
    __syncthreads();
    const uint4* p4 = (const uint4*)(pr + w*1024);
    #pragma unroll
    for (int j = 0; j < 4; ++j){
      uint4 v4 = p4[j*64 + l];
      sc[hlf*16 + j*4+0] = v4.x; sc[hlf*16 + j*4+1] = v4.y;
      sc[hlf*16 + j*4+2] = v4.z; sc[hlf*16 + j*4+3] = v4.w;
    }
    if (hlf == 0) __syncthreads();   // reads done before next half overwrites
  }

  unsigned* row = &pr[w*1024];   // wave-private scratch from here on

  // ---- per-lane packed top-2 ----
  unsigned m1 = pkmax(sc[0], sc[1]);
  unsigned m2 = pkmin(sc[0], sc[1]);
  #pragma unroll
  for (int i = 2; i < 32; ++i){
    unsigned v = sc[i];
    unsigned nm1 = pkmax(m1, v);
    m2 = pkmax(m2, pkmin(m1, v));
    m1 = nm1;
  }

  // ---- T' = 35th largest of the 128 top-2 values (per query half) ----
  unsigned s0 = m1, s1 = m2;
  bsort128(s0, s1, l);
  unsigned Tp  = (unsigned)__shfl((int)s0, 34, 64);   // packed thresholds
  unsigned Tm1 = Tp - 0x00010001u;                    // per-half minus 1 (keys >= 0x0080)

  // ---- survivor mask: slot survives iff (A >= T'A) || (B >= T'B) ----
  unsigned mask = 0;
  #pragma unroll
  for (int i = 0; i < 32; ++i){
    mask |= (pkmax(sc[i], Tm1) != Tm1) ? (1u << i) : 0u;
  }
  int cnt = __popc(mask);

  // exclusive prefix over lanes
  int pre = cnt;
  #pragma unroll
  for (int off = 1; off < 64; off <<= 1){
    int n = __shfl_up(pre, off, 64);
    if (l >= off) pre += n;
  }
  pre -= cnt;

  // compact survivors into LDS (wave-private row; capacity 128)
  #pragma unroll
  for (int i = 0; i < 32; ++i){
    if (mask & (1u << i)){
      int p = pre++;
      if (p < 128) row[p] = sc[i];
    }
  }
  int tot = __shfl(pre, 63, 64);   // total candidate count

  // read back, pad with 0 (key 0 < any real key)
  unsigned c0 = (l < tot)      ? row[l]      : 0u;
  unsigned c1 = (64 + l < tot) ? row[64 + l] : 0u;

  // V rows 0..34 (loads overlap with the sort below)
  const float* Vb = vb + (size_t)bh*2048*64 + l;   // lane = d
  float vreg[TOPK];
  #pragma unroll
  for (int r = 0; r < TOPK; ++r) vreg[r] = Vb[(size_t)r*64];

  // ---- final sort: ranks 0..34 end up in c0, lanes 0..34 ----
  bsort128(c0, c1, l);

  // ---- softmax weights, computed once per rank ----
  unsigned top0 = (unsigned)__shfl((int)c0, 0, 64);
  float mAf = key_to_f(top0 & 0xFFFFu) * 0.125f;
  float mBf = key_to_f(top0 >> 16)     * 0.125f;
  float tvA = key_to_f(c0 & 0xFFFFu)   * 0.125f;
  float tvB = key_to_f(c0 >> 16)       * 0.125f;
  float wAv = (l < TOPK) ? __expf(tvA - mAf) : 0.f;
  float wBv = (l < TOPK) ? __expf(tvB - mBf) : 0.f;

  float dA = wAv, dB = wBv;
  #pragma unroll
  for (int off = 32; off > 0; off >>= 1){
    dA += __shfl_xor(dA, off, 64);
    dB += __shfl_xor(dB, off, 64);
  }

  float2* wls = (float2*)(row + 128);   // 280 B scratch within wave's row
  if (l < TOPK) wls[l] = make_float2(wAv, wBv);

  float accA = 0.f, accB = 0.f;
  #pragma unroll
  for (int r = 0; r < TOPK; ++r){
    float2 wv = wls[r];
    float vv = vreg[r];
    accA += wv.x * vv;
    accB += wv.y * vv;
  }
  accA *= __builtin_amdgcn_rcpf(dA);
  accB *= __builtin_amdgcn_rcpf(dB);

  int b = bh >> 3, hh = bh & 7;
  int sA = q0 + w*2;
  aob16[(((size_t)(b*2048 + sA))*8 + hh)*64 + l]     = f2b(accA);
  aob16[(((size_t)(b*2048 + sA + 1))*8 + hh)*64 + l] = f2b(accB);
}

// ---------------- h = LayerNorm(h + t) * g + b, in place; also bf16 copy ----------------
__global__ void resid_ln_kernel(float* __restrict__ h, const float* __restrict__ t,
                                const float* __restrict__ g, const float* __restrict__ b,
                                u16* __restrict__ h16){
  int tok = blockIdx.x;
  int tid = threadIdx.x;        // 256 threads, 2 elems each
  size_t base = (size_t)tok * 512;
  float x0 = h[base + tid]       + t[base + tid];
  float x1 = h[base + tid + 256] + t[base + tid + 256];
  __shared__ float red[8];
  int wid = tid >> 6, lane = tid & 63;

  float s = x0 + x1;
  #pragma unroll
  for (int off = 32; off > 0; off >>= 1) s += __shfl_xor(s, off, 64);
  if (lane == 0) red[wid] = s;
  __syncthreads();
  float mean = (red[0] + red[1] + red[2] + red[3]) * (1.f/512.f);

  float d0 = x0 - mean, d1 = x1 - mean;
  float sq = d0*d0 + d1*d1;
  #pragma unroll
  for (int off = 32; off > 0; off >>= 1) sq += __shfl_xor(sq, off, 64);
  if (lane == 0) red[4 + wid] = sq;
  __syncthreads();
  float var = (red[4] + red[5] + red[6] + red[7]) * (1.f/512.f);
  float inv = rsqrtf(var + 1e-5f);
  float o0 = d0 * inv * g[tid]       + b[tid];
  float o1 = d1 * inv * g[tid + 256] + b[tid + 256];
  h[base + tid]         = o0;  h16[base + tid]       = f2b(o0);
  h[base + tid + 256]   = o1;  h16[base + tid + 256] = f2b(o1);
}

// ---------------- mean over sequence: parallel partial sums + atomicAdd ----------------
__global__ void pool_zero(float* __restrict__ pooled){
  pooled[blockIdx.x*512 + threadIdx.x] = 0.f;   // grid 4, block 512
}
__global__ void pool_kernel(const float* __restrict__ h, float* __restrict__ pooled){
  int c = blockIdx.x * 256 + threadIdx.x;   // 0..511
  int b = blockIdx.y;
  int s0 = blockIdx.z * 64;
  const float* p = h + ((size_t)b * 2048 + s0) * 512 + c;
  float acc = 0.f;
  #pragma unroll 8
  for (int s = 0; s < 64; ++s) acc += p[(size_t)s * 512];
  atomicAdd(&pooled[b*512 + c], acc * (1.f/2048.f));
}

// ---------------- tiny decoder ----------------
__global__ void decoder_kernel(const float* __restrict__ pooled,
                               const float* __restrict__ w1, const float* __restrict__ b1,
                               const float* __restrict__ w2, const float* __restrict__ b2,
                               float* __restrict__ out){
  __shared__ float ps[4][512];
  __shared__ float hid[4][256];
  int tid = threadIdx.x;
  for (int i = tid; i < 2048; i += 256) ps[i >> 9][i & 511] = pooled[i];
  __syncthreads();
  float bb = b1[tid];
  for (int b = 0; b < 4; ++b){
    float acc = bb;
    for (int k = 0; k < 512; ++k) acc += ps[b][k] * w1[k*256 + tid];
    hid[b][tid] = fmaxf(acc, 0.f);
  }
  __syncthreads();
  if (tid < 8){
    int b = tid >> 1, c = tid & 1;
    float acc = b2[c];
    for (int j = 0; j < 256; ++j) acc += hid[b][j] * w2[j*2 + c];
    out[b*2 + c] = acc;
  }
}

extern "C" void kernel_launch(void* const* d_in, const int* in_sizes, int n_in,
                              void* d_out, int out_size, void* d_ws, size_t ws_size,
                              hipStream_t stream){
  const float* x     = (const float*)d_in[0];
  const float* emb_w = (const float*)d_in[1];
  const float* emb_b = (const float*)d_in[2];
  const float* wq    = (const float*)d_in[3];
  const float* bq    = (const float*)d_in[4];
  const float* wk    = (const float*)d_in[5];
  const float* bk    = (const float*)d_in[6];
  const float* wv    = (const float*)d_in[7];
  const float* bv    = (const float*)d_in[8];
  const float* wo    = (const float*)d_in[9];
  const float* bo    = (const float*)d_in[10];
  const float* ff1w  = (const float*)d_in[11];
  const float* ff1b  = (const float*)d_in[12];
  const float* ff2w  = (const float*)d_in[13];
  const float* ff2b  = (const float*)d_in[14];
  const float* ln1g  = (const float*)d_in[15];
  const float* ln1b  = (const float*)d_in[16];
  const float* ln2g  = (const float*)d_in[17];
  const float* ln2b  = (const float*)d_in[18];
  const float* d1w   = (const float*)d_in[19];
  const float* d1b   = (const float*)d_in[20];
  const float* d2w   = (const float*)d_in[21];
  const float* d2b   = (const float*)d_in[22];

  // ---- workspace layout (~92 MB) ----
  float* h      = (float*)d_ws;
  float* tmp    = h + NT512;
  u16*   u      = (u16*)(tmp + NT512);
  u16*   h16    = u;
  u16*   q16    = u + NT512;
  u16*   k16    = u + 2*NT512;
  float* vb     = (float*)(u + 3*NT512);
  u16*   ff16   = q16;                 // 32 MB overlay of q16+k16+vb
  u16*   aob16  = (u16*)(vb + NT512);
  u16*   wt     = aob16 + NT512;
  u16*   wt_qkv = wt;                          // 2 x 1536*512
  u16*   wt_wo  = wt_qkv + (size_t)2*1536*512; // 2 x 512*512
  u16*   wt_ff1 = wt_wo  + (size_t)2*512*512;  // 2 x 2048*512
  u16*   wt_ff2 = wt_ff1 + (size_t)2*2048*512; // 2 x 512*2048
  float* pooled = (float*)(wt_ff2 + (size_t)2*512*2048);

  WtArgs wa{wq, wk, wv, wo, ff1w, ff2w, wt_qkv, wt_wo, wt_ff1, wt_ff2};
  convert_all<<<dim3(3072, 2), dim3(32, 8), 0, stream>>>(wa);

  embed_kernel<<<NTOK, 256, 0, stream>>>(x, emb_w, emb_b, h, h16);

  for (int l = 0; l < 2; ++l){
    // fused QKV: N=1536, scatter epilogue
    gemm_mfma<2><<<dim3(12, 64), 256, 0, stream>>>(
        h16, 512, wt_qkv + (size_t)l*1536*512, 512,
        bq + l*512, bk + l*512, bv + l*512,
        nullptr, q16, k16, vb, NTOK, 1536, 512);

    attn_mfma_topk<<<dim3(128, 32), 512, 0, stream>>>(q16, k16, vb, aob16);

    gemm_mfma<0><<<dim3(4, 64), 256, 0, stream>>>(
        aob16, 512, wt_wo + (size_t)l*512*512, 512,
        bo + l*512, nullptr, nullptr,
        tmp, nullptr, nullptr, nullptr, NTOK, 512, 512);
    resid_ln_kernel<<<NTOK, 256, 0, stream>>>(h, tmp, ln1g + l*512, ln1b + l*512, h16);

    gemm_mfma<1><<<dim3(16, 64), 256, 0, stream>>>(
        h16, 512, wt_ff1 + (size_t)l*2048*512, 512,
        ff1b + l*2048, nullptr, nullptr,
        nullptr, ff16, nullptr, nullptr, NTOK, 2048, 512);

    gemm_mfma<0><<<dim3(4, 64), 256, 0, stream>>>(
        ff16, 2048, wt_ff2 + (size_t)l*512*2048, 2048,
        ff2b + l*512, nullptr, nullptr,
        tmp, nullptr, nullptr, nullptr, NTOK, 512, 2048);
    resid_ln_kernel<<<NTOK, 256, 0, stream>>>(h, tmp, ln2g + l*512, ln2b + l*512, h16);
  }

  pool_zero<<<4, 512, 0, stream>>>(pooled);
  pool_kernel<<<dim3(2, 4, 32), 256, 0, stream>>>(h, pooled);
  decoder_kernel<<<1, 256, 0, stream>>>(pooled, d1w, d1b, d2w, d2b, (float*)d_out);
}

// Round 4
// 745.546 us; speedup vs baseline: 1.1904x; 1.0060x over previous
//
#include <hip/hip_runtime.h>
#include <cmath>

typedef unsigned short u16;
typedef __attribute__((ext_vector_type(8))) short short8;
typedef __attribute__((ext_vector_type(4))) float float4v;
typedef unsigned short ushort2v __attribute__((ext_vector_type(2)));

#define S_LEN 2048
#define NTOK  8192   // B*S
#define TOPK  35
#define NT512 ((size_t)NTOK*512)

__device__ __forceinline__ u16 f2b(float f){
  unsigned int x = __float_as_uint(f);
  unsigned int r = (x + 0x7fffu + ((x >> 16) & 1u)) >> 16;
  return (u16)r;
}
__device__ __forceinline__ float b2f(u16 u){
  return __uint_as_float(((unsigned int)u) << 16);
}

// bf16(f) -> monotone-increasing u16 sort key (no NaNs assumed)
__device__ __forceinline__ unsigned key_of(float f){
  unsigned u = (unsigned)f2b(f);
  unsigned m = (u & 0x8000u) ? 0xFFFFu : 0x8000u;
  return (u ^ m) & 0xFFFFu;
}
__device__ __forceinline__ float key_to_f(unsigned key){
  unsigned m = (key & 0x8000u) ? 0x8000u : 0xFFFFu;
  return __uint_as_float(((key ^ m) & 0xFFFFu) << 16);
}
__device__ __forceinline__ unsigned pkmax(unsigned a, unsigned b){
  union { unsigned u; ushort2v v; } x, y, r;
  x.u = a; y.u = b;
  r.v = __builtin_elementwise_max(x.v, y.v);
  return r.u;
}
__device__ __forceinline__ unsigned pkmin(unsigned a, unsigned b){
  union { unsigned u; ushort2v v; } x, y, r;
  x.u = a; y.u = b;
  r.v = __builtin_elementwise_min(x.v, y.v);
  return r.u;
}

// full bitonic sort, DESCENDING, of 128 packed-u16x2 values distributed
// 2 per lane: element e = l (v0) and e = 64+l (v1). Sorts both u16 halves
// independently (pk ops are per-half).
__device__ __forceinline__ void bsort128(unsigned &v0, unsigned &v1, int l){
  #pragma unroll
  for (int k = 2; k <= 128; k <<= 1){
    #pragma unroll
    for (int j = k >> 1; j > 0; j >>= 1){
      if (j == 64){
        unsigned hi = pkmax(v0, v1), lo = pkmin(v0, v1);
        v0 = hi; v1 = lo;
      } else {
        unsigned o0 = (unsigned)__shfl_xor((int)v0, j, 64);
        unsigned o1 = (unsigned)__shfl_xor((int)v1, j, 64);
        bool up0 = (((l & k) == 0) != ((l & j) != 0));
        bool up1 = ((((64 + l) & k) == 0) != ((l & j) != 0));
        unsigned hi0 = pkmax(v0, o0), lo0 = pkmin(v0, o0);
        unsigned hi1 = pkmax(v1, o1), lo1 = pkmin(v1, o1);
        v0 = up0 ? hi0 : lo0;
        v1 = up1 ? hi1 : lo1;
      }
    }
  }
}

// async global->LDS 16B direct copy; LDS dest pattern = wave-uniform base + lane*16
__device__ __forceinline__ void gload16(const void* g, void* l){
  __builtin_amdgcn_global_load_lds(
      (const __attribute__((address_space(1))) unsigned int*)g,
      (__attribute__((address_space(3))) unsigned int*)l, 16, 0, 0);
}

// ---------------- fused weight transpose + bf16 convert (all 12 weights) ----------------
struct WtArgs {
  const float* wq; const float* wk; const float* wv; const float* wo;
  const float* ff1w; const float* ff2w;
  u16* wt_qkv; u16* wt_wo; u16* wt_ff1; u16* wt_ff2;
};
__global__ void convert_all(WtArgs a){
  __shared__ u16 t[32][33];
  int l = blockIdx.y;
  int tt = blockIdx.x;
  const float* W; u16* Wt; int K, N, tx_, ty_;
  if (tt < 1024){                 // qkv (3 segs) + wo, all 512x512, 16x16 tiles
    int seg = tt >> 8, r = tt & 255;
    tx_ = r & 15; ty_ = r >> 4; K = 512; N = 512;
    if (seg == 0){ W = a.wq + (size_t)l*262144; Wt = a.wt_qkv + (size_t)l*786432; }
    else if (seg == 1){ W = a.wk + (size_t)l*262144; Wt = a.wt_qkv + (size_t)l*786432 + 262144; }
    else if (seg == 2){ W = a.wv + (size_t)l*262144; Wt = a.wt_qkv + (size_t)l*786432 + 524288; }
    else { W = a.wo + (size_t)l*262144; Wt = a.wt_wo + (size_t)l*262144; }
  } else if (tt < 2048){          // ff1: K=512, N=2048 -> tiles 64 x 16
    int r = tt - 1024;
    tx_ = r & 63; ty_ = r >> 6; K = 512; N = 2048;
    W = a.ff1w + (size_t)l*1048576; Wt = a.wt_ff1 + (size_t)l*1048576;
  } else {                        // ff2: K=2048, N=512 -> tiles 16 x 64
    int r = tt - 2048;
    tx_ = r & 15; ty_ = r >> 4; K = 2048; N = 512;
    W = a.ff2w + (size_t)l*1048576; Wt = a.wt_ff2 + (size_t)l*1048576;
  }
  int k0 = ty_*32, n0 = tx_*32;
  int tx = threadIdx.x, ty = threadIdx.y;   // 32x8
  #pragma unroll
  for (int i = ty; i < 32; i += 8)
    t[i][tx] = f2b(W[(size_t)(k0+i)*N + n0+tx]);
  __syncthreads();
  #pragma unroll
  for (int i = ty; i < 32; i += 8)
    Wt[(size_t)(n0+i)*K + k0+tx] = t[tx][i];
}

// ---------------- embedding + sinusoidal PE (writes fp32 h + bf16 h16) ----------------
__global__ void embed_kernel(const float* __restrict__ x, const float* __restrict__ w,
                             const float* __restrict__ bias, float* __restrict__ h,
                             u16* __restrict__ h16){
  int t = blockIdx.x;          // token 0..8191
  int tid = threadIdx.x;       // 0..255
  __shared__ float xs[64];
  if (tid < 64) xs[tid] = x[(size_t)t*64 + tid];
  __syncthreads();
  float acc0 = bias[tid];
  float acc1 = bias[tid + 256];
  #pragma unroll 8
  for (int k = 0; k < 64; ++k){
    float xv = xs[k];
    acc0 += xv * w[k*512 + tid];
    acc1 += xv * w[k*512 + tid + 256];
  }
  int s = t & (S_LEN - 1);
  const float neg_ln1e4_over_D = -9.210340371976184f / 512.f;
  int c0 = tid, c1 = tid + 256;
  float a0 = (float)s * expf((float)(c0 & ~1) * neg_ln1e4_over_D);
  float p0 = (c0 & 1) ? cosf(a0) : sinf(a0);
  float a1 = (float)s * expf((float)(c1 & ~1) * neg_ln1e4_over_D);
  float p1 = (c1 & 1) ? cosf(a1) : sinf(a1);
  float v0 = acc0 + p0, v1 = acc1 + p1;
  h[(size_t)t*512 + c0] = v0;  h16[(size_t)t*512 + c0] = f2b(v0);
  h[(size_t)t*512 + c1] = v1;  h16[(size_t)t*512 + c1] = f2b(v1);
}

// ---------------- bf16 MFMA GEMM: C = A[M,lda] @ Bt[N,ldb]^T + bias ----------------
template<int EPI>
__global__ __launch_bounds__(256) void gemm_mfma(
    const u16* __restrict__ A, int lda, const u16* __restrict__ Bt, int ldb,
    const float* __restrict__ bias0, const float* __restrict__ bias1,
    const float* __restrict__ bias2,
    float* __restrict__ Cf, u16* __restrict__ C16a, u16* __restrict__ C16b,
    float* __restrict__ Cv, int M, int N, int Klen){
  __shared__ __align__(16) u16 As[128*64];
  __shared__ __align__(16) u16 Bs[128*64];
  int tid = threadIdx.x;
  int w = tid >> 6, l = tid & 63, quad = l >> 4, m = l & 15;
  int m0 = blockIdx.y*128, n0 = blockIdx.x*128;
  int mh = (w >> 1)*64, nh = (w & 1)*64;
  float4v acc[4][4];
  #pragma unroll
  for (int i = 0; i < 4; ++i)
    #pragma unroll
    for (int j = 0; j < 4; ++j) acc[i][j] = (float4v){0.f,0.f,0.f,0.f};

  for (int kt = 0; kt < Klen; kt += 64){
    #pragma unroll
    for (int c = 0; c < 4; ++c){
      int g = c*256 + tid;
      int row = g >> 3, sc = g & 7, dc = sc ^ (row & 7);
      gload16(A  + (size_t)(m0+row)*lda + kt + dc*8, As + (size_t)g*8);
      gload16(Bt + (size_t)(n0+row)*ldb + kt + dc*8, Bs + (size_t)g*8);
    }
    __syncthreads();
    #pragma unroll
    for (int kk = 0; kk < 2; ++kk){
      short8 af[4], bf[4];
      #pragma unroll
      for (int i = 0; i < 4; ++i){
        int dcx = kk*4 + quad;
        int ra = mh + i*16 + m;
        af[i] = *(const short8*)(As + (size_t)(ra*8 + (dcx ^ (ra & 7)))*8);
        int rb = nh + i*16 + m;
        bf[i] = *(const short8*)(Bs + (size_t)(rb*8 + (dcx ^ (rb & 7)))*8);
      }
      #pragma unroll
      for (int i = 0; i < 4; ++i)
        #pragma unroll
        for (int j = 0; j < 4; ++j)
          acc[i][j] = __builtin_amdgcn_mfma_f32_16x16x32_bf16(af[i], bf[j], acc[i][j], 0, 0, 0);
    }
    __syncthreads();
  }

  // C/D layout: row_local = quad*4+r, col_local = m
  #pragma unroll
  for (int i = 0; i < 4; ++i){
    #pragma unroll
    for (int j = 0; j < 4; ++j){
      int col = n0 + nh + j*16 + m;
      #pragma unroll
      for (int r = 0; r < 4; ++r){
        int row = m0 + mh + i*16 + quad*4 + r;
        float v = acc[i][j][r];
        if (EPI == 0){
          Cf[(size_t)row*N + col] = v + bias0[col];
        } else if (EPI == 1){
          C16a[(size_t)row*N + col] = f2b(fmaxf(v + bias0[col], 0.f));
        } else {
          int sel = col >> 9, n5 = col & 511;
          const float* bp = (sel == 0) ? bias0 : (sel == 1) ? bias1 : bias2;
          float vv = v + bp[n5];
          int d = n5 & 63, hh = n5 >> 6;
          int b = row >> 11, s = row & 2047;
          size_t idx = (((size_t)(b*8 + hh))*2048 + s)*64 + d;
          if (sel == 0)      C16a[idx] = f2b(vv);
          else if (sel == 1) C16b[idx] = f2b(vv);
          else               Cv[idx]  = vv;
        }
      }
    }
  }
}

// ---------------- fused MFMA scores + top-35 + softmax + P@V[:35] ----------------
// Selection:
//   1. per-lane packed top-2 of its 32 keys
//   2. T' (rank-35 of the 128 top-2 values, per query) via 16-step binary
//      search on the u16 key space using ballot+popcount — 0 DS ops,
//      exactly equal to the rank-34 element of a descending sort
//   3. compact candidates (>= T') to LDS, capacity 128
//   4. bitonic sort-128 of candidates -> ranks 0..34 live in lanes 0..34
//   5. softmax once per rank, weights broadcast via LDS
// Score keys use f2b (RNE) — verified good; v_cvt_pk_bf16_f32 variant broke
// correctness in R3 (suspected lo/hi pack-order swap), reverted.
__global__ __launch_bounds__(512, 8) void attn_mfma_topk(
    const u16* __restrict__ qb16, const u16* __restrict__ kb16,
    const float* __restrict__ vb, u16* __restrict__ aob16){
  __shared__ unsigned pr[8*1024];   // 32 KB
  int tid  = threadIdx.x;
  int w    = tid >> 6, l = tid & 63;
  int quad = l >> 4,  m = l & 15;
  int bh = blockIdx.y;
  int q0 = blockIdx.x * 16;

  const u16* Qp = qb16 + ((size_t)bh*2048 + q0 + m)*64 + quad*8;
  short8 a0 = *(const short8*)Qp;
  short8 a1 = *(const short8*)(Qp + 32);

  const u16* Kbase = kb16 + (size_t)bh*2048*64;
  unsigned sc[32];
  int swz = (quad & 1) << 4;
  #pragma unroll
  for (int hlf = 0; hlf < 2; ++hlf){
    #pragma unroll
    for (int kt = 0; kt < 8; ++kt){
      int lk = w*128 + kt*16;                       // local key idx in half
      const u16* Kp = Kbase + (size_t)(hlf*1024 + lk + m)*64 + quad*8;
      short8 b0 = *(const short8*)Kp;
      short8 b1 = *(const short8*)(Kp + 32);
      float4v acc = {0.f, 0.f, 0.f, 0.f};
      acc = __builtin_amdgcn_mfma_f32_16x16x32_bf16(a0, b0, acc, 0, 0, 0);
      acc = __builtin_amdgcn_mfma_f32_16x16x32_bf16(a1, b1, acc, 0, 0, 0);
      #pragma unroll
      for (int c = 0; c < 2; ++c){
        unsigned lo = key_of(acc[2*c]);
        unsigned hi = key_of(acc[2*c+1]);
        pr[(quad*2 + c)*1024 + ((lk + m) ^ swz)] = lo | (hi << 16);
      }
    }
    __syncthreads();
    const uint4* p4 = (const uint4*)(pr + w*1024);
    #pragma unroll
    for (int j = 0; j < 4; ++j){
      uint4 v4 = p4[j*64 + l];
      sc[hlf*16 + j*4+0] = v4.x; sc[hlf*16 + j*4+1] = v4.y;
      sc[hlf*16 + j*4+2] = v4.z; sc[hlf*16 + j*4+3] = v4.w;
    }
    if (hlf == 0) __syncthreads();   // reads done before next half overwrites
  }

  unsigned* row = &pr[w*1024];   // wave-private scratch from here on

  // ---- per-lane packed top-2 ----
  unsigned m1 = pkmax(sc[0], sc[1]);
  unsigned m2 = pkmin(sc[0], sc[1]);
  #pragma unroll
  for (int i = 2; i < 32; ++i){
    unsigned v = sc[i];
    unsigned nm1 = pkmax(m1, v);
    m2 = pkmax(m2, pkmin(m1, v));
    m1 = nm1;
  }

  // ---- T' via binary search on key space (rank-35 of the 128 top-2s) ----
  unsigned mA1 = m1 & 0xFFFFu, mB1 = m1 >> 16;
  unsigned mA2 = m2 & 0xFFFFu, mB2 = m2 >> 16;
  unsigned tA = 0, tB = 0;
  #pragma unroll
  for (int bit = 15; bit >= 0; --bit){
    unsigned cA = tA | (1u << bit);
    unsigned cB = tB | (1u << bit);
    int nA = __popcll(__ballot(mA1 >= cA)) + __popcll(__ballot(mA2 >= cA));
    int nB = __popcll(__ballot(mB1 >= cB)) + __popcll(__ballot(mB2 >= cB));
    if (nA >= TOPK) tA = cA;
    if (nB >= TOPK) tB = cB;
  }
  unsigned TT = (tA - 1) | ((tB - 1) << 16);   // per-half threshold-minus-1

  // ---- survivor mask: slot survives iff (A >= tA) || (B >= tB) ----
  unsigned mask = 0;
  #pragma unroll
  for (int i = 0; i < 32; ++i){
    mask |= (pkmax(sc[i], TT) != TT) ? (1u << i) : 0u;
  }
  int cnt = __popc(mask);

  // exclusive prefix over lanes
  int pre = cnt;
  #pragma unroll
  for (int off = 1; off < 64; off <<= 1){
    int n = __shfl_up(pre, off, 64);
    if (l >= off) pre += n;
  }
  pre -= cnt;

  // compact survivors into LDS (wave-private row; capacity 128)
  #pragma unroll
  for (int i = 0; i < 32; ++i){
    if (mask & (1u << i)){
      int p = pre++;
      if (p < 128) row[p] = sc[i];
    }
  }
  int tot = __shfl(pre, 63, 64);   // total candidate count

  // read back, pad with 0 (key 0 < any real key)
  unsigned c0 = (l < tot)      ? row[l]      : 0u;
  unsigned c1 = (64 + l < tot) ? row[64 + l] : 0u;

  // V rows 0..34 (loads overlap with the sort below)
  const float* Vb = vb + (size_t)bh*2048*64 + l;   // lane = d
  float vreg[TOPK];
  #pragma unroll
  for (int r = 0; r < TOPK; ++r) vreg[r] = Vb[(size_t)r*64];

  // ---- final sort: ranks 0..34 end up in c0, lanes 0..34 ----
  bsort128(c0, c1, l);

  // ---- softmax weights, computed once per rank ----
  unsigned top0 = (unsigned)__shfl((int)c0, 0, 64);
  float mAf = key_to_f(top0 & 0xFFFFu) * 0.125f;
  float mBf = key_to_f(top0 >> 16)     * 0.125f;
  float tvA = key_to_f(c0 & 0xFFFFu)   * 0.125f;
  float tvB = key_to_f(c0 >> 16)       * 0.125f;
  float wAv = (l < TOPK) ? __expf(tvA - mAf) : 0.f;
  float wBv = (l < TOPK) ? __expf(tvB - mBf) : 0.f;

  float dA = wAv, dB = wBv;
  #pragma unroll
  for (int off = 32; off > 0; off >>= 1){
    dA += __shfl_xor(dA, off, 64);
    dB += __shfl_xor(dB, off, 64);
  }

  float2* wls = (float2*)(row + 128);   // 280 B scratch within wave's row
  if (l < TOPK) wls[l] = make_float2(wAv, wBv);

  float accA = 0.f, accB = 0.f;
  #pragma unroll
  for (int r = 0; r < TOPK; ++r){
    float2 wv = wls[r];
    float vv = vreg[r];
    accA += wv.x * vv;
    accB += wv.y * vv;
  }
  accA *= __builtin_amdgcn_rcpf(dA);
  accB *= __builtin_amdgcn_rcpf(dB);

  int b = bh >> 3, hh = bh & 7;
  int sA = q0 + w*2;
  aob16[(((size_t)(b*2048 + sA))*8 + hh)*64 + l]     = f2b(accA);
  aob16[(((size_t)(b*2048 + sA + 1))*8 + hh)*64 + l] = f2b(accB);
}

// ---------------- h = LayerNorm(h + t) * g + b, in place; also bf16 copy ----------------
__global__ void resid_ln_kernel(float* __restrict__ h, const float* __restrict__ t,
                                const float* __restrict__ g, const float* __restrict__ b,
                                u16* __restrict__ h16){
  int tok = blockIdx.x;
  int tid = threadIdx.x;        // 256 threads, 2 elems each
  size_t base = (size_t)tok * 512;
  float x0 = h[base + tid]       + t[base + tid];
  float x1 = h[base + tid + 256] + t[base + tid + 256];
  __shared__ float red[8];
  int wid = tid >> 6, lane = tid & 63;

  float s = x0 + x1;
  #pragma unroll
  for (int off = 32; off > 0; off >>= 1) s += __shfl_xor(s, off, 64);
  if (lane == 0) red[wid] = s;
  __syncthreads();
  float mean = (red[0] + red[1] + red[2] + red[3]) * (1.f/512.f);

  float d0 = x0 - mean, d1 = x1 - mean;
  float sq = d0*d0 + d1*d1;
  #pragma unroll
  for (int off = 32; off > 0; off >>= 1) sq += __shfl_xor(sq, off, 64);
  if (lane == 0) red[4 + wid] = sq;
  __syncthreads();
  float var = (red[4] + red[5] + red[6] + red[7]) * (1.f/512.f);
  float inv = rsqrtf(var + 1e-5f);
  float o0 = d0 * inv * g[tid]       + b[tid];
  float o1 = d1 * inv * g[tid + 256] + b[tid + 256];
  h[base + tid]         = o0;  h16[base + tid]       = f2b(o0);
  h[base + tid + 256]   = o1;  h16[base + tid + 256] = f2b(o1);
}

// ---------------- mean over sequence: parallel partial sums + atomicAdd ----------------
__global__ void pool_zero(float* __restrict__ pooled){
  pooled[blockIdx.x*512 + threadIdx.x] = 0.f;   // grid 4, block 512
}
__global__ void pool_kernel(const float* __restrict__ h, float* __restrict__ pooled){
  int c = blockIdx.x * 256 + threadIdx.x;   // 0..511
  int b = blockIdx.y;
  int s0 = blockIdx.z * 64;
  const float* p = h + ((size_t)b * 2048 + s0) * 512 + c;
  float acc = 0.f;
  #pragma unroll 8
  for (int s = 0; s < 64; ++s) acc += p[(size_t)s * 512];
  atomicAdd(&pooled[b*512 + c], acc * (1.f/2048.f));
}

// ---------------- tiny decoder ----------------
__global__ void decoder_kernel(const float* __restrict__ pooled,
                               const float* __restrict__ w1, const float* __restrict__ b1,
                               const float* __restrict__ w2, const float* __restrict__ b2,
                               float* __restrict__ out){
  __shared__ float ps[4][512];
  __shared__ float hid[4][256];
  int tid = threadIdx.x;
  for (int i = tid; i < 2048; i += 256) ps[i >> 9][i & 511] = pooled[i];
  __syncthreads();
  float bb = b1[tid];
  for (int b = 0; b < 4; ++b){
    float acc = bb;
    for (int k = 0; k < 512; ++k) acc += ps[b][k] * w1[k*256 + tid];
    hid[b][tid] = fmaxf(acc, 0.f);
  }
  __syncthreads();
  if (tid < 8){
    int b = tid >> 1, c = tid & 1;
    float acc = b2[c];
    for (int j = 0; j < 256; ++j) acc += hid[b][j] * w2[j*2 + c];
    out[b*2 + c] = acc;
  }
}

extern "C" void kernel_launch(void* const* d_in, const int* in_sizes, int n_in,
                              void* d_out, int out_size, void* d_ws, size_t ws_size,
                              hipStream_t stream){
  const float* x     = (const float*)d_in[0];
  const float* emb_w = (const float*)d_in[1];
  const float* emb_b = (const float*)d_in[2];
  const float* wq    = (const float*)d_in[3];
  const float* bq    = (const float*)d_in[4];
  const float* wk    = (const float*)d_in[5];
  const float* bk    = (const float*)d_in[6];
  const float* wv    = (const float*)d_in[7];
  const float* bv    = (const float*)d_in[8];
  const float* wo    = (const float*)d_in[9];
  const float* bo    = (const float*)d_in[10];
  const float* ff1w  = (const float*)d_in[11];
  const float* ff1b  = (const float*)d_in[12];
  const float* ff2w  = (const float*)d_in[13];
  const float* ff2b  = (const float*)d_in[14];
  const float* ln1g  = (const float*)d_in[15];
  const float* ln1b  = (const float*)d_in[16];
  const float* ln2g  = (const float*)d_in[17];
  const float* ln2b  = (const float*)d_in[18];
  const float* d1w   = (const float*)d_in[19];
  const float* d1b   = (const float*)d_in[20];
  const float* d2w   = (const float*)d_in[21];
  const float* d2b   = (const float*)d_in[22];

  // ---- workspace layout (~92 MB) ----
  float* h      = (float*)d_ws;
  float* tmp    = h + NT512;
  u16*   u      = (u16*)(tmp + NT512);
  u16*   h16    = u;
  u16*   q16    = u + NT512;
  u16*   k16    = u + 2*NT512;
  float* vb     = (float*)(u + 3*NT512);
  u16*   ff16   = q16;                 // 32 MB overlay of q16+k16+vb
  u16*   aob16  = (u16*)(vb + NT512);
  u16*   wt     = aob16 + NT512;
  u16*   wt_qkv = wt;                          // 2 x 1536*512
  u16*   wt_wo  = wt_qkv + (size_t)2*1536*512; // 2 x 512*512
  u16*   wt_ff1 = wt_wo  + (size_t)2*512*512;  // 2 x 2048*512
  u16*   wt_ff2 = wt_ff1 + (size_t)2*2048*512; // 2 x 512*2048
  float* pooled = (float*)(wt_ff2 + (size_t)2*512*2048);

  WtArgs wa{wq, wk, wv, wo, ff1w, ff2w, wt_qkv, wt_wo, wt_ff1, wt_ff2};
  convert_all<<<dim3(3072, 2), dim3(32, 8), 0, stream>>>(wa);

  embed_kernel<<<NTOK, 256, 0, stream>>>(x, emb_w, emb_b, h, h16);

  for (int l = 0; l < 2; ++l){
    // fused QKV: N=1536, scatter epilogue
    gemm_mfma<2><<<dim3(12, 64), 256, 0, stream>>>(
        h16, 512, wt_qkv + (size_t)l*1536*512, 512,
        bq + l*512, bk + l*512, bv + l*512,
        nullptr, q16, k16, vb, NTOK, 1536, 512);

    attn_mfma_topk<<<dim3(128, 32), 512, 0, stream>>>(q16, k16, vb, aob16);

    gemm_mfma<0><<<dim3(4, 64), 256, 0, stream>>>(
        aob16, 512, wt_wo + (size_t)l*512*512, 512,
        bo + l*512, nullptr, nullptr,
        tmp, nullptr, nullptr, nullptr, NTOK, 512, 512);
    resid_ln_kernel<<<NTOK, 256, 0, stream>>>(h, tmp, ln1g + l*512, ln1b + l*512, h16);

    gemm_mfma<1><<<dim3(16, 64), 256, 0, stream>>>(
        h16, 512, wt_ff1 + (size_t)l*2048*512, 512,
        ff1b + l*2048, nullptr, nullptr,
        nullptr, ff16, nullptr, nullptr, NTOK, 2048, 512);

    gemm_mfma<0><<<dim3(4, 64), 256, 0, stream>>>(
        ff16, 2048, wt_ff2 + (size_t)l*512*2048, 2048,
        ff2b + l*512, nullptr, nullptr,
        tmp, nullptr, nullptr, nullptr, NTOK, 512, 2048);
    resid_ln_kernel<<<NTOK, 256, 0, stream>>>(h, tmp, ln2g + l*512, ln2b + l*512, h16);
  }

  pool_zero<<<4, 512, 0, stream>>>(pooled);
  pool_kernel<<<dim3(2, 4, 32), 256, 0, stream>>>(h, pooled);
  decoder_kernel<<<1, 256, 0, stream>>>(pooled, d1w, d1b, d2w, d2b, (float*)d_out);
}

// Round 5
// 724.572 us; speedup vs baseline: 1.2248x; 1.0289x over previous
//
#include <hip/hip_runtime.h>
#include <cmath>

typedef unsigned short u16;
typedef __attribute__((ext_vector_type(8))) short short8;
typedef __attribute__((ext_vector_type(4))) float float4v;
typedef unsigned short ushort2v __attribute__((ext_vector_type(2)));

#define S_LEN 2048
#define NTOK  8192   // B*S
#define TOPK  35
#define NT512 ((size_t)NTOK*512)

__device__ __forceinline__ u16 f2b(float f){
  unsigned int x = __float_as_uint(f);
  unsigned int r = (x + 0x7fffu + ((x >> 16) & 1u)) >> 16;
  return (u16)r;
}
__device__ __forceinline__ float b2f(u16 u){
  return __uint_as_float(((unsigned int)u) << 16);
}

// bf16(f) -> monotone-increasing u16 sort key (no NaNs assumed)
__device__ __forceinline__ unsigned key_of(float f){
  unsigned u = (unsigned)f2b(f);
  unsigned m = (u & 0x8000u) ? 0xFFFFu : 0x8000u;
  return (u ^ m) & 0xFFFFu;
}
__device__ __forceinline__ float key_to_f(unsigned key){
  unsigned m = (key & 0x8000u) ? 0x8000u : 0xFFFFu;
  return __uint_as_float(((key ^ m) & 0xFFFFu) << 16);
}
__device__ __forceinline__ unsigned pkmax(unsigned a, unsigned b){
  union { unsigned u; ushort2v v; } x, y, r;
  x.u = a; y.u = b;
  r.v = __builtin_elementwise_max(x.v, y.v);
  return r.u;
}
__device__ __forceinline__ unsigned pkmin(unsigned a, unsigned b){
  union { unsigned u; ushort2v v; } x, y, r;
  x.u = a; y.u = b;
  r.v = __builtin_elementwise_min(x.v, y.v);
  return r.u;
}

// full bitonic sort, DESCENDING, of 128 packed-u16x2 values distributed
// 2 per lane: element e = l (v0) and e = 64+l (v1). Sorts both u16 halves
// independently (pk ops are per-half).
__device__ __forceinline__ void bsort128(unsigned &v0, unsigned &v1, int l){
  #pragma unroll
  for (int k = 2; k <= 128; k <<= 1){
    #pragma unroll
    for (int j = k >> 1; j > 0; j >>= 1){
      if (j == 64){
        unsigned hi = pkmax(v0, v1), lo = pkmin(v0, v1);
        v0 = hi; v1 = lo;
      } else {
        unsigned o0 = (unsigned)__shfl_xor((int)v0, j, 64);
        unsigned o1 = (unsigned)__shfl_xor((int)v1, j, 64);
        bool up0 = (((l & k) == 0) != ((l & j) != 0));
        bool up1 = ((((64 + l) & k) == 0) != ((l & j) != 0));
        unsigned hi0 = pkmax(v0, o0), lo0 = pkmin(v0, o0);
        unsigned hi1 = pkmax(v1, o1), lo1 = pkmin(v1, o1);
        v0 = up0 ? hi0 : lo0;
        v1 = up1 ? hi1 : lo1;
      }
    }
  }
}

// async global->LDS 16B direct copy; LDS dest pattern = wave-uniform base + lane*16
__device__ __forceinline__ void gload16(const void* g, void* l){
  __builtin_amdgcn_global_load_lds(
      (const __attribute__((address_space(1))) unsigned int*)g,
      (__attribute__((address_space(3))) unsigned int*)l, 16, 0, 0);
}

// ---------------- fused weight transpose + bf16 convert (all 12 weights) ----------------
struct WtArgs {
  const float* wq; const float* wk; const float* wv; const float* wo;
  const float* ff1w; const float* ff2w;
  u16* wt_qkv; u16* wt_wo; u16* wt_ff1; u16* wt_ff2;
};
__global__ void convert_all(WtArgs a){
  __shared__ u16 t[32][33];
  int l = blockIdx.y;
  int tt = blockIdx.x;
  const float* W; u16* Wt; int K, N, tx_, ty_;
  if (tt < 1024){                 // qkv (3 segs) + wo, all 512x512, 16x16 tiles
    int seg = tt >> 8, r = tt & 255;
    tx_ = r & 15; ty_ = r >> 4; K = 512; N = 512;
    if (seg == 0){ W = a.wq + (size_t)l*262144; Wt = a.wt_qkv + (size_t)l*786432; }
    else if (seg == 1){ W = a.wk + (size_t)l*262144; Wt = a.wt_qkv + (size_t)l*786432 + 262144; }
    else if (seg == 2){ W = a.wv + (size_t)l*262144; Wt = a.wt_qkv + (size_t)l*786432 + 524288; }
    else { W = a.wo + (size_t)l*262144; Wt = a.wt_wo + (size_t)l*262144; }
  } else if (tt < 2048){          // ff1: K=512, N=2048 -> tiles 64 x 16
    int r = tt - 1024;
    tx_ = r & 63; ty_ = r >> 6; K = 512; N = 2048;
    W = a.ff1w + (size_t)l*1048576; Wt = a.wt_ff1 + (size_t)l*1048576;
  } else {                        // ff2: K=2048, N=512 -> tiles 16 x 64
    int r = tt - 2048;
    tx_ = r & 15; ty_ = r >> 4; K = 2048; N = 512;
    W = a.ff2w + (size_t)l*1048576; Wt = a.wt_ff2 + (size_t)l*1048576;
  }
  int k0 = ty_*32, n0 = tx_*32;
  int tx = threadIdx.x, ty = threadIdx.y;   // 32x8
  #pragma unroll
  for (int i = ty; i < 32; i += 8)
    t[i][tx] = f2b(W[(size_t)(k0+i)*N + n0+tx]);
  __syncthreads();
  #pragma unroll
  for (int i = ty; i < 32; i += 8)
    Wt[(size_t)(n0+i)*K + k0+tx] = t[tx][i];
}

// ---------------- embedding + sinusoidal PE (writes fp32 h + bf16 h16) ----------------
__global__ void embed_kernel(const float* __restrict__ x, const float* __restrict__ w,
                             const float* __restrict__ bias, float* __restrict__ h,
                             u16* __restrict__ h16){
  int t = blockIdx.x;          // token 0..8191
  int tid = threadIdx.x;       // 0..255
  __shared__ float xs[64];
  if (tid < 64) xs[tid] = x[(size_t)t*64 + tid];
  __syncthreads();
  float acc0 = bias[tid];
  float acc1 = bias[tid + 256];
  #pragma unroll 8
  for (int k = 0; k < 64; ++k){
    float xv = xs[k];
    acc0 += xv * w[k*512 + tid];
    acc1 += xv * w[k*512 + tid + 256];
  }
  int s = t & (S_LEN - 1);
  const float neg_ln1e4_over_D = -9.210340371976184f / 512.f;
  int c0 = tid, c1 = tid + 256;
  float a0 = (float)s * expf((float)(c0 & ~1) * neg_ln1e4_over_D);
  float p0 = (c0 & 1) ? cosf(a0) : sinf(a0);
  float a1 = (float)s * expf((float)(c1 & ~1) * neg_ln1e4_over_D);
  float p1 = (c1 & 1) ? cosf(a1) : sinf(a1);
  float v0 = acc0 + p0, v1 = acc1 + p1;
  h[(size_t)t*512 + c0] = v0;  h16[(size_t)t*512 + c0] = f2b(v0);
  h[(size_t)t*512 + c1] = v1;  h16[(size_t)t*512 + c1] = f2b(v1);
}

// ---------------- bf16 MFMA GEMM: C = A[M,lda] @ Bt[N,ldb]^T + bias ----------------
// XCD-aware bijective tile swizzle (all grids have nwg%8==0): consecutive
// tiles (sharing an A-panel) land on the same XCD's L2.
template<int EPI>
__global__ __launch_bounds__(256) void gemm_mfma(
    const u16* __restrict__ A, int lda, const u16* __restrict__ Bt, int ldb,
    const float* __restrict__ bias0, const float* __restrict__ bias1,
    const float* __restrict__ bias2,
    float* __restrict__ Cf, u16* __restrict__ C16a, u16* __restrict__ C16b,
    float* __restrict__ Cv, int M, int N, int Klen){
  __shared__ __align__(16) u16 As[128*64];
  __shared__ __align__(16) u16 Bs[128*64];
  int tid = threadIdx.x;
  int w = tid >> 6, l = tid & 63, quad = l >> 4, m = l & 15;
  int gx = gridDim.x;
  int orig = blockIdx.y * gx + blockIdx.x;
  int nwg  = gx * gridDim.y;
  int tt   = (orig & 7) * (nwg >> 3) + (orig >> 3);
  int m0 = (tt / gx) * 128, n0 = (tt % gx) * 128;
  int mh = (w >> 1)*64, nh = (w & 1)*64;
  float4v acc[4][4];
  #pragma unroll
  for (int i = 0; i < 4; ++i)
    #pragma unroll
    for (int j = 0; j < 4; ++j) acc[i][j] = (float4v){0.f,0.f,0.f,0.f};

  for (int kt = 0; kt < Klen; kt += 64){
    #pragma unroll
    for (int c = 0; c < 4; ++c){
      int g = c*256 + tid;
      int row = g >> 3, sc = g & 7, dc = sc ^ (row & 7);
      gload16(A  + (size_t)(m0+row)*lda + kt + dc*8, As + (size_t)g*8);
      gload16(Bt + (size_t)(n0+row)*ldb + kt + dc*8, Bs + (size_t)g*8);
    }
    __syncthreads();
    #pragma unroll
    for (int kk = 0; kk < 2; ++kk){
      short8 af[4], bf[4];
      #pragma unroll
      for (int i = 0; i < 4; ++i){
        int dcx = kk*4 + quad;
        int ra = mh + i*16 + m;
        af[i] = *(const short8*)(As + (size_t)(ra*8 + (dcx ^ (ra & 7)))*8);
        int rb = nh + i*16 + m;
        bf[i] = *(const short8*)(Bs + (size_t)(rb*8 + (dcx ^ (rb & 7)))*8);
      }
      #pragma unroll
      for (int i = 0; i < 4; ++i)
        #pragma unroll
        for (int j = 0; j < 4; ++j)
          acc[i][j] = __builtin_amdgcn_mfma_f32_16x16x32_bf16(af[i], bf[j], acc[i][j], 0, 0, 0);
    }
    __syncthreads();
  }

  // C/D layout: row_local = quad*4+r, col_local = m
  #pragma unroll
  for (int i = 0; i < 4; ++i){
    #pragma unroll
    for (int j = 0; j < 4; ++j){
      int col = n0 + nh + j*16 + m;
      #pragma unroll
      for (int r = 0; r < 4; ++r){
        int row = m0 + mh + i*16 + quad*4 + r;
        float v = acc[i][j][r];
        if (EPI == 0){
          Cf[(size_t)row*N + col] = v + bias0[col];
        } else if (EPI == 1){
          C16a[(size_t)row*N + col] = f2b(fmaxf(v + bias0[col], 0.f));
        } else {
          int sel = col >> 9, n5 = col & 511;
          const float* bp = (sel == 0) ? bias0 : (sel == 1) ? bias1 : bias2;
          float vv = v + bp[n5];
          int d = n5 & 63, hh = n5 >> 6;
          int b = row >> 11, s = row & 2047;
          size_t idx = (((size_t)(b*8 + hh))*2048 + s)*64 + d;
          if (sel == 0)      C16a[idx] = f2b(vv);
          else if (sel == 1) C16b[idx] = f2b(vv);
          else               Cv[idx]  = vv;
        }
      }
    }
  }
}

// ---------------- fused MFMA scores + top-35 + softmax + P@V[:35] ----------------
// Selection:
//   1. per-lane packed top-2 of its 32 keys
//   2. T' (rank-35 of the 128 top-2 values, per query) via 16-step binary
//      search on the u16 key space using ballot+popcount
//   3. compact candidates (>= T') to LDS, capacity 128 (de-chained index)
//   4. bitonic sort-128 of candidates -> ranks 0..34 live in lanes 0..34
//   5. softmax once per rank, weights broadcast via LDS
// Score phase: depth-2 software-pipelined K loads (prefetch crosses the
// half-boundary barrier; loads fly during the LDS readback).
// XCD-aware block swizzle: consecutive q-tiles of one bh share an XCD L2.
__global__ __launch_bounds__(512, 8) void attn_mfma_topk(
    const u16* __restrict__ qb16, const u16* __restrict__ kb16,
    const float* __restrict__ vb, u16* __restrict__ aob16){
  __shared__ unsigned pr[8*1024];   // 32 KB
  int tid  = threadIdx.x;
  int w    = tid >> 6, l = tid & 63;
  int quad = l >> 4,  m = l & 15;
  // bijective XCD swizzle over 4096 blocks (128 x 32)
  int orig = blockIdx.y * 128 + blockIdx.x;
  int t4   = ((orig & 7) << 9) | (orig >> 3);
  int bh   = t4 >> 7;
  int q0   = (t4 & 127) << 4;

  const u16* Qp = qb16 + ((size_t)bh*2048 + q0 + m)*64 + quad*8;
  short8 a0 = *(const short8*)Qp;
  short8 a1 = *(const short8*)(Qp + 32);

  const u16* Kbase = kb16 + (size_t)bh*2048*64;
  unsigned sc[32];
  int swz = (quad & 1) << 4;
  const u16* kp0 = Kbase + (size_t)(w*128 + m)*64 + quad*8;
  // tile t (0..15): row offset = (t>>3)*1024 + (t&7)*16
  const uint4* p4 = (const uint4*)(pr + w*1024);

  short8 cb0 = *(const short8*)kp0;
  short8 cb1 = *(const short8*)(kp0 + 32);
  #pragma unroll
  for (int t = 0; t < 16; ++t){
    short8 nb0, nb1;
    if (t < 15){
      int tn = t + 1;
      const u16* np = kp0 + (size_t)(((tn >> 3) << 10) + ((tn & 7) << 4))*64;
      nb0 = *(const short8*)np;
      nb1 = *(const short8*)(np + 32);
    }
    float4v acc = {0.f, 0.f, 0.f, 0.f};
    acc = __builtin_amdgcn_mfma_f32_16x16x32_bf16(a0, cb0, acc, 0, 0, 0);
    acc = __builtin_amdgcn_mfma_f32_16x16x32_bf16(a1, cb1, acc, 0, 0, 0);
    int lk = (w << 7) + ((t & 7) << 4);
    #pragma unroll
    for (int c = 0; c < 2; ++c){
      unsigned lo = key_of(acc[2*c]);
      unsigned hi = key_of(acc[2*c+1]);
      pr[(quad*2 + c)*1024 + ((lk + m) ^ swz)] = lo | (hi << 16);
    }
    cb0 = nb0; cb1 = nb1;
    if (t == 7){
      __syncthreads();
      #pragma unroll
      for (int j = 0; j < 4; ++j){
        uint4 v4 = p4[j*64 + l];
        sc[j*4+0] = v4.x; sc[j*4+1] = v4.y; sc[j*4+2] = v4.z; sc[j*4+3] = v4.w;
      }
      __syncthreads();
    }
  }
  __syncthreads();
  #pragma unroll
  for (int j = 0; j < 4; ++j){
    uint4 v4 = p4[j*64 + l];
    sc[16+j*4+0] = v4.x; sc[16+j*4+1] = v4.y; sc[16+j*4+2] = v4.z; sc[16+j*4+3] = v4.w;
  }

  unsigned* row = &pr[w*1024];   // wave-private scratch from here on

  // ---- per-lane packed top-2 ----
  unsigned m1 = pkmax(sc[0], sc[1]);
  unsigned m2 = pkmin(sc[0], sc[1]);
  #pragma unroll
  for (int i = 2; i < 32; ++i){
    unsigned v = sc[i];
    unsigned nm1 = pkmax(m1, v);
    m2 = pkmax(m2, pkmin(m1, v));
    m1 = nm1;
  }

  // ---- T' via binary search on key space (rank-35 of the 128 top-2s) ----
  unsigned mA1 = m1 & 0xFFFFu, mB1 = m1 >> 16;
  unsigned mA2 = m2 & 0xFFFFu, mB2 = m2 >> 16;
  unsigned tA = 0, tB = 0;
  #pragma unroll
  for (int bit = 15; bit >= 0; --bit){
    unsigned cA = tA | (1u << bit);
    unsigned cB = tB | (1u << bit);
    int nA = __popcll(__ballot(mA1 >= cA)) + __popcll(__ballot(mA2 >= cA));
    int nB = __popcll(__ballot(mB1 >= cB)) + __popcll(__ballot(mB2 >= cB));
    if (nA >= TOPK) tA = cA;
    if (nB >= TOPK) tB = cB;
  }
  unsigned TT = (tA - 1) | ((tB - 1) << 16);   // per-half threshold-minus-1

  // ---- survivor mask: slot survives iff (A >= tA) || (B >= tB) ----
  unsigned mask = 0;
  #pragma unroll
  for (int i = 0; i < 32; ++i){
    mask |= (pkmax(sc[i], TT) != TT) ? (1u << i) : 0u;
  }
  int cnt = __popc(mask);

  // exclusive prefix over lanes
  int pre = cnt;
  #pragma unroll
  for (int off = 1; off < 64; off <<= 1){
    int n = __shfl_up(pre, off, 64);
    if (l >= off) pre += n;
  }
  pre -= cnt;

  // compact survivors into LDS (wave-private row; capacity 128).
  // position = pre + popc(lower set bits): no serial dependence.
  #pragma unroll
  for (int i = 0; i < 32; ++i){
    if (mask & (1u << i)){
      int p = pre + __popc(mask & ((1u << i) - 1u));
      if (p < 128) row[p] = sc[i];
    }
  }
  int tot = __shfl(pre + cnt, 63, 64);   // total candidate count

  // read back, pad with 0 (key 0 < any real key)
  unsigned c0 = (l < tot)      ? row[l]      : 0u;
  unsigned c1 = (64 + l < tot) ? row[64 + l] : 0u;

  // V rows 0..34 (loads overlap with the sort below)
  const float* Vb = vb + (size_t)bh*2048*64 + l;   // lane = d
  float vreg[TOPK];
  #pragma unroll
  for (int r = 0; r < TOPK; ++r) vreg[r] = Vb[(size_t)r*64];

  // ---- final sort: ranks 0..34 end up in c0, lanes 0..34 ----
  bsort128(c0, c1, l);

  // ---- softmax weights, computed once per rank ----
  unsigned top0 = (unsigned)__shfl((int)c0, 0, 64);
  float mAf = key_to_f(top0 & 0xFFFFu) * 0.125f;
  float mBf = key_to_f(top0 >> 16)     * 0.125f;
  float tvA = key_to_f(c0 & 0xFFFFu)   * 0.125f;
  float tvB = key_to_f(c0 >> 16)       * 0.125f;
  float wAv = (l < TOPK) ? __expf(tvA - mAf) : 0.f;
  float wBv = (l < TOPK) ? __expf(tvB - mBf) : 0.f;

  float dA = wAv, dB = wBv;
  #pragma unroll
  for (int off = 32; off > 0; off >>= 1){
    dA += __shfl_xor(dA, off, 64);
    dB += __shfl_xor(dB, off, 64);
  }

  float2* wls = (float2*)(row + 128);   // 280 B scratch within wave's row
  if (l < TOPK) wls[l] = make_float2(wAv, wBv);

  float accA = 0.f, accB = 0.f;
  #pragma unroll
  for (int r = 0; r < TOPK; ++r){
    float2 wv = wls[r];
    float vv = vreg[r];
    accA += wv.x * vv;
    accB += wv.y * vv;
  }
  accA *= __builtin_amdgcn_rcpf(dA);
  accB *= __builtin_amdgcn_rcpf(dB);

  int b = bh >> 3, hh = bh & 7;
  int sA = q0 + w*2;
  aob16[(((size_t)(b*2048 + sA))*8 + hh)*64 + l]     = f2b(accA);
  aob16[(((size_t)(b*2048 + sA + 1))*8 + hh)*64 + l] = f2b(accB);
}

// ---------------- h = LayerNorm(h + t) * g + b, in place; also bf16 copy ----------------
// float2-vectorized: thread handles cols 2*tid, 2*tid+1.
__global__ void resid_ln_kernel(float* __restrict__ h, const float* __restrict__ t,
                                const float* __restrict__ g, const float* __restrict__ b,
                                u16* __restrict__ h16){
  int tok = blockIdx.x;
  int tid = threadIdx.x;        // 256 threads, 2 consecutive elems each
  size_t base2 = (size_t)tok * 256;    // float2 units
  float2 hv = ((const float2*)h)[base2 + tid];
  float2 tv = ((const float2*)t)[base2 + tid];
  float x0 = hv.x + tv.x;
  float x1 = hv.y + tv.y;
  __shared__ float red[8];
  int wid = tid >> 6, lane = tid & 63;

  float s = x0 + x1;
  #pragma unroll
  for (int off = 32; off > 0; off >>= 1) s += __shfl_xor(s, off, 64);
  if (lane == 0) red[wid] = s;
  __syncthreads();
  float mean = (red[0] + red[1] + red[2] + red[3]) * (1.f/512.f);

  float d0 = x0 - mean, d1 = x1 - mean;
  float sq = d0*d0 + d1*d1;
  #pragma unroll
  for (int off = 32; off > 0; off >>= 1) sq += __shfl_xor(sq, off, 64);
  if (lane == 0) red[4 + wid] = sq;
  __syncthreads();
  float var = (red[4] + red[5] + red[6] + red[7]) * (1.f/512.f);
  float inv = rsqrtf(var + 1e-5f);
  float2 gv = ((const float2*)g)[tid];
  float2 bv = ((const float2*)b)[tid];
  float o0 = d0 * inv * gv.x + bv.x;
  float o1 = d1 * inv * gv.y + bv.y;
  ((float2*)h)[base2 + tid] = make_float2(o0, o1);
  ((unsigned*)h16)[base2 + tid] = (unsigned)f2b(o0) | ((unsigned)f2b(o1) << 16);
}

// ---------------- mean over sequence: parallel partial sums + atomicAdd ----------------
__global__ void pool_zero(float* __restrict__ pooled){
  pooled[blockIdx.x*512 + threadIdx.x] = 0.f;   // grid 4, block 512
}
__global__ void pool_kernel(const float* __restrict__ h, float* __restrict__ pooled){
  int c = blockIdx.x * 256 + threadIdx.x;   // 0..511
  int b = blockIdx.y;
  int s0 = blockIdx.z * 64;
  const float* p = h + ((size_t)b * 2048 + s0) * 512 + c;
  float acc = 0.f;
  #pragma unroll 8
  for (int s = 0; s < 64; ++s) acc += p[(size_t)s * 512];
  atomicAdd(&pooled[b*512 + c], acc * (1.f/2048.f));
}

// ---------------- tiny decoder ----------------
__global__ void decoder_kernel(const float* __restrict__ pooled,
                               const float* __restrict__ w1, const float* __restrict__ b1,
                               const float* __restrict__ w2, const float* __restrict__ b2,
                               float* __restrict__ out){
  __shared__ float ps[4][512];
  __shared__ float hid[4][256];
  int tid = threadIdx.x;
  for (int i = tid; i < 2048; i += 256) ps[i >> 9][i & 511] = pooled[i];
  __syncthreads();
  float bb = b1[tid];
  for (int b = 0; b < 4; ++b){
    float acc = bb;
    for (int k = 0; k < 512; ++k) acc += ps[b][k] * w1[k*256 + tid];
    hid[b][tid] = fmaxf(acc, 0.f);
  }
  __syncthreads();
  if (tid < 8){
    int b = tid >> 1, c = tid & 1;
    float acc = b2[c];
    for (int j = 0; j < 256; ++j) acc += hid[b][j] * w2[j*2 + c];
    out[b*2 + c] = acc;
  }
}

extern "C" void kernel_launch(void* const* d_in, const int* in_sizes, int n_in,
                              void* d_out, int out_size, void* d_ws, size_t ws_size,
                              hipStream_t stream){
  const float* x     = (const float*)d_in[0];
  const float* emb_w = (const float*)d_in[1];
  const float* emb_b = (const float*)d_in[2];
  const float* wq    = (const float*)d_in[3];
  const float* bq    = (const float*)d_in[4];
  const float* wk    = (const float*)d_in[5];
  const float* bk    = (const float*)d_in[6];
  const float* wv    = (const float*)d_in[7];
  const float* bv    = (const float*)d_in[8];
  const float* wo    = (const float*)d_in[9];
  const float* bo    = (const float*)d_in[10];
  const float* ff1w  = (const float*)d_in[11];
  const float* ff1b  = (const float*)d_in[12];
  const float* ff2w  = (const float*)d_in[13];
  const float* ff2b  = (const float*)d_in[14];
  const float* ln1g  = (const float*)d_in[15];
  const float* ln1b  = (const float*)d_in[16];
  const float* ln2g  = (const float*)d_in[17];
  const float* ln2b  = (const float*)d_in[18];
  const float* d1w   = (const float*)d_in[19];
  const float* d1b   = (const float*)d_in[20];
  const float* d2w   = (const float*)d_in[21];
  const float* d2b   = (const float*)d_in[22];

  // ---- workspace layout (~92 MB) ----
  float* h      = (float*)d_ws;
  float* tmp    = h + NT512;
  u16*   u      = (u16*)(tmp + NT512);
  u16*   h16    = u;
  u16*   q16    = u + NT512;
  u16*   k16    = u + 2*NT512;
  float* vb     = (float*)(u + 3*NT512);
  u16*   ff16   = q16;                 // 32 MB overlay of q16+k16+vb
  u16*   aob16  = (u16*)(vb + NT512);
  u16*   wt     = aob16 + NT512;
  u16*   wt_qkv = wt;                          // 2 x 1536*512
  u16*   wt_wo  = wt_qkv + (size_t)2*1536*512; // 2 x 512*512
  u16*   wt_ff1 = wt_wo  + (size_t)2*512*512;  // 2 x 2048*512
  u16*   wt_ff2 = wt_ff1 + (size_t)2*2048*512; // 2 x 512*2048
  float* pooled = (float*)(wt_ff2 + (size_t)2*512*2048);

  WtArgs wa{wq, wk, wv, wo, ff1w, ff2w, wt_qkv, wt_wo, wt_ff1, wt_ff2};
  convert_all<<<dim3(3072, 2), dim3(32, 8), 0, stream>>>(wa);

  embed_kernel<<<NTOK, 256, 0, stream>>>(x, emb_w, emb_b, h, h16);

  for (int l = 0; l < 2; ++l){
    // fused QKV: N=1536, scatter epilogue
    gemm_mfma<2><<<dim3(12, 64), 256, 0, stream>>>(
        h16, 512, wt_qkv + (size_t)l*1536*512, 512,
        bq + l*512, bk + l*512, bv + l*512,
        nullptr, q16, k16, vb, NTOK, 1536, 512);

    attn_mfma_topk<<<dim3(128, 32), 512, 0, stream>>>(q16, k16, vb, aob16);

    gemm_mfma<0><<<dim3(4, 64), 256, 0, stream>>>(
        aob16, 512, wt_wo + (size_t)l*512*512, 512,
        bo + l*512, nullptr, nullptr,
        tmp, nullptr, nullptr, nullptr, NTOK, 512, 512);
    resid_ln_kernel<<<NTOK, 256, 0, stream>>>(h, tmp, ln1g + l*512, ln1b + l*512, h16);

    gemm_mfma<1><<<dim3(16, 64), 256, 0, stream>>>(
        h16, 512, wt_ff1 + (size_t)l*2048*512, 512,
        ff1b + l*2048, nullptr, nullptr,
        nullptr, ff16, nullptr, nullptr, NTOK, 2048, 512);

    gemm_mfma<0><<<dim3(4, 64), 256, 0, stream>>>(
        ff16, 2048, wt_ff2 + (size_t)l*512*2048, 2048,
        ff2b + l*512, nullptr, nullptr,
        tmp, nullptr, nullptr, nullptr, NTOK, 512, 2048);
    resid_ln_kernel<<<NTOK, 256, 0, stream>>>(h, tmp, ln2g + l*512, ln2b + l*512, h16);
  }

  pool_zero<<<4, 512, 0, stream>>>(pooled);
  pool_kernel<<<dim3(2, 4, 32), 256, 0, stream>>>(h, pooled);
  decoder_kernel<<<1, 256, 0, stream>>>(pooled, d1w, d1b, d2w, d2b, (float*)d_out);
}

// Round 6
// 709.873 us; speedup vs baseline: 1.2502x; 1.0207x over previous
//
#include <hip/hip_runtime.h>
#include <cmath>

typedef unsigned short u16;
typedef __attribute__((ext_vector_type(8))) short short8;
typedef __attribute__((ext_vector_type(4))) float float4v;
typedef unsigned short ushort2v __attribute__((ext_vector_type(2)));

#define S_LEN 2048
#define NTOK  8192   // B*S
#define TOPK  35
#define NT512 ((size_t)NTOK*512)

__device__ __forceinline__ u16 f2b(float f){
  unsigned int x = __float_as_uint(f);
  unsigned int r = (x + 0x7fffu + ((x >> 16) & 1u)) >> 16;
  return (u16)r;
}
__device__ __forceinline__ float b2f(u16 u){
  return __uint_as_float(((unsigned int)u) << 16);
}

// bf16(f) -> monotone-increasing u16 sort key (no NaNs assumed)
__device__ __forceinline__ unsigned key_of(float f){
  unsigned u = (unsigned)f2b(f);
  unsigned m = (u & 0x8000u) ? 0xFFFFu : 0x8000u;
  return (u ^ m) & 0xFFFFu;
}
__device__ __forceinline__ float key_to_f(unsigned key){
  unsigned m = (key & 0x8000u) ? 0x8000u : 0xFFFFu;
  return __uint_as_float(((key ^ m) & 0xFFFFu) << 16);
}
__device__ __forceinline__ unsigned pkmax(unsigned a, unsigned b){
  union { unsigned u; ushort2v v; } x, y, r;
  x.u = a; y.u = b;
  r.v = __builtin_elementwise_max(x.v, y.v);
  return r.u;
}
__device__ __forceinline__ unsigned pkmin(unsigned a, unsigned b){
  union { unsigned u; ushort2v v; } x, y, r;
  x.u = a; y.u = b;
  r.v = __builtin_elementwise_min(x.v, y.v);
  return r.u;
}

// full bitonic sort, DESCENDING, of 128 packed-u16x2 values distributed
// 2 per lane: element e = l (v0) and e = 64+l (v1). Sorts both u16 halves
// independently (pk ops are per-half).
__device__ __forceinline__ void bsort128(unsigned &v0, unsigned &v1, int l){
  #pragma unroll
  for (int k = 2; k <= 128; k <<= 1){
    #pragma unroll
    for (int j = k >> 1; j > 0; j >>= 1){
      if (j == 64){
        unsigned hi = pkmax(v0, v1), lo = pkmin(v0, v1);
        v0 = hi; v1 = lo;
      } else {
        unsigned o0 = (unsigned)__shfl_xor((int)v0, j, 64);
        unsigned o1 = (unsigned)__shfl_xor((int)v1, j, 64);
        bool up0 = (((l & k) == 0) != ((l & j) != 0));
        bool up1 = ((((64 + l) & k) == 0) != ((l & j) != 0));
        unsigned hi0 = pkmax(v0, o0), lo0 = pkmin(v0, o0);
        unsigned hi1 = pkmax(v1, o1), lo1 = pkmin(v1, o1);
        v0 = up0 ? hi0 : lo0;
        v1 = up1 ? hi1 : lo1;
      }
    }
  }
}

// async global->LDS 16B direct copy; LDS dest pattern = wave-uniform base + lane*16
__device__ __forceinline__ void gload16(const void* g, void* l){
  __builtin_amdgcn_global_load_lds(
      (const __attribute__((address_space(1))) unsigned int*)g,
      (__attribute__((address_space(3))) unsigned int*)l, 16, 0, 0);
}

// ---------------- fused prep: weight transpose/convert + embedding ----------------
// blocks 0..6143: weight tiles (tt = bx%3072, layer = bx/3072).
// blocks 6144..8191: embedding, 4 tokens per block (w re-read from L2 /4).
struct WtArgs {
  const float* wq; const float* wk; const float* wv; const float* wo;
  const float* ff1w; const float* ff2w;
  u16* wt_qkv; u16* wt_wo; u16* wt_ff1; u16* wt_ff2;
};
__global__ void prep_kernel(WtArgs a,
                            const float* __restrict__ x, const float* __restrict__ w,
                            const float* __restrict__ bias, float* __restrict__ h,
                            u16* __restrict__ h16){
  __shared__ float xs[4][64];          // embed staging (also covers convert's 2.1KB)
  __shared__ u16 t[32][33];
  int bx = blockIdx.x;
  int tid = threadIdx.x;               // 0..255
  if (bx < 6144){
    int l  = (bx >= 3072) ? 1 : 0;
    int tt = bx - l*3072;
    const float* W; u16* Wt; int K, N, tx_, ty_;
    if (tt < 1024){                 // qkv (3 segs) + wo, all 512x512, 16x16 tiles
      int seg = tt >> 8, r = tt & 255;
      tx_ = r & 15; ty_ = r >> 4; K = 512; N = 512;
      if (seg == 0){ W = a.wq + (size_t)l*262144; Wt = a.wt_qkv + (size_t)l*786432; }
      else if (seg == 1){ W = a.wk + (size_t)l*262144; Wt = a.wt_qkv + (size_t)l*786432 + 262144; }
      else if (seg == 2){ W = a.wv + (size_t)l*262144; Wt = a.wt_qkv + (size_t)l*786432 + 524288; }
      else { W = a.wo + (size_t)l*262144; Wt = a.wt_wo + (size_t)l*262144; }
    } else if (tt < 2048){          // ff1: K=512, N=2048 -> tiles 64 x 16
      int r = tt - 1024;
      tx_ = r & 63; ty_ = r >> 6; K = 512; N = 2048;
      W = a.ff1w + (size_t)l*1048576; Wt = a.wt_ff1 + (size_t)l*1048576;
    } else {                        // ff2: K=2048, N=512 -> tiles 16 x 64
      int r = tt - 2048;
      tx_ = r & 15; ty_ = r >> 4; K = 2048; N = 512;
      W = a.ff2w + (size_t)l*1048576; Wt = a.wt_ff2 + (size_t)l*1048576;
    }
    int k0 = ty_*32, n0 = tx_*32;
    int tx = tid & 31, ty = tid >> 5;   // 32x8
    #pragma unroll
    for (int i = ty; i < 32; i += 8)
      t[i][tx] = f2b(W[(size_t)(k0+i)*N + n0+tx]);
    __syncthreads();
    #pragma unroll
    for (int i = ty; i < 32; i += 8)
      Wt[(size_t)(n0+i)*K + k0+tx] = t[tx][i];
  } else {
    int t0 = (bx - 6144) * 4;          // 4 tokens per block
    xs[tid >> 6][tid & 63] = x[(size_t)(t0 + (tid >> 6))*64 + (tid & 63)];
    __syncthreads();
    float b0 = bias[tid], b1 = bias[tid + 256];
    float acc[4][2];
    #pragma unroll
    for (int tk = 0; tk < 4; ++tk){ acc[tk][0] = b0; acc[tk][1] = b1; }
    #pragma unroll 8
    for (int k = 0; k < 64; ++k){
      float w0 = w[k*512 + tid];
      float w1 = w[k*512 + tid + 256];
      #pragma unroll
      for (int tk = 0; tk < 4; ++tk){
        float xv = xs[tk][k];
        acc[tk][0] += xv * w0;
        acc[tk][1] += xv * w1;
      }
    }
    const float neg_ln1e4_over_D = -9.210340371976184f / 512.f;
    int c0 = tid, c1 = tid + 256;
    float e0 = expf((float)(c0 & ~1) * neg_ln1e4_over_D);
    float e1 = expf((float)(c1 & ~1) * neg_ln1e4_over_D);
    #pragma unroll
    for (int tk = 0; tk < 4; ++tk){
      int tok = t0 + tk;
      int s = tok & (S_LEN - 1);
      float a0 = (float)s * e0;
      float p0 = (c0 & 1) ? cosf(a0) : sinf(a0);
      float a1 = (float)s * e1;
      float p1 = (c1 & 1) ? cosf(a1) : sinf(a1);
      float v0 = acc[tk][0] + p0, v1 = acc[tk][1] + p1;
      h[(size_t)tok*512 + c0] = v0;  h16[(size_t)tok*512 + c0] = f2b(v0);
      h[(size_t)tok*512 + c1] = v1;  h16[(size_t)tok*512 + c1] = f2b(v1);
    }
  }
}

// ---------------- bf16 MFMA GEMM: C = A[M,lda] @ Bt[N,ldb]^T + bias ----------------
// XCD-aware bijective tile swizzle (all grids have nwg%8==0): consecutive
// tiles (sharing an A-panel) land on the same XCD's L2.
template<int EPI>
__global__ __launch_bounds__(256) void gemm_mfma(
    const u16* __restrict__ A, int lda, const u16* __restrict__ Bt, int ldb,
    const float* __restrict__ bias0, const float* __restrict__ bias1,
    const float* __restrict__ bias2,
    float* __restrict__ Cf, u16* __restrict__ C16a, u16* __restrict__ C16b,
    float* __restrict__ Cv, int M, int N, int Klen){
  __shared__ __align__(16) u16 As[128*64];
  __shared__ __align__(16) u16 Bs[128*64];
  int tid = threadIdx.x;
  int w = tid >> 6, l = tid & 63, quad = l >> 4, m = l & 15;
  int gx = gridDim.x;
  int orig = blockIdx.y * gx + blockIdx.x;
  int nwg  = gx * gridDim.y;
  int tt   = (orig & 7) * (nwg >> 3) + (orig >> 3);
  int m0 = (tt / gx) * 128, n0 = (tt % gx) * 128;
  int mh = (w >> 1)*64, nh = (w & 1)*64;
  float4v acc[4][4];
  #pragma unroll
  for (int i = 0; i < 4; ++i)
    #pragma unroll
    for (int j = 0; j < 4; ++j) acc[i][j] = (float4v){0.f,0.f,0.f,0.f};

  for (int kt = 0; kt < Klen; kt += 64){
    #pragma unroll
    for (int c = 0; c < 4; ++c){
      int g = c*256 + tid;
      int row = g >> 3, sc = g & 7, dc = sc ^ (row & 7);
      gload16(A  + (size_t)(m0+row)*lda + kt + dc*8, As + (size_t)g*8);
      gload16(Bt + (size_t)(n0+row)*ldb + kt + dc*8, Bs + (size_t)g*8);
    }
    __syncthreads();
    #pragma unroll
    for (int kk = 0; kk < 2; ++kk){
      short8 af[4], bf[4];
      #pragma unroll
      for (int i = 0; i < 4; ++i){
        int dcx = kk*4 + quad;
        int ra = mh + i*16 + m;
        af[i] = *(const short8*)(As + (size_t)(ra*8 + (dcx ^ (ra & 7)))*8);
        int rb = nh + i*16 + m;
        bf[i] = *(const short8*)(Bs + (size_t)(rb*8 + (dcx ^ (rb & 7)))*8);
      }
      #pragma unroll
      for (int i = 0; i < 4; ++i)
        #pragma unroll
        for (int j = 0; j < 4; ++j)
          acc[i][j] = __builtin_amdgcn_mfma_f32_16x16x32_bf16(af[i], bf[j], acc[i][j], 0, 0, 0);
    }
    __syncthreads();
  }

  // C/D layout: row_local = quad*4+r, col_local = m
  #pragma unroll
  for (int i = 0; i < 4; ++i){
    #pragma unroll
    for (int j = 0; j < 4; ++j){
      int col = n0 + nh + j*16 + m;
      #pragma unroll
      for (int r = 0; r < 4; ++r){
        int row = m0 + mh + i*16 + quad*4 + r;
        float v = acc[i][j][r];
        if (EPI == 0){
          Cf[(size_t)row*N + col] = v + bias0[col];
        } else if (EPI == 1){
          C16a[(size_t)row*N + col] = f2b(fmaxf(v + bias0[col], 0.f));
        } else {
          int sel = col >> 9, n5 = col & 511;
          const float* bp = (sel == 0) ? bias0 : (sel == 1) ? bias1 : bias2;
          float vv = v + bp[n5];
          int d = n5 & 63, hh = n5 >> 6;
          int b = row >> 11, s = row & 2047;
          size_t idx = (((size_t)(b*8 + hh))*2048 + s)*64 + d;
          if (sel == 0)      C16a[idx] = f2b(vv);
          else if (sel == 1) C16b[idx] = f2b(vv);
          else               Cv[idx]  = vv;
        }
      }
    }
  }
}

// ---------------- fused MFMA scores + top-35 + softmax + P@V[:35] ----------------
// Selection:
//   1. per-lane packed top-2 of its 32 keys
//   2. T' (rank-35 of the 128 top-2 values, per query) via 16-step binary
//      search on the u16 key space using ballot+popcount
//   3. compact candidates (>= T') to LDS, capacity 128 (de-chained index)
//   4. bitonic sort-128 of candidates -> ranks 0..34 live in lanes 0..34
//   5. softmax once per rank; weights broadcast via v_readlane (no LDS)
// Score phase: depth-2 software-pipelined K loads.
// XCD-aware block swizzle: consecutive q-tiles of one bh share an XCD L2.
__global__ __launch_bounds__(512, 8) void attn_mfma_topk(
    const u16* __restrict__ qb16, const u16* __restrict__ kb16,
    const float* __restrict__ vb, u16* __restrict__ aob16){
  __shared__ unsigned pr[8*1024];   // 32 KB
  int tid  = threadIdx.x;
  int w    = tid >> 6, l = tid & 63;
  int quad = l >> 4,  m = l & 15;
  // bijective XCD swizzle over 4096 blocks (128 x 32)
  int orig = blockIdx.y * 128 + blockIdx.x;
  int t4   = ((orig & 7) << 9) | (orig >> 3);
  int bh   = t4 >> 7;
  int q0   = (t4 & 127) << 4;

  const u16* Qp = qb16 + ((size_t)bh*2048 + q0 + m)*64 + quad*8;
  short8 a0 = *(const short8*)Qp;
  short8 a1 = *(const short8*)(Qp + 32);

  const u16* Kbase = kb16 + (size_t)bh*2048*64;
  unsigned sc[32];
  int swz = (quad & 1) << 4;
  const u16* kp0 = Kbase + (size_t)(w*128 + m)*64 + quad*8;
  // tile t (0..15): row offset = (t>>3)*1024 + (t&7)*16
  const uint4* p4 = (const uint4*)(pr + w*1024);

  short8 cb0 = *(const short8*)kp0;
  short8 cb1 = *(const short8*)(kp0 + 32);
  #pragma unroll
  for (int t = 0; t < 16; ++t){
    short8 nb0, nb1;
    if (t < 15){
      int tn = t + 1;
      const u16* np = kp0 + (size_t)(((tn >> 3) << 10) + ((tn & 7) << 4))*64;
      nb0 = *(const short8*)np;
      nb1 = *(const short8*)(np + 32);
    }
    float4v acc = {0.f, 0.f, 0.f, 0.f};
    acc = __builtin_amdgcn_mfma_f32_16x16x32_bf16(a0, cb0, acc, 0, 0, 0);
    acc = __builtin_amdgcn_mfma_f32_16x16x32_bf16(a1, cb1, acc, 0, 0, 0);
    int lk = (w << 7) + ((t & 7) << 4);
    #pragma unroll
    for (int c = 0; c < 2; ++c){
      unsigned lo = key_of(acc[2*c]);
      unsigned hi = key_of(acc[2*c+1]);
      pr[(quad*2 + c)*1024 + ((lk + m) ^ swz)] = lo | (hi << 16);
    }
    cb0 = nb0; cb1 = nb1;
    if (t == 7){
      __syncthreads();
      #pragma unroll
      for (int j = 0; j < 4; ++j){
        uint4 v4 = p4[j*64 + l];
        sc[j*4+0] = v4.x; sc[j*4+1] = v4.y; sc[j*4+2] = v4.z; sc[j*4+3] = v4.w;
      }
      __syncthreads();
    }
  }
  __syncthreads();
  #pragma unroll
  for (int j = 0; j < 4; ++j){
    uint4 v4 = p4[j*64 + l];
    sc[16+j*4+0] = v4.x; sc[16+j*4+1] = v4.y; sc[16+j*4+2] = v4.z; sc[16+j*4+3] = v4.w;
  }

  unsigned* row = &pr[w*1024];   // wave-private scratch from here on

  // ---- per-lane packed top-2 ----
  unsigned m1 = pkmax(sc[0], sc[1]);
  unsigned m2 = pkmin(sc[0], sc[1]);
  #pragma unroll
  for (int i = 2; i < 32; ++i){
    unsigned v = sc[i];
    unsigned nm1 = pkmax(m1, v);
    m2 = pkmax(m2, pkmin(m1, v));
    m1 = nm1;
  }

  // ---- T' via binary search on key space (rank-35 of the 128 top-2s) ----
  unsigned mA1 = m1 & 0xFFFFu, mB1 = m1 >> 16;
  unsigned mA2 = m2 & 0xFFFFu, mB2 = m2 >> 16;
  unsigned tA = 0, tB = 0;
  #pragma unroll
  for (int bit = 15; bit >= 0; --bit){
    unsigned cA = tA | (1u << bit);
    unsigned cB = tB | (1u << bit);
    int nA = __popcll(__ballot(mA1 >= cA)) + __popcll(__ballot(mA2 >= cA));
    int nB = __popcll(__ballot(mB1 >= cB)) + __popcll(__ballot(mB2 >= cB));
    if (nA >= TOPK) tA = cA;
    if (nB >= TOPK) tB = cB;
  }
  unsigned TT = (tA - 1) | ((tB - 1) << 16);   // per-half threshold-minus-1

  // ---- survivor mask: slot survives iff (A >= tA) || (B >= tB) ----
  unsigned mask = 0;
  #pragma unroll
  for (int i = 0; i < 32; ++i){
    mask |= (pkmax(sc[i], TT) != TT) ? (1u << i) : 0u;
  }
  int cnt = __popc(mask);

  // exclusive prefix over lanes
  int pre = cnt;
  #pragma unroll
  for (int off = 1; off < 64; off <<= 1){
    int n = __shfl_up(pre, off, 64);
    if (l >= off) pre += n;
  }
  pre -= cnt;

  // compact survivors into LDS (wave-private row; capacity 128).
  // position = pre + popc(lower set bits): no serial dependence.
  #pragma unroll
  for (int i = 0; i < 32; ++i){
    if (mask & (1u << i)){
      int p = pre + __popc(mask & ((1u << i) - 1u));
      if (p < 128) row[p] = sc[i];
    }
  }
  int tot = __shfl(pre + cnt, 63, 64);   // total candidate count

  // read back, pad with 0 (key 0 < any real key)
  unsigned c0 = (l < tot)      ? row[l]      : 0u;
  unsigned c1 = (64 + l < tot) ? row[64 + l] : 0u;

  // V rows 0..34 (loads overlap with the sort below)
  const float* Vb = vb + (size_t)bh*2048*64 + l;   // lane = d
  float vreg[TOPK];
  #pragma unroll
  for (int r = 0; r < TOPK; ++r) vreg[r] = Vb[(size_t)r*64];

  // ---- final sort: ranks 0..34 end up in c0, lanes 0..34 ----
  bsort128(c0, c1, l);

  // ---- softmax weights, computed once per rank ----
  unsigned top0 = (unsigned)__shfl((int)c0, 0, 64);
  float mAf = key_to_f(top0 & 0xFFFFu) * 0.125f;
  float mBf = key_to_f(top0 >> 16)     * 0.125f;
  float tvA = key_to_f(c0 & 0xFFFFu)   * 0.125f;
  float tvB = key_to_f(c0 >> 16)       * 0.125f;
  float wAv = (l < TOPK) ? __expf(tvA - mAf) : 0.f;
  float wBv = (l < TOPK) ? __expf(tvB - mBf) : 0.f;

  float dA = wAv, dB = wBv;
  #pragma unroll
  for (int off = 32; off > 0; off >>= 1){
    dA += __shfl_xor(dA, off, 64);
    dB += __shfl_xor(dB, off, 64);
  }

  // PV: weight of rank r broadcast from lane r via readlane (SGPR), no LDS
  float accA = 0.f, accB = 0.f;
  #pragma unroll
  for (int r = 0; r < TOPK; ++r){
    float wA = __uint_as_float((unsigned)__builtin_amdgcn_readlane((int)__float_as_uint(wAv), r));
    float wB = __uint_as_float((unsigned)__builtin_amdgcn_readlane((int)__float_as_uint(wBv), r));
    float vv = vreg[r];
    accA += wA * vv;
    accB += wB * vv;
  }
  accA *= __builtin_amdgcn_rcpf(dA);
  accB *= __builtin_amdgcn_rcpf(dB);

  int b = bh >> 3, hh = bh & 7;
  int sA = q0 + w*2;
  aob16[(((size_t)(b*2048 + sA))*8 + hh)*64 + l]     = f2b(accA);
  aob16[(((size_t)(b*2048 + sA + 1))*8 + hh)*64 + l] = f2b(accB);
}

// ---------------- h = LayerNorm(h + t) * g + b, in place; also bf16 copy ----------------
// float4-vectorized (16B/lane), 2 tokens per block (waves 0,1 -> token A;
// waves 2,3 -> token B).
__global__ void resid_ln_kernel(float* __restrict__ h, const float* __restrict__ t,
                                const float* __restrict__ g, const float* __restrict__ b,
                                u16* __restrict__ h16){
  int half = threadIdx.x >> 7;             // 0 or 1
  int tok  = blockIdx.x*2 + half;
  int tid  = threadIdx.x & 127;            // float4 col index 0..127
  size_t base4 = (size_t)tok * 128;        // float4 units per row
  float4 hv = ((const float4*)h)[base4 + tid];
  float4 tv = ((const float4*)t)[base4 + tid];
  float x0 = hv.x + tv.x, x1 = hv.y + tv.y;
  float x2 = hv.z + tv.z, x3 = hv.w + tv.w;
  __shared__ float red[8];
  int wid = threadIdx.x >> 6, lane = threadIdx.x & 63;

  float s = (x0 + x1) + (x2 + x3);
  #pragma unroll
  for (int off = 32; off > 0; off >>= 1) s += __shfl_xor(s, off, 64);
  if (lane == 0) red[wid] = s;
  __syncthreads();
  int hb = half << 1;
  float mean = (red[hb] + red[hb+1]) * (1.f/512.f);

  float d0 = x0 - mean, d1 = x1 - mean, d2 = x2 - mean, d3 = x3 - mean;
  float sq = (d0*d0 + d1*d1) + (d2*d2 + d3*d3);
  #pragma unroll
  for (int off = 32; off > 0; off >>= 1) sq += __shfl_xor(sq, off, 64);
  if (lane == 0) red[4 + wid] = sq;
  __syncthreads();
  float var = (red[4 + hb] + red[4 + hb + 1]) * (1.f/512.f);
  float inv = rsqrtf(var + 1e-5f);
  float4 gv = ((const float4*)g)[tid];
  float4 bv = ((const float4*)b)[tid];
  float o0 = d0 * inv * gv.x + bv.x;
  float o1 = d1 * inv * gv.y + bv.y;
  float o2 = d2 * inv * gv.z + bv.z;
  float o3 = d3 * inv * gv.w + bv.w;
  ((float4*)h)[base4 + tid] = make_float4(o0, o1, o2, o3);
  uint2 pk;
  pk.x = (unsigned)f2b(o0) | ((unsigned)f2b(o1) << 16);
  pk.y = (unsigned)f2b(o2) | ((unsigned)f2b(o3) << 16);
  ((uint2*)h16)[base4 + tid] = pk;
}

// ---------------- mean over sequence: partial sums (no atomics, no zero-pass) ----------------
__global__ void pool_kernel(const float* __restrict__ h, float* __restrict__ part){
  int c = blockIdx.x * 256 + threadIdx.x;   // 0..511
  int b = blockIdx.y;
  int z = blockIdx.z;
  const float* p = h + ((size_t)b * 2048 + z * 64) * 512 + c;
  float acc = 0.f;
  #pragma unroll 8
  for (int s = 0; s < 64; ++s) acc += p[(size_t)s * 512];
  part[((size_t)(z*4 + b))*512 + c] = acc;
}

// ---------------- tiny decoder (sums the 32 pool partials) ----------------
__global__ void decoder_kernel(const float* __restrict__ part,
                               const float* __restrict__ w1, const float* __restrict__ b1,
                               const float* __restrict__ w2, const float* __restrict__ b2,
                               float* __restrict__ out){
  __shared__ float ps[4][512];
  __shared__ float hid[4][256];
  int tid = threadIdx.x;
  for (int i = tid; i < 2048; i += 256){
    int b = i >> 9, c = i & 511;
    float s = 0.f;
    #pragma unroll
    for (int z = 0; z < 32; ++z) s += part[((size_t)(z*4 + b))*512 + c];
    ps[b][c] = s * (1.f/2048.f);
  }
  __syncthreads();
  float bb = b1[tid];
  for (int b = 0; b < 4; ++b){
    float acc = bb;
    for (int k = 0; k < 512; ++k) acc += ps[b][k] * w1[k*256 + tid];
    hid[b][tid] = fmaxf(acc, 0.f);
  }
  __syncthreads();
  if (tid < 8){
    int b = tid >> 1, c = tid & 1;
    float acc = b2[c];
    for (int j = 0; j < 256; ++j) acc += hid[b][j] * w2[j*2 + c];
    out[b*2 + c] = acc;
  }
}

extern "C" void kernel_launch(void* const* d_in, const int* in_sizes, int n_in,
                              void* d_out, int out_size, void* d_ws, size_t ws_size,
                              hipStream_t stream){
  const float* x     = (const float*)d_in[0];
  const float* emb_w = (const float*)d_in[1];
  const float* emb_b = (const float*)d_in[2];
  const float* wq    = (const float*)d_in[3];
  const float* bq    = (const float*)d_in[4];
  const float* wk    = (const float*)d_in[5];
  const float* bk    = (const float*)d_in[6];
  const float* wv    = (const float*)d_in[7];
  const float* bv    = (const float*)d_in[8];
  const float* wo    = (const float*)d_in[9];
  const float* bo    = (const float*)d_in[10];
  const float* ff1w  = (const float*)d_in[11];
  const float* ff1b  = (const float*)d_in[12];
  const float* ff2w  = (const float*)d_in[13];
  const float* ff2b  = (const float*)d_in[14];
  const float* ln1g  = (const float*)d_in[15];
  const float* ln1b  = (const float*)d_in[16];
  const float* ln2g  = (const float*)d_in[17];
  const float* ln2b  = (const float*)d_in[18];
  const float* d1w   = (const float*)d_in[19];
  const float* d1b   = (const float*)d_in[20];
  const float* d2w   = (const float*)d_in[21];
  const float* d2b   = (const float*)d_in[22];

  // ---- workspace layout (~92 MB) ----
  float* h      = (float*)d_ws;
  float* tmp    = h + NT512;
  u16*   u      = (u16*)(tmp + NT512);
  u16*   h16    = u;
  u16*   q16    = u + NT512;
  u16*   k16    = u + 2*NT512;
  float* vb     = (float*)(u + 3*NT512);
  u16*   ff16   = q16;                 // 32 MB overlay of q16+k16+vb
  u16*   aob16  = (u16*)(vb + NT512);
  u16*   wt     = aob16 + NT512;
  u16*   wt_qkv = wt;                          // 2 x 1536*512
  u16*   wt_wo  = wt_qkv + (size_t)2*1536*512; // 2 x 512*512
  u16*   wt_ff1 = wt_wo  + (size_t)2*512*512;  // 2 x 2048*512
  u16*   wt_ff2 = wt_ff1 + (size_t)2*2048*512; // 2 x 512*2048
  float* part   = tmp;                 // pool partials [32][4][512] in dead tmp

  WtArgs wa{wq, wk, wv, wo, ff1w, ff2w, wt_qkv, wt_wo, wt_ff1, wt_ff2};
  prep_kernel<<<8192, 256, 0, stream>>>(wa, x, emb_w, emb_b, h, h16);

  for (int l = 0; l < 2; ++l){
    // fused QKV: N=1536, scatter epilogue
    gemm_mfma<2><<<dim3(12, 64), 256, 0, stream>>>(
        h16, 512, wt_qkv + (size_t)l*1536*512, 512,
        bq + l*512, bk + l*512, bv + l*512,
        nullptr, q16, k16, vb, NTOK, 1536, 512);

    attn_mfma_topk<<<dim3(128, 32), 512, 0, stream>>>(q16, k16, vb, aob16);

    gemm_mfma<0><<<dim3(4, 64), 256, 0, stream>>>(
        aob16, 512, wt_wo + (size_t)l*512*512, 512,
        bo + l*512, nullptr, nullptr,
        tmp, nullptr, nullptr, nullptr, NTOK, 512, 512);
    resid_ln_kernel<<<NTOK/2, 256, 0, stream>>>(h, tmp, ln1g + l*512, ln1b + l*512, h16);

    gemm_mfma<1><<<dim3(16, 64), 256, 0, stream>>>(
        h16, 512, wt_ff1 + (size_t)l*2048*512, 512,
        ff1b + l*2048, nullptr, nullptr,
        nullptr, ff16, nullptr, nullptr, NTOK, 2048, 512);

    gemm_mfma<0><<<dim3(4, 64), 256, 0, stream>>>(
        ff16, 2048, wt_ff2 + (size_t)l*512*2048, 2048,
        ff2b + l*512, nullptr, nullptr,
        tmp, nullptr, nullptr, nullptr, NTOK, 512, 2048);
    resid_ln_kernel<<<NTOK/2, 256, 0, stream>>>(h, tmp, ln2g + l*512, ln2b + l*512, h16);
  }

  pool_kernel<<<dim3(2, 4, 32), 256, 0, stream>>>(h, part);
  decoder_kernel<<<1, 256, 0, stream>>>(part, d1w, d1b, d2w, d2b, (float*)d_out);
}

// Round 7
// 699.503 us; speedup vs baseline: 1.2687x; 1.0148x over previous
//
#include <hip/hip_runtime.h>
#include <cmath>

typedef unsigned short u16;
typedef __attribute__((ext_vector_type(8))) short short8;
typedef __attribute__((ext_vector_type(4))) float float4v;
typedef unsigned short ushort2v __attribute__((ext_vector_type(2)));

#define S_LEN 2048
#define NTOK  8192   // B*S
#define TOPK  35
#define NT512 ((size_t)NTOK*512)

__device__ __forceinline__ u16 f2b(float f){
  unsigned int x = __float_as_uint(f);
  unsigned int r = (x + 0x7fffu + ((x >> 16) & 1u)) >> 16;
  return (u16)r;
}
__device__ __forceinline__ float b2f(u16 u){
  return __uint_as_float(((unsigned int)u) << 16);
}

// bf16(f) -> monotone-increasing u16 sort key (no NaNs assumed)
__device__ __forceinline__ unsigned key_of(float f){
  unsigned u = (unsigned)f2b(f);
  unsigned m = (u & 0x8000u) ? 0xFFFFu : 0x8000u;
  return (u ^ m) & 0xFFFFu;
}
__device__ __forceinline__ float key_to_f(unsigned key){
  unsigned m = (key & 0x8000u) ? 0x8000u : 0xFFFFu;
  return __uint_as_float(((key ^ m) & 0xFFFFu) << 16);
}
__device__ __forceinline__ unsigned pkmax(unsigned a, unsigned b){
  union { unsigned u; ushort2v v; } x, y, r;
  x.u = a; y.u = b;
  r.v = __builtin_elementwise_max(x.v, y.v);
  return r.u;
}
__device__ __forceinline__ unsigned pkmin(unsigned a, unsigned b){
  union { unsigned u; ushort2v v; } x, y, r;
  x.u = a; y.u = b;
  r.v = __builtin_elementwise_min(x.v, y.v);
  return r.u;
}

// full bitonic sort, DESCENDING, of 128 packed-u16x2 values distributed
// 2 per lane: element e = l (v0) and e = 64+l (v1). Sorts both u16 halves
// independently (pk ops are per-half).
__device__ __forceinline__ void bsort128(unsigned &v0, unsigned &v1, int l){
  #pragma unroll
  for (int k = 2; k <= 128; k <<= 1){
    #pragma unroll
    for (int j = k >> 1; j > 0; j >>= 1){
      if (j == 64){
        unsigned hi = pkmax(v0, v1), lo = pkmin(v0, v1);
        v0 = hi; v1 = lo;
      } else {
        unsigned o0 = (unsigned)__shfl_xor((int)v0, j, 64);
        unsigned o1 = (unsigned)__shfl_xor((int)v1, j, 64);
        bool up0 = (((l & k) == 0) != ((l & j) != 0));
        bool up1 = ((((64 + l) & k) == 0) != ((l & j) != 0));
        unsigned hi0 = pkmax(v0, o0), lo0 = pkmin(v0, o0);
        unsigned hi1 = pkmax(v1, o1), lo1 = pkmin(v1, o1);
        v0 = up0 ? hi0 : lo0;
        v1 = up1 ? hi1 : lo1;
      }
    }
  }
}

// async global->LDS 16B direct copy; LDS dest pattern = wave-uniform base + lane*16
__device__ __forceinline__ void gload16(const void* g, void* l){
  __builtin_amdgcn_global_load_lds(
      (const __attribute__((address_space(1))) unsigned int*)g,
      (__attribute__((address_space(3))) unsigned int*)l, 16, 0, 0);
}

// ---------------- fused prep: weight transpose/convert + embedding ----------------
// blocks 0..6143: weight tiles (tt = bx%3072, layer = bx/3072).
// blocks 6144..8191: embedding, 4 tokens per block (w re-read from L2 /4).
struct WtArgs {
  const float* wq; const float* wk; const float* wv; const float* wo;
  const float* ff1w; const float* ff2w;
  u16* wt_qkv; u16* wt_wo; u16* wt_ff1; u16* wt_ff2;
};
__global__ void prep_kernel(WtArgs a,
                            const float* __restrict__ x, const float* __restrict__ w,
                            const float* __restrict__ bias, float* __restrict__ h,
                            u16* __restrict__ h16){
  __shared__ float xs[4][64];          // embed staging (also covers convert's 2.1KB)
  __shared__ u16 t[32][33];
  int bx = blockIdx.x;
  int tid = threadIdx.x;               // 0..255
  if (bx < 6144){
    int l  = (bx >= 3072) ? 1 : 0;
    int tt = bx - l*3072;
    const float* W; u16* Wt; int K, N, tx_, ty_;
    if (tt < 1024){                 // qkv (3 segs) + wo, all 512x512, 16x16 tiles
      int seg = tt >> 8, r = tt & 255;
      tx_ = r & 15; ty_ = r >> 4; K = 512; N = 512;
      if (seg == 0){ W = a.wq + (size_t)l*262144; Wt = a.wt_qkv + (size_t)l*786432; }
      else if (seg == 1){ W = a.wk + (size_t)l*262144; Wt = a.wt_qkv + (size_t)l*786432 + 262144; }
      else if (seg == 2){ W = a.wv + (size_t)l*262144; Wt = a.wt_qkv + (size_t)l*786432 + 524288; }
      else { W = a.wo + (size_t)l*262144; Wt = a.wt_wo + (size_t)l*262144; }
    } else if (tt < 2048){          // ff1: K=512, N=2048 -> tiles 64 x 16
      int r = tt - 1024;
      tx_ = r & 63; ty_ = r >> 6; K = 512; N = 2048;
      W = a.ff1w + (size_t)l*1048576; Wt = a.wt_ff1 + (size_t)l*1048576;
    } else {                        // ff2: K=2048, N=512 -> tiles 16 x 64
      int r = tt - 2048;
      tx_ = r & 15; ty_ = r >> 4; K = 2048; N = 512;
      W = a.ff2w + (size_t)l*1048576; Wt = a.wt_ff2 + (size_t)l*1048576;
    }
    int k0 = ty_*32, n0 = tx_*32;
    int tx = tid & 31, ty = tid >> 5;   // 32x8
    #pragma unroll
    for (int i = ty; i < 32; i += 8)
      t[i][tx] = f2b(W[(size_t)(k0+i)*N + n0+tx]);
    __syncthreads();
    #pragma unroll
    for (int i = ty; i < 32; i += 8)
      Wt[(size_t)(n0+i)*K + k0+tx] = t[tx][i];
  } else {
    int t0 = (bx - 6144) * 4;          // 4 tokens per block
    xs[tid >> 6][tid & 63] = x[(size_t)(t0 + (tid >> 6))*64 + (tid & 63)];
    __syncthreads();
    float b0 = bias[tid], b1 = bias[tid + 256];
    float acc[4][2];
    #pragma unroll
    for (int tk = 0; tk < 4; ++tk){ acc[tk][0] = b0; acc[tk][1] = b1; }
    #pragma unroll 8
    for (int k = 0; k < 64; ++k){
      float w0 = w[k*512 + tid];
      float w1 = w[k*512 + tid + 256];
      #pragma unroll
      for (int tk = 0; tk < 4; ++tk){
        float xv = xs[tk][k];
        acc[tk][0] += xv * w0;
        acc[tk][1] += xv * w1;
      }
    }
    const float neg_ln1e4_over_D = -9.210340371976184f / 512.f;
    int c0 = tid, c1 = tid + 256;
    float e0 = expf((float)(c0 & ~1) * neg_ln1e4_over_D);
    float e1 = expf((float)(c1 & ~1) * neg_ln1e4_over_D);
    #pragma unroll
    for (int tk = 0; tk < 4; ++tk){
      int tok = t0 + tk;
      int s = tok & (S_LEN - 1);
      float a0 = (float)s * e0;
      float p0 = (c0 & 1) ? cosf(a0) : sinf(a0);
      float a1 = (float)s * e1;
      float p1 = (c1 & 1) ? cosf(a1) : sinf(a1);
      float v0 = acc[tk][0] + p0, v1 = acc[tk][1] + p1;
      h[(size_t)tok*512 + c0] = v0;  h16[(size_t)tok*512 + c0] = f2b(v0);
      h[(size_t)tok*512 + c1] = v1;  h16[(size_t)tok*512 + c1] = f2b(v1);
    }
  }
}

// ---------------- bf16 MFMA GEMM: C = A[M,lda] @ Bt[N,ldb]^T + bias ----------------
// XCD-aware bijective tile swizzle + 2-phase double-buffered pipeline:
// issue next K-tile's global_load_lds BEFORE the MFMA on the current tile;
// ONE barrier per K-step (compiler inserts vmcnt(0)+lgkmcnt(0) before it,
// after ~400cy of MFMA has covered the load latency). Critical for WO/FF2
// which run at 1 block/CU (no TLP to hide staging latency).
template<int EPI>
__global__ __launch_bounds__(256) void gemm_mfma(
    const u16* __restrict__ A, int lda, const u16* __restrict__ Bt, int ldb,
    const float* __restrict__ bias0, const float* __restrict__ bias1,
    const float* __restrict__ bias2,
    float* __restrict__ Cf, u16* __restrict__ C16a, u16* __restrict__ C16b,
    float* __restrict__ Cv, int M, int N, int Klen){
  __shared__ __align__(16) u16 As[2*128*64];
  __shared__ __align__(16) u16 Bs[2*128*64];
  int tid = threadIdx.x;
  int w = tid >> 6, l = tid & 63, quad = l >> 4, m = l & 15;
  int gx = gridDim.x;
  int orig = blockIdx.y * gx + blockIdx.x;
  int nwg  = gx * gridDim.y;
  int tt   = (orig & 7) * (nwg >> 3) + (orig >> 3);
  int m0 = (tt / gx) * 128, n0 = (tt % gx) * 128;
  int mh = (w >> 1)*64, nh = (w & 1)*64;
  float4v acc[4][4];
  #pragma unroll
  for (int i = 0; i < 4; ++i)
    #pragma unroll
    for (int j = 0; j < 4; ++j) acc[i][j] = (float4v){0.f,0.f,0.f,0.f};

  // stage K-tile kt into buffer half ofs (0 or 128*64)
  #define GSTAGE(ofs, kt) do { \
    _Pragma("unroll") \
    for (int c = 0; c < 4; ++c){ \
      int g = c*256 + tid; \
      int row = g >> 3, scx = g & 7, dc = scx ^ (row & 7); \
      gload16(A  + (size_t)(m0+row)*lda + (kt) + dc*8, As + (ofs) + (size_t)g*8); \
      gload16(Bt + (size_t)(n0+row)*ldb + (kt) + dc*8, Bs + (ofs) + (size_t)g*8); \
    } } while(0)

  GSTAGE(0, 0);
  __syncthreads();                       // vmcnt(0) auto-inserted: buf0 ready
  int cur = 0;
  for (int kt = 0; kt < Klen; kt += 64){
    int nxt = cur ^ 1;
    if (kt + 64 < Klen) GSTAGE(nxt*(128*64), kt + 64);   // prefetch in flight
    const u16* Ac = As + cur*(128*64);
    const u16* Bc = Bs + cur*(128*64);
    #pragma unroll
    for (int kk = 0; kk < 2; ++kk){
      short8 af[4], bf[4];
      #pragma unroll
      for (int i = 0; i < 4; ++i){
        int dcx = kk*4 + quad;
        int ra = mh + i*16 + m;
        af[i] = *(const short8*)(Ac + (size_t)(ra*8 + (dcx ^ (ra & 7)))*8);
        int rb = nh + i*16 + m;
        bf[i] = *(const short8*)(Bc + (size_t)(rb*8 + (dcx ^ (rb & 7)))*8);
      }
      #pragma unroll
      for (int i = 0; i < 4; ++i)
        #pragma unroll
        for (int j = 0; j < 4; ++j)
          acc[i][j] = __builtin_amdgcn_mfma_f32_16x16x32_bf16(af[i], bf[j], acc[i][j], 0, 0, 0);
    }
    __syncthreads();   // drains prefetch (vmcnt) + ds_reads (lgkm); WAR-safe
    cur = nxt;
  }
  #undef GSTAGE

  // C/D layout: row_local = quad*4+r, col_local = m
  #pragma unroll
  for (int i = 0; i < 4; ++i){
    #pragma unroll
    for (int j = 0; j < 4; ++j){
      int col = n0 + nh + j*16 + m;
      #pragma unroll
      for (int r = 0; r < 4; ++r){
        int row = m0 + mh + i*16 + quad*4 + r;
        float v = acc[i][j][r];
        if (EPI == 0){
          Cf[(size_t)row*N + col] = v + bias0[col];
        } else if (EPI == 1){
          C16a[(size_t)row*N + col] = f2b(fmaxf(v + bias0[col], 0.f));
        } else {
          int sel = col >> 9, n5 = col & 511;
          const float* bp = (sel == 0) ? bias0 : (sel == 1) ? bias1 : bias2;
          float vv = v + bp[n5];
          int d = n5 & 63, hh = n5 >> 6;
          int b = row >> 11, s = row & 2047;
          size_t idx = (((size_t)(b*8 + hh))*2048 + s)*64 + d;
          if (sel == 0)      C16a[idx] = f2b(vv);
          else if (sel == 1) C16b[idx] = f2b(vv);
          else               Cv[idx]  = vv;
        }
      }
    }
  }
}

// ---------------- fused MFMA scores + top-35 + softmax + P@V[:35] ----------------
// Selection:
//   1. per-lane packed top-2 of its 32 keys
//   2. T' (rank-35 of the 128 top-2 values, per query) via 16-step binary
//      search on the u16 key space using ballot+popcount
//   3. compact candidates (>= T') to LDS, capacity 128 (de-chained index)
//   4. bitonic sort-128 of candidates -> ranks 0..34 live in lanes 0..34
//   5. softmax once per rank; weights broadcast via v_readlane (no LDS)
// Score phase: depth-2 software-pipelined K loads.
// XCD-aware block swizzle: consecutive q-tiles of one bh share an XCD L2.
__global__ __launch_bounds__(512, 8) void attn_mfma_topk(
    const u16* __restrict__ qb16, const u16* __restrict__ kb16,
    const float* __restrict__ vb, u16* __restrict__ aob16){
  __shared__ unsigned pr[8*1024];   // 32 KB
  int tid  = threadIdx.x;
  int w    = tid >> 6, l = tid & 63;
  int quad = l >> 4,  m = l & 15;
  // bijective XCD swizzle over 4096 blocks (128 x 32)
  int orig = blockIdx.y * 128 + blockIdx.x;
  int t4   = ((orig & 7) << 9) | (orig >> 3);
  int bh   = t4 >> 7;
  int q0   = (t4 & 127) << 4;

  const u16* Qp = qb16 + ((size_t)bh*2048 + q0 + m)*64 + quad*8;
  short8 a0 = *(const short8*)Qp;
  short8 a1 = *(const short8*)(Qp + 32);

  const u16* Kbase = kb16 + (size_t)bh*2048*64;
  unsigned sc[32];
  int swz = (quad & 1) << 4;
  const u16* kp0 = Kbase + (size_t)(w*128 + m)*64 + quad*8;
  // tile t (0..15): row offset = (t>>3)*1024 + (t&7)*16
  const uint4* p4 = (const uint4*)(pr + w*1024);

  short8 cb0 = *(const short8*)kp0;
  short8 cb1 = *(const short8*)(kp0 + 32);
  #pragma unroll
  for (int t = 0; t < 16; ++t){
    short8 nb0, nb1;
    if (t < 15){
      int tn = t + 1;
      const u16* np = kp0 + (size_t)(((tn >> 3) << 10) + ((tn & 7) << 4))*64;
      nb0 = *(const short8*)np;
      nb1 = *(const short8*)(np + 32);
    }
    float4v acc = {0.f, 0.f, 0.f, 0.f};
    acc = __builtin_amdgcn_mfma_f32_16x16x32_bf16(a0, cb0, acc, 0, 0, 0);
    acc = __builtin_amdgcn_mfma_f32_16x16x32_bf16(a1, cb1, acc, 0, 0, 0);
    int lk = (w << 7) + ((t & 7) << 4);
    #pragma unroll
    for (int c = 0; c < 2; ++c){
      unsigned lo = key_of(acc[2*c]);
      unsigned hi = key_of(acc[2*c+1]);
      pr[(quad*2 + c)*1024 + ((lk + m) ^ swz)] = lo | (hi << 16);
    }
    cb0 = nb0; cb1 = nb1;
    if (t == 7){
      __syncthreads();
      #pragma unroll
      for (int j = 0; j < 4; ++j){
        uint4 v4 = p4[j*64 + l];
        sc[j*4+0] = v4.x; sc[j*4+1] = v4.y; sc[j*4+2] = v4.z; sc[j*4+3] = v4.w;
      }
      __syncthreads();
    }
  }
  __syncthreads();
  #pragma unroll
  for (int j = 0; j < 4; ++j){
    uint4 v4 = p4[j*64 + l];
    sc[16+j*4+0] = v4.x; sc[16+j*4+1] = v4.y; sc[16+j*4+2] = v4.z; sc[16+j*4+3] = v4.w;
  }

  unsigned* row = &pr[w*1024];   // wave-private scratch from here on

  // ---- per-lane packed top-2 ----
  unsigned m1 = pkmax(sc[0], sc[1]);
  unsigned m2 = pkmin(sc[0], sc[1]);
  #pragma unroll
  for (int i = 2; i < 32; ++i){
    unsigned v = sc[i];
    unsigned nm1 = pkmax(m1, v);
    m2 = pkmax(m2, pkmin(m1, v));
    m1 = nm1;
  }

  // ---- T' via binary search on key space (rank-35 of the 128 top-2s) ----
  unsigned mA1 = m1 & 0xFFFFu, mB1 = m1 >> 16;
  unsigned mA2 = m2 & 0xFFFFu, mB2 = m2 >> 16;
  unsigned tA = 0, tB = 0;
  #pragma unroll
  for (int bit = 15; bit >= 0; --bit){
    unsigned cA = tA | (1u << bit);
    unsigned cB = tB | (1u << bit);
    int nA = __popcll(__ballot(mA1 >= cA)) + __popcll(__ballot(mA2 >= cA));
    int nB = __popcll(__ballot(mB1 >= cB)) + __popcll(__ballot(mB2 >= cB));
    if (nA >= TOPK) tA = cA;
    if (nB >= TOPK) tB = cB;
  }
  unsigned TT = (tA - 1) | ((tB - 1) << 16);   // per-half threshold-minus-1

  // ---- survivor mask: slot survives iff (A >= tA) || (B >= tB) ----
  unsigned mask = 0;
  #pragma unroll
  for (int i = 0; i < 32; ++i){
    mask |= (pkmax(sc[i], TT) != TT) ? (1u << i) : 0u;
  }
  int cnt = __popc(mask);

  // exclusive prefix over lanes
  int pre = cnt;
  #pragma unroll
  for (int off = 1; off < 64; off <<= 1){
    int n = __shfl_up(pre, off, 64);
    if (l >= off) pre += n;
  }
  pre -= cnt;

  // compact survivors into LDS (wave-private row; capacity 128).
  // position = pre + popc(lower set bits): no serial dependence.
  #pragma unroll
  for (int i = 0; i < 32; ++i){
    if (mask & (1u << i)){
      int p = pre + __popc(mask & ((1u << i) - 1u));
      if (p < 128) row[p] = sc[i];
    }
  }
  int tot = __shfl(pre + cnt, 63, 64);   // total candidate count

  // read back, pad with 0 (key 0 < any real key)
  unsigned c0 = (l < tot)      ? row[l]      : 0u;
  unsigned c1 = (64 + l < tot) ? row[64 + l] : 0u;

  // V rows 0..34 (loads overlap with the sort below)
  const float* Vb = vb + (size_t)bh*2048*64 + l;   // lane = d
  float vreg[TOPK];
  #pragma unroll
  for (int r = 0; r < TOPK; ++r) vreg[r] = Vb[(size_t)r*64];

  // ---- final sort: ranks 0..34 end up in c0, lanes 0..34 ----
  bsort128(c0, c1, l);

  // ---- softmax weights, computed once per rank ----
  unsigned top0 = (unsigned)__shfl((int)c0, 0, 64);
  float mAf = key_to_f(top0 & 0xFFFFu) * 0.125f;
  float mBf = key_to_f(top0 >> 16)     * 0.125f;
  float tvA = key_to_f(c0 & 0xFFFFu)   * 0.125f;
  float tvB = key_to_f(c0 >> 16)       * 0.125f;
  float wAv = (l < TOPK) ? __expf(tvA - mAf) : 0.f;
  float wBv = (l < TOPK) ? __expf(tvB - mBf) : 0.f;

  float dA = wAv, dB = wBv;
  #pragma unroll
  for (int off = 32; off > 0; off >>= 1){
    dA += __shfl_xor(dA, off, 64);
    dB += __shfl_xor(dB, off, 64);
  }

  // PV: weight of rank r broadcast from lane r via readlane (SGPR), no LDS
  float accA = 0.f, accB = 0.f;
  #pragma unroll
  for (int r = 0; r < TOPK; ++r){
    float wA = __uint_as_float((unsigned)__builtin_amdgcn_readlane((int)__float_as_uint(wAv), r));
    float wB = __uint_as_float((unsigned)__builtin_amdgcn_readlane((int)__float_as_uint(wBv), r));
    float vv = vreg[r];
    accA += wA * vv;
    accB += wB * vv;
  }
  accA *= __builtin_amdgcn_rcpf(dA);
  accB *= __builtin_amdgcn_rcpf(dB);

  int b = bh >> 3, hh = bh & 7;
  int sA = q0 + w*2;
  aob16[(((size_t)(b*2048 + sA))*8 + hh)*64 + l]     = f2b(accA);
  aob16[(((size_t)(b*2048 + sA + 1))*8 + hh)*64 + l] = f2b(accB);
}

// ---------------- h = LayerNorm(h + t) * g + b, in place; also bf16 copy ----------------
// float4-vectorized (16B/lane), 2 tokens per block (waves 0,1 -> token A;
// waves 2,3 -> token B).
__global__ void resid_ln_kernel(float* __restrict__ h, const float* __restrict__ t,
                                const float* __restrict__ g, const float* __restrict__ b,
                                u16* __restrict__ h16){
  int half = threadIdx.x >> 7;             // 0 or 1
  int tok  = blockIdx.x*2 + half;
  int tid  = threadIdx.x & 127;            // float4 col index 0..127
  size_t base4 = (size_t)tok * 128;        // float4 units per row
  float4 hv = ((const float4*)h)[base4 + tid];
  float4 tv = ((const float4*)t)[base4 + tid];
  float x0 = hv.x + tv.x, x1 = hv.y + tv.y;
  float x2 = hv.z + tv.z, x3 = hv.w + tv.w;
  __shared__ float red[8];
  int wid = threadIdx.x >> 6, lane = threadIdx.x & 63;

  float s = (x0 + x1) + (x2 + x3);
  #pragma unroll
  for (int off = 32; off > 0; off >>= 1) s += __shfl_xor(s, off, 64);
  if (lane == 0) red[wid] = s;
  __syncthreads();
  int hb = half << 1;
  float mean = (red[hb] + red[hb+1]) * (1.f/512.f);

  float d0 = x0 - mean, d1 = x1 - mean, d2 = x2 - mean, d3 = x3 - mean;
  float sq = (d0*d0 + d1*d1) + (d2*d2 + d3*d3);
  #pragma unroll
  for (int off = 32; off > 0; off >>= 1) sq += __shfl_xor(sq, off, 64);
  if (lane == 0) red[4 + wid] = sq;
  __syncthreads();
  float var = (red[4 + hb] + red[4 + hb + 1]) * (1.f/512.f);
  float inv = rsqrtf(var + 1e-5f);
  float4 gv = ((const float4*)g)[tid];
  float4 bv = ((const float4*)b)[tid];
  float o0 = d0 * inv * gv.x + bv.x;
  float o1 = d1 * inv * gv.y + bv.y;
  float o2 = d2 * inv * gv.z + bv.z;
  float o3 = d3 * inv * gv.w + bv.w;
  ((float4*)h)[base4 + tid] = make_float4(o0, o1, o2, o3);
  uint2 pk;
  pk.x = (unsigned)f2b(o0) | ((unsigned)f2b(o1) << 16);
  pk.y = (unsigned)f2b(o2) | ((unsigned)f2b(o3) << 16);
  ((uint2*)h16)[base4 + tid] = pk;
}

// ---------------- mean over sequence: partial sums (no atomics, no zero-pass) ----------------
__global__ void pool_kernel(const float* __restrict__ h, float* __restrict__ part){
  int c = blockIdx.x * 256 + threadIdx.x;   // 0..511
  int b = blockIdx.y;
  int z = blockIdx.z;
  const float* p = h + ((size_t)b * 2048 + z * 64) * 512 + c;
  float acc = 0.f;
  #pragma unroll 8
  for (int s = 0; s < 64; ++s) acc += p[(size_t)s * 512];
  part[((size_t)(z*4 + b))*512 + c] = acc;
}

// ---------------- tiny decoder (sums the 32 pool partials) ----------------
__global__ void decoder_kernel(const float* __restrict__ part,
                               const float* __restrict__ w1, const float* __restrict__ b1,
                               const float* __restrict__ w2, const float* __restrict__ b2,
                               float* __restrict__ out){
  __shared__ float ps[4][512];
  __shared__ float hid[4][256];
  int tid = threadIdx.x;
  for (int i = tid; i < 2048; i += 256){
    int b = i >> 9, c = i & 511;
    float s = 0.f;
    #pragma unroll
    for (int z = 0; z < 32; ++z) s += part[((size_t)(z*4 + b))*512 + c];
    ps[b][c] = s * (1.f/2048.f);
  }
  __syncthreads();
  float bb = b1[tid];
  for (int b = 0; b < 4; ++b){
    float acc = bb;
    for (int k = 0; k < 512; ++k) acc += ps[b][k] * w1[k*256 + tid];
    hid[b][tid] = fmaxf(acc, 0.f);
  }
  __syncthreads();
  if (tid < 8){
    int b = tid >> 1, c = tid & 1;
    float acc = b2[c];
    for (int j = 0; j < 256; ++j) acc += hid[b][j] * w2[j*2 + c];
    out[b*2 + c] = acc;
  }
}

extern "C" void kernel_launch(void* const* d_in, const int* in_sizes, int n_in,
                              void* d_out, int out_size, void* d_ws, size_t ws_size,
                              hipStream_t stream){
  const float* x     = (const float*)d_in[0];
  const float* emb_w = (const float*)d_in[1];
  const float* emb_b = (const float*)d_in[2];
  const float* wq    = (const float*)d_in[3];
  const float* bq    = (const float*)d_in[4];
  const float* wk    = (const float*)d_in[5];
  const float* bk    = (const float*)d_in[6];
  const float* wv    = (const float*)d_in[7];
  const float* bv    = (const float*)d_in[8];
  const float* wo    = (const float*)d_in[9];
  const float* bo    = (const float*)d_in[10];
  const float* ff1w  = (const float*)d_in[11];
  const float* ff1b  = (const float*)d_in[12];
  const float* ff2w  = (const float*)d_in[13];
  const float* ff2b  = (const float*)d_in[14];
  const float* ln1g  = (const float*)d_in[15];
  const float* ln1b  = (const float*)d_in[16];
  const float* ln2g  = (const float*)d_in[17];
  const float* ln2b  = (const float*)d_in[18];
  const float* d1w   = (const float*)d_in[19];
  const float* d1b   = (const float*)d_in[20];
  const float* d2w   = (const float*)d_in[21];
  const float* d2b   = (const float*)d_in[22];

  // ---- workspace layout (~92 MB) ----
  float* h      = (float*)d_ws;
  float* tmp    = h + NT512;
  u16*   u      = (u16*)(tmp + NT512);
  u16*   h16    = u;
  u16*   q16    = u + NT512;
  u16*   k16    = u + 2*NT512;
  float* vb     = (float*)(u + 3*NT512);
  u16*   ff16   = q16;                 // 32 MB overlay of q16+k16+vb
  u16*   aob16  = (u16*)(vb + NT512);
  u16*   wt     = aob16 + NT512;
  u16*   wt_qkv = wt;                          // 2 x 1536*512
  u16*   wt_wo  = wt_qkv + (size_t)2*1536*512; // 2 x 512*512
  u16*   wt_ff1 = wt_wo  + (size_t)2*512*512;  // 2 x 2048*512
  u16*   wt_ff2 = wt_ff1 + (size_t)2*2048*512; // 2 x 512*2048
  float* part   = tmp;                 // pool partials [32][4][512] in dead tmp

  WtArgs wa{wq, wk, wv, wo, ff1w, ff2w, wt_qkv, wt_wo, wt_ff1, wt_ff2};
  prep_kernel<<<8192, 256, 0, stream>>>(wa, x, emb_w, emb_b, h, h16);

  for (int l = 0; l < 2; ++l){
    // fused QKV: N=1536, scatter epilogue
    gemm_mfma<2><<<dim3(12, 64), 256, 0, stream>>>(
        h16, 512, wt_qkv + (size_t)l*1536*512, 512,
        bq + l*512, bk + l*512, bv + l*512,
        nullptr, q16, k16, vb, NTOK, 1536, 512);

    attn_mfma_topk<<<dim3(128, 32), 512, 0, stream>>>(q16, k16, vb, aob16);

    gemm_mfma<0><<<dim3(4, 64), 256, 0, stream>>>(
        aob16, 512, wt_wo + (size_t)l*512*512, 512,
        bo + l*512, nullptr, nullptr,
        tmp, nullptr, nullptr, nullptr, NTOK, 512, 512);
    resid_ln_kernel<<<NTOK/2, 256, 0, stream>>>(h, tmp, ln1g + l*512, ln1b + l*512, h16);

    gemm_mfma<1><<<dim3(16, 64), 256, 0, stream>>>(
        h16, 512, wt_ff1 + (size_t)l*2048*512, 512,
        ff1b + l*2048, nullptr, nullptr,
        nullptr, ff16, nullptr, nullptr, NTOK, 2048, 512);

    gemm_mfma<0><<<dim3(4, 64), 256, 0, stream>>>(
        ff16, 2048, wt_ff2 + (size_t)l*512*2048, 2048,
        ff2b + l*512, nullptr, nullptr,
        tmp, nullptr, nullptr, nullptr, NTOK, 512, 2048);
    resid_ln_kernel<<<NTOK/2, 256, 0, stream>>>(h, tmp, ln2g + l*512, ln2b + l*512, h16);
  }

  pool_kernel<<<dim3(2, 4, 32), 256, 0, stream>>>(h, part);
  decoder_kernel<<<1, 256, 0, stream>>>(part, d1w, d1b, d2w, d2b, (float*)d_out);
}

// Round 8
// 689.254 us; speedup vs baseline: 1.2876x; 1.0149x over previous
//
#include <hip/hip_runtime.h>
#include <cmath>

typedef unsigned short u16;
typedef __attribute__((ext_vector_type(8))) short short8;
typedef __attribute__((ext_vector_type(4))) float float4v;
typedef unsigned short ushort2v __attribute__((ext_vector_type(2)));

#define S_LEN 2048
#define NTOK  8192   // B*S
#define TOPK  35
#define NT512 ((size_t)NTOK*512)

__device__ __forceinline__ u16 f2b(float f){
  unsigned int x = __float_as_uint(f);
  unsigned int r = (x + 0x7fffu + ((x >> 16) & 1u)) >> 16;
  return (u16)r;
}

// bf16(f) -> monotone-increasing u16 sort key (no NaNs assumed)
__device__ __forceinline__ unsigned key_of(float f){
  unsigned u = (unsigned)f2b(f);
  unsigned m = (u & 0x8000u) ? 0xFFFFu : 0x8000u;
  return (u ^ m) & 0xFFFFu;
}
__device__ __forceinline__ float key_to_f(unsigned key){
  unsigned m = (key & 0x8000u) ? 0x8000u : 0xFFFFu;
  return __uint_as_float(((key ^ m) & 0xFFFFu) << 16);
}
// packed u16x2 of bf16 bit patterns -> monotone sort keys, both halves at
// once. Per half: key = u ^ (sign ? 0xFFFF : 0x8000). Carry/borrow across
// the halves cancels exactly (verified all 4 sign combos):
//   lo-neg: 0x8000+0x8000-1 = 0xFFFF, bit16 carry reclaimed by the borrow.
__device__ __forceinline__ unsigned key2_of(unsigned u){
  unsigned t = (u >> 15) & 0x00010001u;
  unsigned mask = 0x80008000u + (t << 15) - t;
  return u ^ mask;
}
__device__ __forceinline__ unsigned pkmax(unsigned a, unsigned b){
  union { unsigned u; ushort2v v; } x, y, r;
  x.u = a; y.u = b;
  r.v = __builtin_elementwise_max(x.v, y.v);
  return r.u;
}
__device__ __forceinline__ unsigned pkmin(unsigned a, unsigned b){
  union { unsigned u; ushort2v v; } x, y, r;
  x.u = a; y.u = b;
  r.v = __builtin_elementwise_min(x.v, y.v);
  return r.u;
}

// full bitonic sort, DESCENDING, of 128 packed-u16x2 values distributed
// 2 per lane: element e = l (v0) and e = 64+l (v1). Sorts both u16 halves
// independently (pk ops are per-half).
__device__ __forceinline__ void bsort128(unsigned &v0, unsigned &v1, int l){
  #pragma unroll
  for (int k = 2; k <= 128; k <<= 1){
    #pragma unroll
    for (int j = k >> 1; j > 0; j >>= 1){
      if (j == 64){
        unsigned hi = pkmax(v0, v1), lo = pkmin(v0, v1);
        v0 = hi; v1 = lo;
      } else {
        unsigned o0 = (unsigned)__shfl_xor((int)v0, j, 64);
        unsigned o1 = (unsigned)__shfl_xor((int)v1, j, 64);
        bool up0 = (((l & k) == 0) != ((l & j) != 0));
        bool up1 = ((((64 + l) & k) == 0) != ((l & j) != 0));
        unsigned hi0 = pkmax(v0, o0), lo0 = pkmin(v0, o0);
        unsigned hi1 = pkmax(v1, o1), lo1 = pkmin(v1, o1);
        v0 = up0 ? hi0 : lo0;
        v1 = up1 ? hi1 : lo1;
      }
    }
  }
}

// async global->LDS 16B direct copy; LDS dest pattern = wave-uniform base + lane*16
__device__ __forceinline__ void gload16(const void* g, void* l){
  __builtin_amdgcn_global_load_lds(
      (const __attribute__((address_space(1))) unsigned int*)g,
      (__attribute__((address_space(3))) unsigned int*)l, 16, 0, 0);
}

// ---------------- fused prep: weight transpose/convert + embedding ----------------
// blocks 0..6143: weight tiles (tt = bx%3072, layer = bx/3072).
// blocks 6144..8191: embedding, 4 tokens per block (w re-read from L2 /4).
struct WtArgs {
  const float* wq; const float* wk; const float* wv; const float* wo;
  const float* ff1w; const float* ff2w;
  u16* wt_qkv; u16* wt_wo; u16* wt_ff1; u16* wt_ff2;
};
__global__ void prep_kernel(WtArgs a,
                            const float* __restrict__ x, const float* __restrict__ w,
                            const float* __restrict__ bias, float* __restrict__ h,
                            u16* __restrict__ h16){
  __shared__ float xs[4][64];          // embed staging (also covers convert's 2.1KB)
  __shared__ u16 t[32][33];
  int bx = blockIdx.x;
  int tid = threadIdx.x;               // 0..255
  if (bx < 6144){
    int l  = (bx >= 3072) ? 1 : 0;
    int tt = bx - l*3072;
    const float* W; u16* Wt; int K, N, tx_, ty_;
    if (tt < 1024){                 // qkv (3 segs) + wo, all 512x512, 16x16 tiles
      int seg = tt >> 8, r = tt & 255;
      tx_ = r & 15; ty_ = r >> 4; K = 512; N = 512;
      if (seg == 0){ W = a.wq + (size_t)l*262144; Wt = a.wt_qkv + (size_t)l*786432; }
      else if (seg == 1){ W = a.wk + (size_t)l*262144; Wt = a.wt_qkv + (size_t)l*786432 + 262144; }
      else if (seg == 2){ W = a.wv + (size_t)l*262144; Wt = a.wt_qkv + (size_t)l*786432 + 524288; }
      else { W = a.wo + (size_t)l*262144; Wt = a.wt_wo + (size_t)l*262144; }
    } else if (tt < 2048){          // ff1: K=512, N=2048 -> tiles 64 x 16
      int r = tt - 1024;
      tx_ = r & 63; ty_ = r >> 6; K = 512; N = 2048;
      W = a.ff1w + (size_t)l*1048576; Wt = a.wt_ff1 + (size_t)l*1048576;
    } else {                        // ff2: K=2048, N=512 -> tiles 16 x 64
      int r = tt - 2048;
      tx_ = r & 15; ty_ = r >> 4; K = 2048; N = 512;
      W = a.ff2w + (size_t)l*1048576; Wt = a.wt_ff2 + (size_t)l*1048576;
    }
    int k0 = ty_*32, n0 = tx_*32;
    int tx = tid & 31, ty = tid >> 5;   // 32x8
    #pragma unroll
    for (int i = ty; i < 32; i += 8)
      t[i][tx] = f2b(W[(size_t)(k0+i)*N + n0+tx]);
    __syncthreads();
    #pragma unroll
    for (int i = ty; i < 32; i += 8)
      Wt[(size_t)(n0+i)*K + k0+tx] = t[tx][i];
  } else {
    int t0 = (bx - 6144) * 4;          // 4 tokens per block
    xs[tid >> 6][tid & 63] = x[(size_t)(t0 + (tid >> 6))*64 + (tid & 63)];
    __syncthreads();
    float b0 = bias[tid], b1 = bias[tid + 256];
    float acc[4][2];
    #pragma unroll
    for (int tk = 0; tk < 4; ++tk){ acc[tk][0] = b0; acc[tk][1] = b1; }
    #pragma unroll 8
    for (int k = 0; k < 64; ++k){
      float w0 = w[k*512 + tid];
      float w1 = w[k*512 + tid + 256];
      #pragma unroll
      for (int tk = 0; tk < 4; ++tk){
        float xv = xs[tk][k];
        acc[tk][0] += xv * w0;
        acc[tk][1] += xv * w1;
      }
    }
    const float neg_ln1e4_over_D = -9.210340371976184f / 512.f;
    int c0 = tid, c1 = tid + 256;
    float e0 = expf((float)(c0 & ~1) * neg_ln1e4_over_D);
    float e1 = expf((float)(c1 & ~1) * neg_ln1e4_over_D);
    #pragma unroll
    for (int tk = 0; tk < 4; ++tk){
      int tok = t0 + tk;
      int s = tok & (S_LEN - 1);
      float a0 = (float)s * e0;
      float p0 = (c0 & 1) ? cosf(a0) : sinf(a0);
      float a1 = (float)s * e1;
      float p1 = (c1 & 1) ? cosf(a1) : sinf(a1);
      float v0 = acc[tk][0] + p0, v1 = acc[tk][1] + p1;
      h[(size_t)tok*512 + c0] = v0;  h16[(size_t)tok*512 + c0] = f2b(v0);
      h[(size_t)tok*512 + c1] = v1;  h16[(size_t)tok*512 + c1] = f2b(v1);
    }
  }
}

// ---------------- bf16 MFMA GEMM: C = A[M,lda] @ Bt[N,ldb]^T + bias ----------------
// XCD-aware bijective tile swizzle. DBUF=1: 2-phase double-buffered pipeline
// (for 1-block/CU shapes: WO/FF2 — no TLP to hide staging latency).
// DBUF=0: single-buffer 32 KB (for QKV/FF1: 3-4 blocks/CU provide TLP;
// 64 KB dbuf would cut them to 2 blocks/CU — measured net loss in R7).
// EPI 2 additionally predicates the V write on s<TOPK (attn reads only
// rows 0..34 per bh; saves ~16 MB of dead HBM writes).
template<int EPI, int DBUF>
__global__ __launch_bounds__(256) void gemm_mfma(
    const u16* __restrict__ A, int lda, const u16* __restrict__ Bt, int ldb,
    const float* __restrict__ bias0, const float* __restrict__ bias1,
    const float* __restrict__ bias2,
    float* __restrict__ Cf, u16* __restrict__ C16a, u16* __restrict__ C16b,
    float* __restrict__ Cv, int M, int N, int Klen){
  __shared__ __align__(16) u16 As[(DBUF ? 2 : 1)*128*64];
  __shared__ __align__(16) u16 Bs[(DBUF ? 2 : 1)*128*64];
  int tid = threadIdx.x;
  int w = tid >> 6, l = tid & 63, quad = l >> 4, m = l & 15;
  int gx = gridDim.x;
  int orig = blockIdx.y * gx + blockIdx.x;
  int nwg  = gx * gridDim.y;
  int tt   = (orig & 7) * (nwg >> 3) + (orig >> 3);
  int m0 = (tt / gx) * 128, n0 = (tt % gx) * 128;
  int mh = (w >> 1)*64, nh = (w & 1)*64;
  float4v acc[4][4];
  #pragma unroll
  for (int i = 0; i < 4; ++i)
    #pragma unroll
    for (int j = 0; j < 4; ++j) acc[i][j] = (float4v){0.f,0.f,0.f,0.f};

  // stage K-tile kt into buffer half ofs
  #define GSTAGE(ofs, kt) do { \
    _Pragma("unroll") \
    for (int c = 0; c < 4; ++c){ \
      int g = c*256 + tid; \
      int row = g >> 3, scx = g & 7, dc = scx ^ (row & 7); \
      gload16(A  + (size_t)(m0+row)*lda + (kt) + dc*8, As + (ofs) + (size_t)g*8); \
      gload16(Bt + (size_t)(n0+row)*ldb + (kt) + dc*8, Bs + (ofs) + (size_t)g*8); \
    } } while(0)

  #define GCOMPUTE(Ac, Bc) do { \
    _Pragma("unroll") \
    for (int kk = 0; kk < 2; ++kk){ \
      short8 af[4], bf[4]; \
      _Pragma("unroll") \
      for (int i = 0; i < 4; ++i){ \
        int dcx = kk*4 + quad; \
        int ra = mh + i*16 + m; \
        af[i] = *(const short8*)((Ac) + (size_t)(ra*8 + (dcx ^ (ra & 7)))*8); \
        int rb = nh + i*16 + m; \
        bf[i] = *(const short8*)((Bc) + (size_t)(rb*8 + (dcx ^ (rb & 7)))*8); \
      } \
      _Pragma("unroll") \
      for (int i = 0; i < 4; ++i) \
        _Pragma("unroll") \
        for (int j = 0; j < 4; ++j) \
          acc[i][j] = __builtin_amdgcn_mfma_f32_16x16x32_bf16(af[i], bf[j], acc[i][j], 0, 0, 0); \
    } } while(0)

  if (DBUF){
    GSTAGE(0, 0);
    __syncthreads();                       // vmcnt(0) auto-inserted: buf0 ready
    int cur = 0;
    for (int kt = 0; kt < Klen; kt += 64){
      int nxt = cur ^ 1;
      if (kt + 64 < Klen) GSTAGE(nxt*(128*64), kt + 64);   // prefetch in flight
      GCOMPUTE(As + cur*(128*64), Bs + cur*(128*64));
      __syncthreads();   // drains prefetch (vmcnt) + ds_reads (lgkm); WAR-safe
      cur = nxt;
    }
  } else {
    for (int kt = 0; kt < Klen; kt += 64){
      GSTAGE(0, kt);
      __syncthreads();
      GCOMPUTE(As, Bs);
      __syncthreads();
    }
  }
  #undef GSTAGE
  #undef GCOMPUTE

  // C/D layout: row_local = quad*4+r, col_local = m
  #pragma unroll
  for (int i = 0; i < 4; ++i){
    #pragma unroll
    for (int j = 0; j < 4; ++j){
      int col = n0 + nh + j*16 + m;
      #pragma unroll
      for (int r = 0; r < 4; ++r){
        int row = m0 + mh + i*16 + quad*4 + r;
        float v = acc[i][j][r];
        if (EPI == 0){
          Cf[(size_t)row*N + col] = v + bias0[col];
        } else if (EPI == 1){
          C16a[(size_t)row*N + col] = f2b(fmaxf(v + bias0[col], 0.f));
        } else {
          int sel = col >> 9, n5 = col & 511;
          const float* bp = (sel == 0) ? bias0 : (sel == 1) ? bias1 : bias2;
          float vv = v + bp[n5];
          int d = n5 & 63, hh = n5 >> 6;
          int b = row >> 11, s = row & 2047;
          size_t idx = (((size_t)(b*8 + hh))*2048 + s)*64 + d;
          if (sel == 0)      C16a[idx] = f2b(vv);
          else if (sel == 1) C16b[idx] = f2b(vv);
          else if (s < TOPK) Cv[idx]  = vv;   // attn reads only V rows 0..34
        }
      }
    }
  }
}

// ---------------- fused MFMA scores + top-35 + softmax + P@V[:35] ----------------
// Selection:
//   1. per-lane packed top-2 of its 32 keys
//   2. T' (rank-35 of the 128 top-2 values, per query) via 16-step binary
//      search on the u16 key space using ballot+popcount
//   3. compact candidates (>= T') to LDS, capacity 128 (de-chained index)
//   4. bitonic sort-128 of candidates -> ranks 0..34 live in lanes 0..34
//   5. softmax once per rank; weights broadcast via v_readlane (no LDS)
// Score keys: packed bit-exact path (same arithmetic as f2b/key_of, both
// halves converted together; R3's cvt_pk instruction NOT used).
__global__ __launch_bounds__(512, 8) void attn_mfma_topk(
    const u16* __restrict__ qb16, const u16* __restrict__ kb16,
    const float* __restrict__ vb, u16* __restrict__ aob16){
  __shared__ unsigned pr[8*1024];   // 32 KB
  int tid  = threadIdx.x;
  int w    = tid >> 6, l = tid & 63;
  int quad = l >> 4,  m = l & 15;
  // bijective XCD swizzle over 4096 blocks (128 x 32)
  int orig = blockIdx.y * 128 + blockIdx.x;
  int t4   = ((orig & 7) << 9) | (orig >> 3);
  int bh   = t4 >> 7;
  int q0   = (t4 & 127) << 4;

  const u16* Qp = qb16 + ((size_t)bh*2048 + q0 + m)*64 + quad*8;
  short8 a0 = *(const short8*)Qp;
  short8 a1 = *(const short8*)(Qp + 32);

  const u16* Kbase = kb16 + (size_t)bh*2048*64;
  unsigned sc[32];
  int swz = (quad & 1) << 4;
  const u16* kp0 = Kbase + (size_t)(w*128 + m)*64 + quad*8;
  // tile t (0..15): row offset = (t>>3)*1024 + (t&7)*16
  const uint4* p4 = (const uint4*)(pr + w*1024);

  short8 cb0 = *(const short8*)kp0;
  short8 cb1 = *(const short8*)(kp0 + 32);
  #pragma unroll
  for (int t = 0; t < 16; ++t){
    short8 nb0, nb1;
    if (t < 15){
      int tn = t + 1;
      const u16* np = kp0 + (size_t)(((tn >> 3) << 10) + ((tn & 7) << 4))*64;
      nb0 = *(const short8*)np;
      nb1 = *(const short8*)(np + 32);
    }
    float4v acc = {0.f, 0.f, 0.f, 0.f};
    acc = __builtin_amdgcn_mfma_f32_16x16x32_bf16(a0, cb0, acc, 0, 0, 0);
    acc = __builtin_amdgcn_mfma_f32_16x16x32_bf16(a1, cb1, acc, 0, 0, 0);
    int lk = (w << 7) + ((t & 7) << 4);
    #pragma unroll
    for (int c = 0; c < 2; ++c){
      // packed RNE bf16 round of (acc[2c], acc[2c+1]) -> u16x2, then
      // packed sort-key transform. Bit-exact vs key_of|key_of<<16.
      unsigned xa = __float_as_uint(acc[2*c]);
      unsigned xb = __float_as_uint(acc[2*c+1]);
      unsigned ta = xa + 0x7fffu + ((xa >> 16) & 1u);
      unsigned tb = xb + 0x7fffu + ((xb >> 16) & 1u);
      unsigned pk = (ta >> 16) | (tb & 0xFFFF0000u);
      pr[(quad*2 + c)*1024 + ((lk + m) ^ swz)] = key2_of(pk);
    }
    cb0 = nb0; cb1 = nb1;
    if (t == 7){
      __syncthreads();
      #pragma unroll
      for (int j = 0; j < 4; ++j){
        uint4 v4 = p4[j*64 + l];
        sc[j*4+0] = v4.x; sc[j*4+1] = v4.y; sc[j*4+2] = v4.z; sc[j*4+3] = v4.w;
      }
      __syncthreads();
    }
  }
  __syncthreads();
  #pragma unroll
  for (int j = 0; j < 4; ++j){
    uint4 v4 = p4[j*64 + l];
    sc[16+j*4+0] = v4.x; sc[16+j*4+1] = v4.y; sc[16+j*4+2] = v4.z; sc[16+j*4+3] = v4.w;
  }

  unsigned* row = &pr[w*1024];   // wave-private scratch from here on

  // ---- per-lane packed top-2 ----
  unsigned m1 = pkmax(sc[0], sc[1]);
  unsigned m2 = pkmin(sc[0], sc[1]);
  #pragma unroll
  for (int i = 2; i < 32; ++i){
    unsigned v = sc[i];
    unsigned nm1 = pkmax(m1, v);
    m2 = pkmax(m2, pkmin(m1, v));
    m1 = nm1;
  }

  // ---- T' via binary search on key space (rank-35 of the 128 top-2s) ----
  unsigned mA1 = m1 & 0xFFFFu, mB1 = m1 >> 16;
  unsigned mA2 = m2 & 0xFFFFu, mB2 = m2 >> 16;
  unsigned tA = 0, tB = 0;
  #pragma unroll
  for (int bit = 15; bit >= 0; --bit){
    unsigned cA = tA | (1u << bit);
    unsigned cB = tB | (1u << bit);
    int nA = __popcll(__ballot(mA1 >= cA)) + __popcll(__ballot(mA2 >= cA));
    int nB = __popcll(__ballot(mB1 >= cB)) + __popcll(__ballot(mB2 >= cB));
    if (nA >= TOPK) tA = cA;
    if (nB >= TOPK) tB = cB;
  }
  unsigned TT = (tA - 1) | ((tB - 1) << 16);   // per-half threshold-minus-1

  // ---- survivor mask: slot survives iff (A >= tA) || (B >= tB) ----
  unsigned mask = 0;
  #pragma unroll
  for (int i = 0; i < 32; ++i){
    mask |= (pkmax(sc[i], TT) != TT) ? (1u << i) : 0u;
  }
  int cnt = __popc(mask);

  // exclusive prefix over lanes
  int pre = cnt;
  #pragma unroll
  for (int off = 1; off < 64; off <<= 1){
    int n = __shfl_up(pre, off, 64);
    if (l >= off) pre += n;
  }
  pre -= cnt;

  // compact survivors into LDS (wave-private row; capacity 128).
  // position = pre + popc(lower set bits): no serial dependence.
  #pragma unroll
  for (int i = 0; i < 32; ++i){
    if (mask & (1u << i)){
      int p = pre + __popc(mask & ((1u << i) - 1u));
      if (p < 128) row[p] = sc[i];
    }
  }
  int tot = __shfl(pre + cnt, 63, 64);   // total candidate count

  // read back, pad with 0 (key 0 < any real key)
  unsigned c0 = (l < tot)      ? row[l]      : 0u;
  unsigned c1 = (64 + l < tot) ? row[64 + l] : 0u;

  // V rows 0..34 (loads overlap with the sort below)
  const float* Vb = vb + (size_t)bh*2048*64 + l;   // lane = d
  float vreg[TOPK];
  #pragma unroll
  for (int r = 0; r < TOPK; ++r) vreg[r] = Vb[(size_t)r*64];

  // ---- final sort: ranks 0..34 end up in c0, lanes 0..34 ----
  bsort128(c0, c1, l);

  // ---- softmax weights, computed once per rank ----
  unsigned top0 = (unsigned)__shfl((int)c0, 0, 64);
  float mAf = key_to_f(top0 & 0xFFFFu) * 0.125f;
  float mBf = key_to_f(top0 >> 16)     * 0.125f;
  float tvA = key_to_f(c0 & 0xFFFFu)   * 0.125f;
  float tvB = key_to_f(c0 >> 16)       * 0.125f;
  float wAv = (l < TOPK) ? __expf(tvA - mAf) : 0.f;
  float wBv = (l < TOPK) ? __expf(tvB - mBf) : 0.f;

  float dA = wAv, dB = wBv;
  #pragma unroll
  for (int off = 32; off > 0; off >>= 1){
    dA += __shfl_xor(dA, off, 64);
    dB += __shfl_xor(dB, off, 64);
  }

  // PV: weight of rank r broadcast from lane r via readlane (SGPR), no LDS
  float accA = 0.f, accB = 0.f;
  #pragma unroll
  for (int r = 0; r < TOPK; ++r){
    float wA = __uint_as_float((unsigned)__builtin_amdgcn_readlane((int)__float_as_uint(wAv), r));
    float wB = __uint_as_float((unsigned)__builtin_amdgcn_readlane((int)__float_as_uint(wBv), r));
    float vv = vreg[r];
    accA += wA * vv;
    accB += wB * vv;
  }
  accA *= __builtin_amdgcn_rcpf(dA);
  accB *= __builtin_amdgcn_rcpf(dB);

  int b = bh >> 3, hh = bh & 7;
  int sA = q0 + w*2;
  aob16[(((size_t)(b*2048 + sA))*8 + hh)*64 + l]     = f2b(accA);
  aob16[(((size_t)(b*2048 + sA + 1))*8 + hh)*64 + l] = f2b(accB);
}

// ---------------- h = LayerNorm(h + t) * g + b, in place; also bf16 copy ----------------
// float4-vectorized (16B/lane), 2 tokens per block. h16 write skipped when
// null (the final LN's bf16 copy is never read).
__global__ void resid_ln_kernel(float* __restrict__ h, const float* __restrict__ t,
                                const float* __restrict__ g, const float* __restrict__ b,
                                u16* __restrict__ h16){
  int half = threadIdx.x >> 7;             // 0 or 1
  int tok  = blockIdx.x*2 + half;
  int tid  = threadIdx.x & 127;            // float4 col index 0..127
  size_t base4 = (size_t)tok * 128;        // float4 units per row
  float4 hv = ((const float4*)h)[base4 + tid];
  float4 tv = ((const float4*)t)[base4 + tid];
  float x0 = hv.x + tv.x, x1 = hv.y + tv.y;
  float x2 = hv.z + tv.z, x3 = hv.w + tv.w;
  __shared__ float red[8];
  int wid = threadIdx.x >> 6, lane = threadIdx.x & 63;

  float s = (x0 + x1) + (x2 + x3);
  #pragma unroll
  for (int off = 32; off > 0; off >>= 1) s += __shfl_xor(s, off, 64);
  if (lane == 0) red[wid] = s;
  __syncthreads();
  int hb = half << 1;
  float mean = (red[hb] + red[hb+1]) * (1.f/512.f);

  float d0 = x0 - mean, d1 = x1 - mean, d2 = x2 - mean, d3 = x3 - mean;
  float sq = (d0*d0 + d1*d1) + (d2*d2 + d3*d3);
  #pragma unroll
  for (int off = 32; off > 0; off >>= 1) sq += __shfl_xor(sq, off, 64);
  if (lane == 0) red[4 + wid] = sq;
  __syncthreads();
  float var = (red[4 + hb] + red[4 + hb + 1]) * (1.f/512.f);
  float inv = rsqrtf(var + 1e-5f);
  float4 gv = ((const float4*)g)[tid];
  float4 bv = ((const float4*)b)[tid];
  float o0 = d0 * inv * gv.x + bv.x;
  float o1 = d1 * inv * gv.y + bv.y;
  float o2 = d2 * inv * gv.z + bv.z;
  float o3 = d3 * inv * gv.w + bv.w;
  ((float4*)h)[base4 + tid] = make_float4(o0, o1, o2, o3);
  if (h16){
    uint2 pk;
    pk.x = (unsigned)f2b(o0) | ((unsigned)f2b(o1) << 16);
    pk.y = (unsigned)f2b(o2) | ((unsigned)f2b(o3) << 16);
    ((uint2*)h16)[base4 + tid] = pk;
  }
}

// ---------------- mean over sequence: partial sums (no atomics, no zero-pass) ----------------
__global__ void pool_kernel(const float* __restrict__ h, float* __restrict__ part){
  int c = blockIdx.x * 256 + threadIdx.x;   // 0..511
  int b = blockIdx.y;
  int z = blockIdx.z;
  const float* p = h + ((size_t)b * 2048 + z * 64) * 512 + c;
  float acc = 0.f;
  #pragma unroll 8
  for (int s = 0; s < 64; ++s) acc += p[(size_t)s * 512];
  part[((size_t)(z*4 + b))*512 + c] = acc;
}

// ---------------- tiny decoder (sums the 32 pool partials) ----------------
__global__ void decoder_kernel(const float* __restrict__ part,
                               const float* __restrict__ w1, const float* __restrict__ b1,
                               const float* __restrict__ w2, const float* __restrict__ b2,
                               float* __restrict__ out){
  __shared__ float ps[4][512];
  __shared__ float hid[4][256];
  int tid = threadIdx.x;
  for (int i = tid; i < 2048; i += 256){
    int b = i >> 9, c = i & 511;
    float s = 0.f;
    #pragma unroll
    for (int z = 0; z < 32; ++z) s += part[((size_t)(z*4 + b))*512 + c];
    ps[b][c] = s * (1.f/2048.f);
  }
  __syncthreads();
  float bb = b1[tid];
  for (int b = 0; b < 4; ++b){
    float acc = bb;
    for (int k = 0; k < 512; ++k) acc += ps[b][k] * w1[k*256 + tid];
    hid[b][tid] = fmaxf(acc, 0.f);
  }
  __syncthreads();
  if (tid < 8){
    int b = tid >> 1, c = tid & 1;
    float acc = b2[c];
    for (int j = 0; j < 256; ++j) acc += hid[b][j] * w2[j*2 + c];
    out[b*2 + c] = acc;
  }
}

extern "C" void kernel_launch(void* const* d_in, const int* in_sizes, int n_in,
                              void* d_out, int out_size, void* d_ws, size_t ws_size,
                              hipStream_t stream){
  const float* x     = (const float*)d_in[0];
  const float* emb_w = (const float*)d_in[1];
  const float* emb_b = (const float*)d_in[2];
  const float* wq    = (const float*)d_in[3];
  const float* bq    = (const float*)d_in[4];
  const float* wk    = (const float*)d_in[5];
  const float* bk    = (const float*)d_in[6];
  const float* wv    = (const float*)d_in[7];
  const float* bv    = (const float*)d_in[8];
  const float* wo    = (const float*)d_in[9];
  const float* bo    = (const float*)d_in[10];
  const float* ff1w  = (const float*)d_in[11];
  const float* ff1b  = (const float*)d_in[12];
  const float* ff2w  = (const float*)d_in[13];
  const float* ff2b  = (const float*)d_in[14];
  const float* ln1g  = (const float*)d_in[15];
  const float* ln1b  = (const float*)d_in[16];
  const float* ln2g  = (const float*)d_in[17];
  const float* ln2b  = (const float*)d_in[18];
  const float* d1w   = (const float*)d_in[19];
  const float* d1b   = (const float*)d_in[20];
  const float* d2w   = (const float*)d_in[21];
  const float* d2b   = (const float*)d_in[22];

  // ---- workspace layout (~92 MB) ----
  float* h      = (float*)d_ws;
  float* tmp    = h + NT512;
  u16*   u      = (u16*)(tmp + NT512);
  u16*   h16    = u;
  u16*   q16    = u + NT512;
  u16*   k16    = u + 2*NT512;
  float* vb     = (float*)(u + 3*NT512);
  u16*   ff16   = q16;                 // 32 MB overlay of q16+k16+vb
  u16*   aob16  = (u16*)(vb + NT512);
  u16*   wt     = aob16 + NT512;
  u16*   wt_qkv = wt;                          // 2 x 1536*512
  u16*   wt_wo  = wt_qkv + (size_t)2*1536*512; // 2 x 512*512
  u16*   wt_ff1 = wt_wo  + (size_t)2*512*512;  // 2 x 2048*512
  u16*   wt_ff2 = wt_ff1 + (size_t)2*2048*512; // 2 x 512*2048
  float* part   = tmp;                 // pool partials [32][4][512] in dead tmp

  WtArgs wa{wq, wk, wv, wo, ff1w, ff2w, wt_qkv, wt_wo, wt_ff1, wt_ff2};
  prep_kernel<<<8192, 256, 0, stream>>>(wa, x, emb_w, emb_b, h, h16);

  for (int l = 0; l < 2; ++l){
    // fused QKV: N=1536, scatter epilogue. 768 blocks (3/CU): single-buffer.
    gemm_mfma<2, 0><<<dim3(12, 64), 256, 0, stream>>>(
        h16, 512, wt_qkv + (size_t)l*1536*512, 512,
        bq + l*512, bk + l*512, bv + l*512,
        nullptr, q16, k16, vb, NTOK, 1536, 512);

    attn_mfma_topk<<<dim3(128, 32), 512, 0, stream>>>(q16, k16, vb, aob16);

    // WO: 256 blocks (1/CU): double-buffer pipeline.
    gemm_mfma<0, 1><<<dim3(4, 64), 256, 0, stream>>>(
        aob16, 512, wt_wo + (size_t)l*512*512, 512,
        bo + l*512, nullptr, nullptr,
        tmp, nullptr, nullptr, nullptr, NTOK, 512, 512);
    resid_ln_kernel<<<NTOK/2, 256, 0, stream>>>(h, tmp, ln1g + l*512, ln1b + l*512, h16);

    // FF1: 1024 blocks (4/CU): single-buffer.
    gemm_mfma<1, 0><<<dim3(16, 64), 256, 0, stream>>>(
        h16, 512, wt_ff1 + (size_t)l*2048*512, 512,
        ff1b + l*2048, nullptr, nullptr,
        nullptr, ff16, nullptr, nullptr, NTOK, 2048, 512);

    // FF2: 256 blocks (1/CU): double-buffer pipeline.
    gemm_mfma<0, 1><<<dim3(4, 64), 256, 0, stream>>>(
        ff16, 2048, wt_ff2 + (size_t)l*512*2048, 2048,
        ff2b + l*512, nullptr, nullptr,
        tmp, nullptr, nullptr, nullptr, NTOK, 512, 2048);
    resid_ln_kernel<<<NTOK/2, 256, 0, stream>>>(h, tmp, ln2g + l*512, ln2b + l*512,
                                                (l == 1) ? nullptr : h16);
  }

  pool_kernel<<<dim3(2, 4, 32), 256, 0, stream>>>(h, part);
  decoder_kernel<<<1, 256, 0, stream>>>(part, d1w, d1b, d2w, d2b, (float*)d_out);
}

// Round 9
// 673.689 us; speedup vs baseline: 1.3173x; 1.0231x over previous
//
#include <hip/hip_runtime.h>
#include <cmath>

typedef unsigned short u16;
typedef __attribute__((ext_vector_type(8))) short short8;
typedef __attribute__((ext_vector_type(4))) float float4v;
typedef unsigned short ushort2v __attribute__((ext_vector_type(2)));

#define S_LEN 2048
#define NTOK  8192   // B*S
#define TOPK  35
#define NT512 ((size_t)NTOK*512)

__device__ __forceinline__ u16 f2b(float f){
  unsigned int x = __float_as_uint(f);
  unsigned int r = (x + 0x7fffu + ((x >> 16) & 1u)) >> 16;
  return (u16)r;
}

__device__ __forceinline__ float key_to_f(unsigned key){
  unsigned m = (key & 0x8000u) ? 0x8000u : 0xFFFFu;
  return __uint_as_float(((key ^ m) & 0xFFFFu) << 16);
}
// packed u16x2 of bf16 bit patterns -> monotone sort keys, both halves at
// once. Per half: key = u ^ (sign ? 0xFFFF : 0x8000). Carry/borrow across
// the halves cancels exactly (verified all 4 sign combos).
__device__ __forceinline__ unsigned key2_of(unsigned u){
  unsigned t = (u >> 15) & 0x00010001u;
  unsigned mask = 0x80008000u + (t << 15) - t;
  return u ^ mask;
}
__device__ __forceinline__ unsigned pkmax(unsigned a, unsigned b){
  union { unsigned u; ushort2v v; } x, y, r;
  x.u = a; y.u = b;
  r.v = __builtin_elementwise_max(x.v, y.v);
  return r.u;
}
__device__ __forceinline__ unsigned pkmin(unsigned a, unsigned b){
  union { unsigned u; ushort2v v; } x, y, r;
  x.u = a; y.u = b;
  r.v = __builtin_elementwise_min(x.v, y.v);
  return r.u;
}

// full bitonic sort, DESCENDING, of 128 packed-u16x2 values distributed
// 2 per lane: element e = l (v0) and e = 64+l (v1). Sorts both u16 halves
// independently (pk ops are per-half).
__device__ __forceinline__ void bsort128(unsigned &v0, unsigned &v1, int l){
  #pragma unroll
  for (int k = 2; k <= 128; k <<= 1){
    #pragma unroll
    for (int j = k >> 1; j > 0; j >>= 1){
      if (j == 64){
        unsigned hi = pkmax(v0, v1), lo = pkmin(v0, v1);
        v0 = hi; v1 = lo;
      } else {
        unsigned o0 = (unsigned)__shfl_xor((int)v0, j, 64);
        unsigned o1 = (unsigned)__shfl_xor((int)v1, j, 64);
        bool up0 = (((l & k) == 0) != ((l & j) != 0));
        bool up1 = ((((64 + l) & k) == 0) != ((l & j) != 0));
        unsigned hi0 = pkmax(v0, o0), lo0 = pkmin(v0, o0);
        unsigned hi1 = pkmax(v1, o1), lo1 = pkmin(v1, o1);
        v0 = up0 ? hi0 : lo0;
        v1 = up1 ? hi1 : lo1;
      }
    }
  }
}

// async global->LDS 16B direct copy; LDS dest pattern = wave-uniform base + lane*16
__device__ __forceinline__ void gload16(const void* g, void* l){
  __builtin_amdgcn_global_load_lds(
      (const __attribute__((address_space(1))) unsigned int*)g,
      (__attribute__((address_space(3))) unsigned int*)l, 16, 0, 0);
}

// ---------------- fused prep: weight transpose/convert + embedding ----------------
struct WtArgs {
  const float* wq; const float* wk; const float* wv; const float* wo;
  const float* ff1w; const float* ff2w;
  u16* wt_qkv; u16* wt_wo; u16* wt_ff1; u16* wt_ff2;
};
__global__ void prep_kernel(WtArgs a,
                            const float* __restrict__ x, const float* __restrict__ w,
                            const float* __restrict__ bias, float* __restrict__ h,
                            u16* __restrict__ h16){
  __shared__ float xs[4][64];
  __shared__ u16 t[32][33];
  int bx = blockIdx.x;
  int tid = threadIdx.x;               // 0..255
  if (bx < 6144){
    int l  = (bx >= 3072) ? 1 : 0;
    int tt = bx - l*3072;
    const float* W; u16* Wt; int K, N, tx_, ty_;
    if (tt < 1024){                 // qkv (3 segs) + wo, all 512x512, 16x16 tiles
      int seg = tt >> 8, r = tt & 255;
      tx_ = r & 15; ty_ = r >> 4; K = 512; N = 512;
      if (seg == 0){ W = a.wq + (size_t)l*262144; Wt = a.wt_qkv + (size_t)l*786432; }
      else if (seg == 1){ W = a.wk + (size_t)l*262144; Wt = a.wt_qkv + (size_t)l*786432 + 262144; }
      else if (seg == 2){ W = a.wv + (size_t)l*262144; Wt = a.wt_qkv + (size_t)l*786432 + 524288; }
      else { W = a.wo + (size_t)l*262144; Wt = a.wt_wo + (size_t)l*262144; }
    } else if (tt < 2048){          // ff1: K=512, N=2048 -> tiles 64 x 16
      int r = tt - 1024;
      tx_ = r & 63; ty_ = r >> 6; K = 512; N = 2048;
      W = a.ff1w + (size_t)l*1048576; Wt = a.wt_ff1 + (size_t)l*1048576;
    } else {                        // ff2: K=2048, N=512 -> tiles 16 x 64
      int r = tt - 2048;
      tx_ = r & 15; ty_ = r >> 4; K = 2048; N = 512;
      W = a.ff2w + (size_t)l*1048576; Wt = a.wt_ff2 + (size_t)l*1048576;
    }
    int k0 = ty_*32, n0 = tx_*32;
    int tx = tid & 31, ty = tid >> 5;   // 32x8
    #pragma unroll
    for (int i = ty; i < 32; i += 8)
      t[i][tx] = f2b(W[(size_t)(k0+i)*N + n0+tx]);
    __syncthreads();
    #pragma unroll
    for (int i = ty; i < 32; i += 8)
      Wt[(size_t)(n0+i)*K + k0+tx] = t[tx][i];
  } else {
    int t0 = (bx - 6144) * 4;          // 4 tokens per block
    xs[tid >> 6][tid & 63] = x[(size_t)(t0 + (tid >> 6))*64 + (tid & 63)];
    __syncthreads();
    float b0 = bias[tid], b1 = bias[tid + 256];
    float acc[4][2];
    #pragma unroll
    for (int tk = 0; tk < 4; ++tk){ acc[tk][0] = b0; acc[tk][1] = b1; }
    #pragma unroll 8
    for (int k = 0; k < 64; ++k){
      float w0 = w[k*512 + tid];
      float w1 = w[k*512 + tid + 256];
      #pragma unroll
      for (int tk = 0; tk < 4; ++tk){
        float xv = xs[tk][k];
        acc[tk][0] += xv * w0;
        acc[tk][1] += xv * w1;
      }
    }
    const float neg_ln1e4_over_D = -9.210340371976184f / 512.f;
    int c0 = tid, c1 = tid + 256;
    float e0 = expf((float)(c0 & ~1) * neg_ln1e4_over_D);
    float e1 = expf((float)(c1 & ~1) * neg_ln1e4_over_D);
    #pragma unroll
    for (int tk = 0; tk < 4; ++tk){
      int tok = t0 + tk;
      int s = tok & (S_LEN - 1);
      float a0 = (float)s * e0;
      float p0 = (c0 & 1) ? cosf(a0) : sinf(a0);
      float a1 = (float)s * e1;
      float p1 = (c1 & 1) ? cosf(a1) : sinf(a1);
      float v0 = acc[tk][0] + p0, v1 = acc[tk][1] + p1;
      h[(size_t)tok*512 + c0] = v0;  h16[(size_t)tok*512 + c0] = f2b(v0);
      h[(size_t)tok*512 + c1] = v1;  h16[(size_t)tok*512 + c1] = f2b(v1);
    }
  }
}

// ---------------- bf16 MFMA GEMM: C = A[M,lda] @ Bt[N,ldb]^T + bias ----------------
// XCD-aware bijective tile swizzle. DBUF=1: 2-phase double-buffered pipeline
// (1-block/CU shapes: WO/FF2). DBUF=0: single-buffer (QKV/FF1, TLP covers).
template<int EPI, int DBUF>
__global__ __launch_bounds__(256) void gemm_mfma(
    const u16* __restrict__ A, int lda, const u16* __restrict__ Bt, int ldb,
    const float* __restrict__ bias0, const float* __restrict__ bias1,
    const float* __restrict__ bias2,
    float* __restrict__ Cf, u16* __restrict__ C16a, u16* __restrict__ C16b,
    float* __restrict__ Cv, int M, int N, int Klen){
  __shared__ __align__(16) u16 As[(DBUF ? 2 : 1)*128*64];
  __shared__ __align__(16) u16 Bs[(DBUF ? 2 : 1)*128*64];
  int tid = threadIdx.x;
  int w = tid >> 6, l = tid & 63, quad = l >> 4, m = l & 15;
  int gx = gridDim.x;
  int orig = blockIdx.y * gx + blockIdx.x;
  int nwg  = gx * gridDim.y;
  int tt   = (orig & 7) * (nwg >> 3) + (orig >> 3);
  int m0 = (tt / gx) * 128, n0 = (tt % gx) * 128;
  int mh = (w >> 1)*64, nh = (w & 1)*64;
  float4v acc[4][4];
  #pragma unroll
  for (int i = 0; i < 4; ++i)
    #pragma unroll
    for (int j = 0; j < 4; ++j) acc[i][j] = (float4v){0.f,0.f,0.f,0.f};

  #define GSTAGE(ofs, kt) do { \
    _Pragma("unroll") \
    for (int c = 0; c < 4; ++c){ \
      int g = c*256 + tid; \
      int row = g >> 3, scx = g & 7, dc = scx ^ (row & 7); \
      gload16(A  + (size_t)(m0+row)*lda + (kt) + dc*8, As + (ofs) + (size_t)g*8); \
      gload16(Bt + (size_t)(n0+row)*ldb + (kt) + dc*8, Bs + (ofs) + (size_t)g*8); \
    } } while(0)

  #define GCOMPUTE(Ac, Bc) do { \
    _Pragma("unroll") \
    for (int kk = 0; kk < 2; ++kk){ \
      short8 af[4], bf[4]; \
      _Pragma("unroll") \
      for (int i = 0; i < 4; ++i){ \
        int dcx = kk*4 + quad; \
        int ra = mh + i*16 + m; \
        af[i] = *(const short8*)((Ac) + (size_t)(ra*8 + (dcx ^ (ra & 7)))*8); \
        int rb = nh + i*16 + m; \
        bf[i] = *(const short8*)((Bc) + (size_t)(rb*8 + (dcx ^ (rb & 7)))*8); \
      } \
      _Pragma("unroll") \
      for (int i = 0; i < 4; ++i) \
        _Pragma("unroll") \
        for (int j = 0; j < 4; ++j) \
          acc[i][j] = __builtin_amdgcn_mfma_f32_16x16x32_bf16(af[i], bf[j], acc[i][j], 0, 0, 0); \
    } } while(0)

  if (DBUF){
    GSTAGE(0, 0);
    __syncthreads();
    int cur = 0;
    for (int kt = 0; kt < Klen; kt += 64){
      int nxt = cur ^ 1;
      if (kt + 64 < Klen) GSTAGE(nxt*(128*64), kt + 64);
      GCOMPUTE(As + cur*(128*64), Bs + cur*(128*64));
      __syncthreads();
      cur = nxt;
    }
  } else {
    for (int kt = 0; kt < Klen; kt += 64){
      GSTAGE(0, kt);
      __syncthreads();
      GCOMPUTE(As, Bs);
      __syncthreads();
    }
  }
  #undef GSTAGE
  #undef GCOMPUTE

  // C/D layout: row_local = quad*4+r, col_local = m
  #pragma unroll
  for (int i = 0; i < 4; ++i){
    #pragma unroll
    for (int j = 0; j < 4; ++j){
      int col = n0 + nh + j*16 + m;
      #pragma unroll
      for (int r = 0; r < 4; ++r){
        int row = m0 + mh + i*16 + quad*4 + r;
        float v = acc[i][j][r];
        if (EPI == 0){
          Cf[(size_t)row*N + col] = v + bias0[col];
        } else if (EPI == 1){
          C16a[(size_t)row*N + col] = f2b(fmaxf(v + bias0[col], 0.f));
        } else {
          int sel = col >> 9, n5 = col & 511;
          const float* bp = (sel == 0) ? bias0 : (sel == 1) ? bias1 : bias2;
          float vv = v + bp[n5];
          int d = n5 & 63, hh = n5 >> 6;
          int b = row >> 11, s = row & 2047;
          size_t idx = (((size_t)(b*8 + hh))*2048 + s)*64 + d;
          if (sel == 0)      C16a[idx] = f2b(vv);
          else if (sel == 1) C16b[idx] = f2b(vv);
          else if (s < TOPK) Cv[idx]  = vv;   // attn reads only V rows 0..34
        }
      }
    }
  }
}

// ---------------- fused MFMA scores + top-35 + softmax + P@V[:35] ----------------
// ILP-2 restructure: 4 waves x 64 lanes per block; each wave owns TWO
// pair-rows (4 queries) and 512 keys of the score phase (32 tiles).
// Every serial selection stage runs as two register-independent pipelines
// (pair A = row 2w = queries 4w,4w+1; pair B = row 2w+1 = queries 4w+2,4w+3)
// that interleave in the scheduler, filling dependency stalls.
// Selection math per pair is IDENTICAL to the verified R8 version.
__global__ __launch_bounds__(256, 4) void attn_mfma_topk(
    const u16* __restrict__ qb16, const u16* __restrict__ kb16,
    const float* __restrict__ vb, u16* __restrict__ aob16){
  __shared__ unsigned pr[8*1024];   // 32 KB: 8 pair-rows x 1024 (half-split)
  int tid  = threadIdx.x;
  int w    = tid >> 6, l = tid & 63;   // w in 0..3
  int quad = l >> 4,  m = l & 15;
  // bijective XCD swizzle over 4096 blocks (128 x 32)
  int orig = blockIdx.y * 128 + blockIdx.x;
  int t4   = ((orig & 7) << 9) | (orig >> 3);
  int bh   = t4 >> 7;
  int q0   = (t4 & 127) << 4;

  const u16* Qp = qb16 + ((size_t)bh*2048 + q0 + m)*64 + quad*8;
  short8 a0 = *(const short8*)Qp;
  short8 a1 = *(const short8*)(Qp + 32);

  const u16* Kbase = kb16 + (size_t)bh*2048*64;
  unsigned scA[32], scB[32];           // rows 2w, 2w+1
  int swz = (quad & 1) << 4;
  // wave w covers keys [w*256, w*256+256) within each 1024-key half
  const u16* kp0 = Kbase + (size_t)(w*256 + m)*64 + quad*8;
  const uint4* p4a = (const uint4*)(pr + (2*w)*1024);
  const uint4* p4b = (const uint4*)(pr + (2*w+1)*1024);

  short8 cb0 = *(const short8*)kp0;
  short8 cb1 = *(const short8*)(kp0 + 32);
  #pragma unroll
  for (int t = 0; t < 32; ++t){        // tile t: half = t>>4, kt = t&15
    short8 nb0, nb1;
    if (t < 31){
      int tn = t + 1;
      const u16* np = kp0 + (size_t)(((tn >> 4) << 10) + ((tn & 15) << 4))*64;
      nb0 = *(const short8*)np;
      nb1 = *(const short8*)(np + 32);
    }
    float4v acc = {0.f, 0.f, 0.f, 0.f};
    acc = __builtin_amdgcn_mfma_f32_16x16x32_bf16(a0, cb0, acc, 0, 0, 0);
    acc = __builtin_amdgcn_mfma_f32_16x16x32_bf16(a1, cb1, acc, 0, 0, 0);
    int lk = (w << 8) + ((t & 15) << 4);   // within-half key index base
    #pragma unroll
    for (int c = 0; c < 2; ++c){
      // packed RNE bf16 round -> u16x2 -> packed sort keys (bit-exact)
      unsigned xa = __float_as_uint(acc[2*c]);
      unsigned xb = __float_as_uint(acc[2*c+1]);
      unsigned ta = xa + 0x7fffu + ((xa >> 16) & 1u);
      unsigned tb = xb + 0x7fffu + ((xb >> 16) & 1u);
      unsigned pk = (ta >> 16) | (tb & 0xFFFF0000u);
      pr[(quad*2 + c)*1024 + ((lk + m) ^ swz)] = key2_of(pk);
    }
    cb0 = nb0; cb1 = nb1;
    if (t == 15){
      __syncthreads();
      #pragma unroll
      for (int j = 0; j < 4; ++j){
        uint4 va = p4a[j*64 + l];
        scA[j*4+0] = va.x; scA[j*4+1] = va.y; scA[j*4+2] = va.z; scA[j*4+3] = va.w;
        uint4 vb_ = p4b[j*64 + l];
        scB[j*4+0] = vb_.x; scB[j*4+1] = vb_.y; scB[j*4+2] = vb_.z; scB[j*4+3] = vb_.w;
      }
      __syncthreads();
    }
  }
  __syncthreads();
  #pragma unroll
  for (int j = 0; j < 4; ++j){
    uint4 va = p4a[j*64 + l];
    scA[16+j*4+0] = va.x; scA[16+j*4+1] = va.y; scA[16+j*4+2] = va.z; scA[16+j*4+3] = va.w;
    uint4 vb_ = p4b[j*64 + l];
    scB[16+j*4+0] = vb_.x; scB[16+j*4+1] = vb_.y; scB[16+j*4+2] = vb_.z; scB[16+j*4+3] = vb_.w;
  }

  unsigned* rowA = &pr[(2*w)*1024];     // wave-private after the barrier
  unsigned* rowB = &pr[(2*w+1)*1024];

  // ---- per-lane packed top-2, both pairs ----
  unsigned m1a = pkmax(scA[0], scA[1]), m2a = pkmin(scA[0], scA[1]);
  unsigned m1b = pkmax(scB[0], scB[1]), m2b = pkmin(scB[0], scB[1]);
  #pragma unroll
  for (int i = 2; i < 32; ++i){
    unsigned va = scA[i];
    unsigned na = pkmax(m1a, va);
    m2a = pkmax(m2a, pkmin(m1a, va));
    m1a = na;
    unsigned vb_ = scB[i];
    unsigned nb_ = pkmax(m1b, vb_);
    m2b = pkmax(m2b, pkmin(m1b, vb_));
    m1b = nb_;
  }

  // ---- T' via binary search (rank-35 of 128 top-2s), 4 queries ----
  unsigned a1h = m1a & 0xFFFFu, a1H = m1a >> 16;
  unsigned a2h = m2a & 0xFFFFu, a2H = m2a >> 16;
  unsigned b1h = m1b & 0xFFFFu, b1H = m1b >> 16;
  unsigned b2h = m2b & 0xFFFFu, b2H = m2b >> 16;
  unsigned tA = 0, tB = 0, tC = 0, tD = 0;
  #pragma unroll
  for (int bit = 15; bit >= 0; --bit){
    unsigned cA = tA | (1u << bit), cB = tB | (1u << bit);
    unsigned cC = tC | (1u << bit), cD = tD | (1u << bit);
    int nA = __popcll(__ballot(a1h >= cA)) + __popcll(__ballot(a2h >= cA));
    int nB = __popcll(__ballot(a1H >= cB)) + __popcll(__ballot(a2H >= cB));
    int nC = __popcll(__ballot(b1h >= cC)) + __popcll(__ballot(b2h >= cC));
    int nD = __popcll(__ballot(b1H >= cD)) + __popcll(__ballot(b2H >= cD));
    if (nA >= TOPK) tA = cA;
    if (nB >= TOPK) tB = cB;
    if (nC >= TOPK) tC = cC;
    if (nD >= TOPK) tD = cD;
  }
  unsigned TTa = (tA - 1) | ((tB - 1) << 16);
  unsigned TTb = (tC - 1) | ((tD - 1) << 16);

  // ---- survivor masks ----
  unsigned maskA = 0, maskB = 0;
  #pragma unroll
  for (int i = 0; i < 32; ++i){
    maskA |= (pkmax(scA[i], TTa) != TTa) ? (1u << i) : 0u;
    maskB |= (pkmax(scB[i], TTb) != TTb) ? (1u << i) : 0u;
  }
  int cntA = __popc(maskA), cntB = __popc(maskB);

  // exclusive prefix over lanes (two independent chains)
  int preA = cntA, preB = cntB;
  #pragma unroll
  for (int off = 1; off < 64; off <<= 1){
    int nA_ = __shfl_up(preA, off, 64);
    int nB_ = __shfl_up(preB, off, 64);
    if (l >= off){ preA += nA_; preB += nB_; }
  }
  preA -= cntA; preB -= cntB;

  // compact survivors (de-chained positions)
  #pragma unroll
  for (int i = 0; i < 32; ++i){
    if (maskA & (1u << i)){
      int p = preA + __popc(maskA & ((1u << i) - 1u));
      if (p < 128) rowA[p] = scA[i];
    }
    if (maskB & (1u << i)){
      int p = preB + __popc(maskB & ((1u << i) - 1u));
      if (p < 128) rowB[p] = scB[i];
    }
  }
  int totA = __shfl(preA + cntA, 63, 64);
  int totB = __shfl(preB + cntB, 63, 64);

  unsigned c0 = (l < totA)      ? rowA[l]      : 0u;
  unsigned c1 = (64 + l < totA) ? rowA[64 + l] : 0u;
  unsigned c2 = (l < totB)      ? rowB[l]      : 0u;
  unsigned c3 = (64 + l < totB) ? rowB[64 + l] : 0u;

  // V rows 0..34 (shared by all 4 queries; overlaps with the sorts)
  const float* Vb = vb + (size_t)bh*2048*64 + l;   // lane = d
  float vreg[TOPK];
  #pragma unroll
  for (int r = 0; r < TOPK; ++r) vreg[r] = Vb[(size_t)r*64];

  // ---- two independent sort-128s (interleaved by the scheduler) ----
  bsort128(c0, c1, l);
  bsort128(c2, c3, l);

  // ---- softmax weights, once per rank, 4 queries ----
  unsigned topA = (unsigned)__shfl((int)c0, 0, 64);
  unsigned topB = (unsigned)__shfl((int)c2, 0, 64);
  float mA = key_to_f(topA & 0xFFFFu) * 0.125f;
  float mB = key_to_f(topA >> 16)     * 0.125f;
  float mC = key_to_f(topB & 0xFFFFu) * 0.125f;
  float mD = key_to_f(topB >> 16)     * 0.125f;
  float vA = key_to_f(c0 & 0xFFFFu)   * 0.125f;
  float vB = key_to_f(c0 >> 16)       * 0.125f;
  float vC = key_to_f(c2 & 0xFFFFu)   * 0.125f;
  float vD = key_to_f(c2 >> 16)       * 0.125f;
  bool in = (l < TOPK);
  float wA = in ? __expf(vA - mA) : 0.f;
  float wB = in ? __expf(vB - mB) : 0.f;
  float wC = in ? __expf(vC - mC) : 0.f;
  float wD = in ? __expf(vD - mD) : 0.f;

  float dA = wA, dB = wB, dC = wC, dD = wD;
  #pragma unroll
  for (int off = 32; off > 0; off >>= 1){
    dA += __shfl_xor(dA, off, 64);
    dB += __shfl_xor(dB, off, 64);
    dC += __shfl_xor(dC, off, 64);
    dD += __shfl_xor(dD, off, 64);
  }

  // PV: rank-r weights broadcast via readlane (4 independent FMA chains)
  float oA = 0.f, oB = 0.f, oC = 0.f, oD = 0.f;
  #pragma unroll
  for (int r = 0; r < TOPK; ++r){
    float rA = __uint_as_float((unsigned)__builtin_amdgcn_readlane((int)__float_as_uint(wA), r));
    float rB = __uint_as_float((unsigned)__builtin_amdgcn_readlane((int)__float_as_uint(wB), r));
    float rC = __uint_as_float((unsigned)__builtin_amdgcn_readlane((int)__float_as_uint(wC), r));
    float rD = __uint_as_float((unsigned)__builtin_amdgcn_readlane((int)__float_as_uint(wD), r));
    float vv = vreg[r];
    oA += rA * vv;
    oB += rB * vv;
    oC += rC * vv;
    oD += rD * vv;
  }
  oA *= __builtin_amdgcn_rcpf(dA);
  oB *= __builtin_amdgcn_rcpf(dB);
  oC *= __builtin_amdgcn_rcpf(dC);
  oD *= __builtin_amdgcn_rcpf(dD);

  int b = bh >> 3, hh = bh & 7;
  int sA = q0 + 4*w;
  aob16[(((size_t)(b*2048 + sA))*8 + hh)*64 + l]     = f2b(oA);
  aob16[(((size_t)(b*2048 + sA + 1))*8 + hh)*64 + l] = f2b(oB);
  aob16[(((size_t)(b*2048 + sA + 2))*8 + hh)*64 + l] = f2b(oC);
  aob16[(((size_t)(b*2048 + sA + 3))*8 + hh)*64 + l] = f2b(oD);
}

// ---------------- h = LayerNorm(h + t) * g + b, in place; also bf16 copy ----------------
__global__ void resid_ln_kernel(float* __restrict__ h, const float* __restrict__ t,
                                const float* __restrict__ g, const float* __restrict__ b,
                                u16* __restrict__ h16){
  int half = threadIdx.x >> 7;             // 0 or 1
  int tok  = blockIdx.x*2 + half;
  int tid  = threadIdx.x & 127;            // float4 col index 0..127
  size_t base4 = (size_t)tok * 128;        // float4 units per row
  float4 hv = ((const float4*)h)[base4 + tid];
  float4 tv = ((const float4*)t)[base4 + tid];
  float x0 = hv.x + tv.x, x1 = hv.y + tv.y;
  float x2 = hv.z + tv.z, x3 = hv.w + tv.w;
  __shared__ float red[8];
  int wid = threadIdx.x >> 6, lane = threadIdx.x & 63;

  float s = (x0 + x1) + (x2 + x3);
  #pragma unroll
  for (int off = 32; off > 0; off >>= 1) s += __shfl_xor(s, off, 64);
  if (lane == 0) red[wid] = s;
  __syncthreads();
  int hb = half << 1;
  float mean = (red[hb] + red[hb+1]) * (1.f/512.f);

  float d0 = x0 - mean, d1 = x1 - mean, d2 = x2 - mean, d3 = x3 - mean;
  float sq = (d0*d0 + d1*d1) + (d2*d2 + d3*d3);
  #pragma unroll
  for (int off = 32; off > 0; off >>= 1) sq += __shfl_xor(sq, off, 64);
  if (lane == 0) red[4 + wid] = sq;
  __syncthreads();
  float var = (red[4 + hb] + red[4 + hb + 1]) * (1.f/512.f);
  float inv = rsqrtf(var + 1e-5f);
  float4 gv = ((const float4*)g)[tid];
  float4 bv = ((const float4*)b)[tid];
  float o0 = d0 * inv * gv.x + bv.x;
  float o1 = d1 * inv * gv.y + bv.y;
  float o2 = d2 * inv * gv.z + bv.z;
  float o3 = d3 * inv * gv.w + bv.w;
  ((float4*)h)[base4 + tid] = make_float4(o0, o1, o2, o3);
  if (h16){
    uint2 pk;
    pk.x = (unsigned)f2b(o0) | ((unsigned)f2b(o1) << 16);
    pk.y = (unsigned)f2b(o2) | ((unsigned)f2b(o3) << 16);
    ((uint2*)h16)[base4 + tid] = pk;
  }
}

// ---------------- mean over sequence: partial sums ----------------
__global__ void pool_kernel(const float* __restrict__ h, float* __restrict__ part){
  int c = blockIdx.x * 256 + threadIdx.x;   // 0..511
  int b = blockIdx.y;
  int z = blockIdx.z;
  const float* p = h + ((size_t)b * 2048 + z * 64) * 512 + c;
  float acc = 0.f;
  #pragma unroll 8
  for (int s = 0; s < 64; ++s) acc += p[(size_t)s * 512];
  part[((size_t)(z*4 + b))*512 + c] = acc;
}

// ---------------- tiny decoder (sums the 32 pool partials) ----------------
__global__ void decoder_kernel(const float* __restrict__ part,
                               const float* __restrict__ w1, const float* __restrict__ b1,
                               const float* __restrict__ w2, const float* __restrict__ b2,
                               float* __restrict__ out){
  __shared__ float ps[4][512];
  __shared__ float hid[4][256];
  int tid = threadIdx.x;
  for (int i = tid; i < 2048; i += 256){
    int b = i >> 9, c = i & 511;
    float s = 0.f;
    #pragma unroll
    for (int z = 0; z < 32; ++z) s += part[((size_t)(z*4 + b))*512 + c];
    ps[b][c] = s * (1.f/2048.f);
  }
  __syncthreads();
  float bb = b1[tid];
  for (int b = 0; b < 4; ++b){
    float acc = bb;
    for (int k = 0; k < 512; ++k) acc += ps[b][k] * w1[k*256 + tid];
    hid[b][tid] = fmaxf(acc, 0.f);
  }
  __syncthreads();
  if (tid < 8){
    int b = tid >> 1, c = tid & 1;
    float acc = b2[c];
    for (int j = 0; j < 256; ++j) acc += hid[b][j] * w2[j*2 + c];
    out[b*2 + c] = acc;
  }
}

extern "C" void kernel_launch(void* const* d_in, const int* in_sizes, int n_in,
                              void* d_out, int out_size, void* d_ws, size_t ws_size,
                              hipStream_t stream){
  const float* x     = (const float*)d_in[0];
  const float* emb_w = (const float*)d_in[1];
  const float* emb_b = (const float*)d_in[2];
  const float* wq    = (const float*)d_in[3];
  const float* bq    = (const float*)d_in[4];
  const float* wk    = (const float*)d_in[5];
  const float* bk    = (const float*)d_in[6];
  const float* wv    = (const float*)d_in[7];
  const float* bv    = (const float*)d_in[8];
  const float* wo    = (const float*)d_in[9];
  const float* bo    = (const float*)d_in[10];
  const float* ff1w  = (const float*)d_in[11];
  const float* ff1b  = (const float*)d_in[12];
  const float* ff2w  = (const float*)d_in[13];
  const float* ff2b  = (const float*)d_in[14];
  const float* ln1g  = (const float*)d_in[15];
  const float* ln1b  = (const float*)d_in[16];
  const float* ln2g  = (const float*)d_in[17];
  const float* ln2b  = (const float*)d_in[18];
  const float* d1w   = (const float*)d_in[19];
  const float* d1b   = (const float*)d_in[20];
  const float* d2w   = (const float*)d_in[21];
  const float* d2b   = (const float*)d_in[22];

  // ---- workspace layout (~92 MB) ----
  float* h      = (float*)d_ws;
  float* tmp    = h + NT512;
  u16*   u      = (u16*)(tmp + NT512);
  u16*   h16    = u;
  u16*   q16    = u + NT512;
  u16*   k16    = u + 2*NT512;
  float* vb     = (float*)(u + 3*NT512);
  u16*   ff16   = q16;                 // 32 MB overlay of q16+k16+vb
  u16*   aob16  = (u16*)(vb + NT512);
  u16*   wt     = aob16 + NT512;
  u16*   wt_qkv = wt;                          // 2 x 1536*512
  u16*   wt_wo  = wt_qkv + (size_t)2*1536*512; // 2 x 512*512
  u16*   wt_ff1 = wt_wo  + (size_t)2*512*512;  // 2 x 2048*512
  u16*   wt_ff2 = wt_ff1 + (size_t)2*2048*512; // 2 x 512*2048
  float* part   = tmp;                 // pool partials [32][4][512] in dead tmp

  WtArgs wa{wq, wk, wv, wo, ff1w, ff2w, wt_qkv, wt_wo, wt_ff1, wt_ff2};
  prep_kernel<<<8192, 256, 0, stream>>>(wa, x, emb_w, emb_b, h, h16);

  for (int l = 0; l < 2; ++l){
    // fused QKV: N=1536, scatter epilogue. 768 blocks (3/CU): single-buffer.
    gemm_mfma<2, 0><<<dim3(12, 64), 256, 0, stream>>>(
        h16, 512, wt_qkv + (size_t)l*1536*512, 512,
        bq + l*512, bk + l*512, bv + l*512,
        nullptr, q16, k16, vb, NTOK, 1536, 512);

    attn_mfma_topk<<<dim3(128, 32), 256, 0, stream>>>(q16, k16, vb, aob16);

    // WO: 256 blocks (1/CU): double-buffer pipeline.
    gemm_mfma<0, 1><<<dim3(4, 64), 256, 0, stream>>>(
        aob16, 512, wt_wo + (size_t)l*512*512, 512,
        bo + l*512, nullptr, nullptr,
        tmp, nullptr, nullptr, nullptr, NTOK, 512, 512);
    resid_ln_kernel<<<NTOK/2, 256, 0, stream>>>(h, tmp, ln1g + l*512, ln1b + l*512, h16);

    // FF1: 1024 blocks (4/CU): single-buffer.
    gemm_mfma<1, 0><<<dim3(16, 64), 256, 0, stream>>>(
        h16, 512, wt_ff1 + (size_t)l*2048*512, 512,
        ff1b + l*2048, nullptr, nullptr,
        nullptr, ff16, nullptr, nullptr, NTOK, 2048, 512);

    // FF2: 256 blocks (1/CU): double-buffer pipeline.
    gemm_mfma<0, 1><<<dim3(4, 64), 256, 0, stream>>>(
        ff16, 2048, wt_ff2 + (size_t)l*512*2048, 2048,
        ff2b + l*512, nullptr, nullptr,
        tmp, nullptr, nullptr, nullptr, NTOK, 512, 2048);
    resid_ln_kernel<<<NTOK/2, 256, 0, stream>>>(h, tmp, ln2g + l*512, ln2b + l*512,
                                                (l == 1) ? nullptr : h16);
  }

  pool_kernel<<<dim3(2, 4, 32), 256, 0, stream>>>(h, part);
  decoder_kernel<<<1, 256, 0, stream>>>(part, d1w, d1b, d2w, d2b, (float*)d_out);
}